// Round 2
// baseline (182.970 us; speedup 1.0000x reference)
//
#include <hip/hip_runtime.h>

// Problem: b=4, c=256, ci=128, h=w=64 (HW=4096), field=7, kk=49. fp32 I/O.
//
// 6-dispatch pipeline; MFMA GEMMs (split-bf16 hi+lo) with operands PACKED in
// MFMA-fragment order (fragment = 512 ushorts; lane ln reads 16 B at
// frag_base + ln*16). A-frag elem[ln*8+j] = W[row=ln&15][k=(ln>>4)*8+j];
// B-frag elem[ln*8+j] = M[k=(ln>>4)*8+j][col=ln&15]; C/D col=lane&15,
// row=quad*4+reg (all r10/r11-verified).
//  1. prep: x -> xp_hi/lo packed; w3 -> w3p_hi/lo; wm -> wmp_hi/lo; zero planes.
//  2. conv3_mfma: MERGED regions — one block computes phi+theta+g for a
//     32-px tile (grid 128x4). B-fragments (xp) read ONCE (was 3x, one per
//     region); per kb: 4 B-loads + 12 A-loads : 36 MFMAs. Same per-acc MFMA
//     order as the verified baseline -> bit-identical outputs.
//  3. scores: segmented flat-decode gather (verified r6-11): lane=t, serial
//     cc, F = s*6272 + 49*cc + t decodes into padded channel-major planes.
//  4. softmax_stats: per (b,j,t): m and inv=1/sum only (no normalize pass).
//  5. aggregate: attn = exp(sc-m)*inv inline (bit-identical to r11), then
//     segmented gather; y stored packed.
//  6. maskconv_mfma: 2 o-tiles/wave, (wm_hi+wm_lo).y + x -> out fp32.
//
// Padded planes: [b][c0][70][72] bf16, data (py,px) at (py+3,px+4), zero
// borders; patch addr for F -> (ch=F>>12, p=F&4095):
//   a = OFF(ch) + p + 8*(p>>6), OFF(ch) = c0*5040 + kh*72 + kw + 1.
// Per-pixel F-range < 2*4096 -> <=3 ch values -> 3 pure + 2 mixed segments.
//
// ws layout (ushort units):
//   A_phi  @ 0          (2,580,480)
//   A_g    @ 2,580,480  (2,580,480)   (zeroed contiguously with A_phi)
//   y_p    @ 5,160,960  (2,097,152)   packed
//   theta  @ 7,258,112  (2,097,152)
//   scores @ 9,355,264  (2,097,152 ush = 1,048,576 fp32)
//   xp_hi  @ 11,452,416 (4,194,304)
//   xp_lo  @ 15,646,720 (4,194,304)
//   w3p_hi @ 19,841,024 (98,304)
//   w3p_lo @ 19,939,328 (98,304)
//   wmp_hi @ 20,037,632 (32,768)
//   wmp_lo @ 20,070,400 (32,768)
//   m_arr  @ 20,103,168 (25,088 ush = 12,544 fp32)
//   inv    @ 20,128,256 (25,088 ush = 12,544 fp32)   => ~40.3 MB total

#define PLANE    5040
#define A_BATCH  645120

typedef __attribute__((ext_vector_type(8))) short short8;
typedef __attribute__((ext_vector_type(4))) float floatx4;

__device__ __forceinline__ float bf2f(unsigned short u) {
    union { unsigned int i; float f; } v; v.i = ((unsigned int)u) << 16; return v.f;
}
__device__ __forceinline__ unsigned short f2bf(float f) {
    union { float f; unsigned int i; } v; v.f = f;
    unsigned int r = v.i + 0x7FFFu + ((v.i >> 16) & 1u);
    return (unsigned short)(r >> 16);
}

// ---------------------------------------------------------------------------
// prep: blocks [0,1024): x fp32 [b][k][p] -> packed hi/lo fragments.
// blocks [1024,1152): w3p/wmp hi/lo packed casts + zero plane regions.
// ---------------------------------------------------------------------------
__global__ __launch_bounds__(256) void prep_kernel(
    const float* __restrict__ x,
    const float* __restrict__ w_phi,
    const float* __restrict__ w_theta,
    const float* __restrict__ w_g,
    const float* __restrict__ w_mask,
    unsigned short* __restrict__ xp_hi,
    unsigned short* __restrict__ xp_lo,
    unsigned short* __restrict__ w3p_hi,
    unsigned short* __restrict__ w3p_lo,
    unsigned short* __restrict__ wmp_hi,
    unsigned short* __restrict__ wmp_lo,
    uint4* __restrict__ zero_region)
{
    const int tid = threadIdx.x;
    const int bx = blockIdx.x;

    if (bx < 1024) {
        const int b  = bx >> 8;          // batch
        const int kt = (bx >> 6) & 3;    // k 64-tile
        const int pt = bx & 63;          // p 64-tile
        __shared__ float tile[64][65];   // [k][p]
        #pragma unroll
        for (int i = 0; i < 16; ++i) {
            int lin = tid + i * 256;
            int kk = lin >> 6, pp = lin & 63;
            tile[kk][pp] = x[(b * 256 + kt * 64 + kk) * 4096 + pt * 64 + pp];
        }
        __syncthreads();
        #pragma unroll
        for (int i = 0; i < 16; ++i) {
            int lin = tid + i * 256;
            int frag = lin >> 9;          // 0..7
            int idx  = lin & 511;
            int kbL  = frag >> 2;         // 0..1
            int ptL  = frag & 3;          // 0..3
            int j    = idx & 7;
            int n    = (idx >> 3) & 15;
            int quad = idx >> 7;
            float f = tile[kbL * 32 + quad * 8 + j][ptL * 16 + n];
            unsigned short h = f2bf(f);
            int addr = ((b * 8 + kt * 2 + kbL) * 256 + pt * 4 + ptL) * 512 + idx;
            xp_hi[addr] = h;
            xp_lo[addr] = f2bf(f - bf2f(h));
        }
    } else {
        const int wid = (bx - 1024) * 256 + tid;   // 0..32767
        for (int e = wid; e < 98304; e += 32768) {
            int frag = e >> 9;            // 0..191
            int idx  = e & 511;
            int nt16 = frag >> 3, kb = frag & 7;
            int j = idx & 7, m = (idx >> 3) & 15, quad = idx >> 7;
            int n = nt16 * 16 + m;
            int k = kb * 32 + quad * 8 + j;
            float v = (n < 128) ? w_phi[n * 256 + k]
                    : (n < 256) ? w_theta[(n - 128) * 256 + k]
                                : w_g[(n - 256) * 256 + k];
            unsigned short h = f2bf(v);
            w3p_hi[e] = h;
            w3p_lo[e] = f2bf(v - bf2f(h));
        }
        {
            int e = wid;                  // exactly covers wmp
            int frag = e >> 9;            // 0..63
            int idx  = e & 511;
            int ot16 = frag >> 2, kb = frag & 3;
            int j = idx & 7, m = (idx >> 3) & 15, quad = idx >> 7;
            float v = w_mask[(ot16 * 16 + m) * 128 + kb * 32 + quad * 8 + j];
            unsigned short h = f2bf(v);
            wmp_hi[e] = h;
            wmp_lo[e] = f2bf(v - bf2f(h));
        }
        const uint4 z = make_uint4(0u, 0u, 0u, 0u);
        for (int i = wid; i < 645120; i += 32768) zero_region[i] = z;
    }
}

// ---------------------------------------------------------------------------
// conv3_mfma (MERGED): block = (32-px tile bx in [0,128), batch b).
// All 3 regions (phi/theta/g) computed here: B-fragments (xp) loaded once.
// Wave w handles region rows [w*16,+16) (tile a) and [64+w*16,+16) (tile b).
// Per kb: 4 B-loads + 12 A-loads : 36 MFMAs. Per-acc MFMA order identical
// to the verified per-region baseline -> bit-identical results.
// ---------------------------------------------------------------------------
__global__ __launch_bounds__(256) void conv3_mfma_kernel(
    const unsigned short* __restrict__ xp_hi,
    const unsigned short* __restrict__ xp_lo,
    const unsigned short* __restrict__ w3p_hi,
    const unsigned short* __restrict__ w3p_lo,
    unsigned short* __restrict__ A_phi,
    unsigned short* __restrict__ theta_bf,
    unsigned short* __restrict__ A_g)
{
    const int tid = threadIdx.x;
    const int w   = tid >> 6;
    const int ln  = tid & 63;
    const int lm  = ln & 15;
    const int quad = ln >> 4;
    const int bx = blockIdx.x;   // 32-px tile: pixels [bx*32, bx*32+32)
    const int b  = blockIdx.y;
    const int lnofs = ln * 8;

    // acc[nt][tile(a=0,b=1)][ct]
    floatx4 acc[3][2][2];
    #pragma unroll
    for (int nt = 0; nt < 3; ++nt)
        #pragma unroll
        for (int tl = 0; tl < 2; ++tl)
            #pragma unroll
            for (int ct = 0; ct < 2; ++ct)
                acc[nt][tl][ct] = (floatx4){0.f, 0.f, 0.f, 0.f};

    #pragma unroll
    for (int kb = 0; kb < 8; ++kb) {
        const int boff = ((b * 8 + kb) * 256 + bx * 2) * 512 + lnofs;
        short8 bh[2], bl[2];
        #pragma unroll
        for (int ct = 0; ct < 2; ++ct) {
            bh[ct] = *reinterpret_cast<const short8*>(xp_hi + boff + ct * 512);
            bl[ct] = *reinterpret_cast<const short8*>(xp_lo + boff + ct * 512);
        }
        #pragma unroll
        for (int nt = 0; nt < 3; ++nt) {
            const int nt16a = nt * 8 + w;
            const int nt16b = nt * 8 + 4 + w;
            const int aoffA = (nt16a * 8 + kb) * 512 + lnofs;
            const int aoffB = (nt16b * 8 + kb) * 512 + lnofs;
            short8 ahA = *reinterpret_cast<const short8*>(w3p_hi + aoffA);
            short8 alA = *reinterpret_cast<const short8*>(w3p_lo + aoffA);
            short8 ahB = *reinterpret_cast<const short8*>(w3p_hi + aoffB);
            short8 alB = *reinterpret_cast<const short8*>(w3p_lo + aoffB);
            #pragma unroll
            for (int ct = 0; ct < 2; ++ct) {
                acc[nt][0][ct] = __builtin_amdgcn_mfma_f32_16x16x32_bf16(ahA, bh[ct], acc[nt][0][ct], 0, 0, 0);
                acc[nt][0][ct] = __builtin_amdgcn_mfma_f32_16x16x32_bf16(ahA, bl[ct], acc[nt][0][ct], 0, 0, 0);
                acc[nt][0][ct] = __builtin_amdgcn_mfma_f32_16x16x32_bf16(alA, bh[ct], acc[nt][0][ct], 0, 0, 0);
                acc[nt][1][ct] = __builtin_amdgcn_mfma_f32_16x16x32_bf16(ahB, bh[ct], acc[nt][1][ct], 0, 0, 0);
                acc[nt][1][ct] = __builtin_amdgcn_mfma_f32_16x16x32_bf16(ahB, bl[ct], acc[nt][1][ct], 0, 0, 0);
                acc[nt][1][ct] = __builtin_amdgcn_mfma_f32_16x16x32_bf16(alB, bh[ct], acc[nt][1][ct], 0, 0, 0);
            }
        }
    }

    const int py   = bx >> 1;            // image row of this 32-px tile
    const int px32 = (bx & 1) * 32;      // px base within the row

    // theta (nt=1): store [p][cc]
    #pragma unroll
    for (int ct = 0; ct < 2; ++ct) {
        const int p = bx * 32 + ct * 16 + lm;
        #pragma unroll
        for (int reg = 0; reg < 4; ++reg) {
            const int r = w * 16 + quad * 4 + reg;
            theta_bf[(b * 4096 + p) * 128 + r]      = f2bf(acc[1][0][ct][reg]);
            theta_bf[(b * 4096 + p) * 128 + r + 64] = f2bf(acc[1][1][ct][reg]);
        }
    }
    // phi (nt=0) and g (nt=2): channel-major padded planes
    #pragma unroll
    for (int ct = 0; ct < 2; ++ct) {
        const int pxx = px32 + ct * 16 + lm;
        const int pbase = (py + 3) * 72 + pxx + 4;
        #pragma unroll
        for (int reg = 0; reg < 4; ++reg) {
            const int r = w * 16 + quad * 4 + reg;
            A_phi[b * A_BATCH + r * PLANE + pbase]        = f2bf(acc[0][0][ct][reg]);
            A_phi[b * A_BATCH + (r + 64) * PLANE + pbase] = f2bf(acc[0][1][ct][reg]);
            A_g[b * A_BATCH + r * PLANE + pbase]          = f2bf(acc[2][0][ct][reg]);
            A_g[b * A_BATCH + (r + 64) * PLANE + pbase]   = f2bf(acc[2][1][ct][reg]);
        }
    }
}

// ---------------------------------------------------------------------------
// scores: wave per pixel s, lane = t. 3 pure + 2 mixed cc-segments over
// padded phi planes. scores fp32 slots [b][s][64] (first 49 used).
// ---------------------------------------------------------------------------
__global__ __launch_bounds__(256) void scores_kernel(
    const unsigned short* __restrict__ Apad,
    const unsigned short* __restrict__ theta_bf,
    float* __restrict__ scores)
{
    const int w  = threadIdx.x >> 6;
    const int ln = threadIdx.x & 63;
    const int s  = blockIdx.x * 4 + w;
    const int b  = blockIdx.y;

    __shared__ float th[4][128];
    {
        const unsigned short* tb = theta_bf + (b * 4096 + s) * 128;
        th[w][ln]      = bf2f(tb[ln]);
        th[w][ln + 64] = bf2f(tb[ln + 64]);
    }
    __syncthreads();

    const unsigned short* __restrict__ Ab = Apad + b * A_BATCH;

    const int base  = s * 6272;
    const int ch_lo = base >> 12;
    const unsigned B1 = (unsigned)(ch_lo + 1) << 12;
    const unsigned B2 = (unsigned)(ch_lo + 2) << 12;
    const int d1 = (int)B1 - base;
    const int d2 = d1 + 4096;

    int A1 = d1 / 49;
    int A2 = (d1 + 48) / 49;
    int C1 = d2 / 49;        if (C1 > 128) C1 = 128;
    int C2 = (d2 + 48) / 49; if (C2 > 128) C2 = 128;

    unsigned OFFv[3];
    #pragma unroll
    for (int i = 0; i < 3; ++i) {
        int ch = ch_lo + i;
        int c0 = ch / 49; if (c0 > 127) c0 = 127;
        int rr = ch - c0 * 49;
        int kh = rr / 7;
        int kw = rr - kh * 7;
        OFFv[i] = (unsigned)(c0 * PLANE + kh * 72 + kw + 1);
    }

    unsigned F = (unsigned)(base + ln);
    float acc = 0.f;

    {
        const unsigned OFF_ = OFFv[0];
        #pragma unroll 4
        for (int cc = 0; cc < A1; ++cc) {
            unsigned p = F & 4095u;
            unsigned a = OFF_ + p + ((p >> 6) << 3);
            acc = fmaf(th[w][cc], bf2f(Ab[a]), acc);
            F += 49u;
        }
    }
    for (int cc = A1; cc < A2; ++cc) {
        unsigned OFF_ = (F >= B1) ? OFFv[1] : OFFv[0];
        unsigned p = F & 4095u;
        unsigned a = OFF_ + p + ((p >> 6) << 3);
        acc = fmaf(th[w][cc], bf2f(Ab[a]), acc);
        F += 49u;
    }
    {
        const unsigned OFF_ = OFFv[1];
        #pragma unroll 4
        for (int cc = A2; cc < C1; ++cc) {
            unsigned p = F & 4095u;
            unsigned a = OFF_ + p + ((p >> 6) << 3);
            acc = fmaf(th[w][cc], bf2f(Ab[a]), acc);
            F += 49u;
        }
    }
    for (int cc = C1; cc < C2; ++cc) {
        unsigned OFF_ = (F >= B2) ? OFFv[2] : OFFv[1];
        unsigned p = F & 4095u;
        unsigned a = OFF_ + p + ((p >> 6) << 3);
        acc = fmaf(th[w][cc], bf2f(Ab[a]), acc);
        F += 49u;
    }
    {
        const unsigned OFF_ = OFFv[2];
        #pragma unroll 4
        for (int cc = C2; cc < 128; ++cc) {
            unsigned p = F & 4095u;
            unsigned a = OFF_ + p + ((p >> 6) << 3);
            acc = fmaf(th[w][cc], bf2f(Ab[a]), acc);
            F += 49u;
        }
    }

    if (ln < 49) scores[(b * 4096 + s) * 64 + ln] = acc;
}

// ---------------------------------------------------------------------------
// softmax_stats: per (b,j,t) compute m = max_i sc, inv = 1/sum_i exp(sc-m).
// Block per (b,j); LDS tile 64(i) x 49(t). No normalize write-back.
// ---------------------------------------------------------------------------
__global__ __launch_bounds__(256) void softmax_stats_kernel(
    const float* __restrict__ scores,
    float* __restrict__ m_arr,
    float* __restrict__ inv_arr)
{
    const int b = blockIdx.x >> 6;
    const int j = blockIdx.x & 63;
    const int tid = threadIdx.x;
    const int wv = tid >> 6;
    const int ln = tid & 63;

    __shared__ float tile[64][52];

    #pragma unroll
    for (int it = 0; it < 16; ++it) {
        int i = it * 4 + wv;
        if (ln < 49) tile[i][ln] = scores[(b * 4096 + i * 64 + j) * 64 + ln];
    }
    __syncthreads();

    if (tid < 49) {
        float m = -3.4e38f;
        #pragma unroll 8
        for (int i = 0; i < 64; ++i) m = fmaxf(m, tile[i][tid]);
        float sum = 0.f;
        #pragma unroll 8
        for (int i = 0; i < 64; ++i) sum += __expf(tile[i][tid] - m);
        m_arr[(b * 64 + j) * 49 + tid]   = m;
        inv_arr[(b * 64 + j) * 49 + tid] = 1.f / sum;
    }
}

// ---------------------------------------------------------------------------
// aggregate: 2 pixels/block, lane = cc (128). attn computed inline:
// attn[t] = exp(sc[t]-m[j][t]) * inv[j][t]  (bit-identical to r11 path).
// Segment trick over t; y stored packed.
// ---------------------------------------------------------------------------
__global__ __launch_bounds__(256) void aggregate_kernel(
    const float* __restrict__ scores,
    const float* __restrict__ m_arr,
    const float* __restrict__ inv_arr,
    const unsigned short* __restrict__ Apad,
    unsigned short* __restrict__ y_p)
{
    const int pix = threadIdx.x >> 7;
    const int cc  = threadIdx.x & 127;
    const int s   = blockIdx.x * 2 + pix;
    const int b   = blockIdx.y;

    __shared__ float at[2][52];
    if (cc < 49) {
        const int j = s & 63;
        float sc = scores[(b * 4096 + s) * 64 + cc];
        float m  = m_arr[(b * 64 + j) * 49 + cc];
        float iv = inv_arr[(b * 64 + j) * 49 + cc];
        at[pix][cc] = __expf(sc - m) * iv;
    }
    __syncthreads();

    const unsigned short* __restrict__ Ab = Apad + b * A_BATCH;

    const int base  = s * 6272;
    const int ch_lo = base >> 12;
    const unsigned B1 = (unsigned)(ch_lo + 1) << 12;
    const unsigned B2 = (unsigned)(ch_lo + 2) << 12;
    const int d1 = (int)B1 - base;
    const int d2 = d1 + 4096;

    int A1 = d1 >> 7;
    int A2 = (d1 + 127) >> 7;
    int C1 = d2 >> 7;          if (C1 > 49) C1 = 49;
    int C2 = (d2 + 127) >> 7;  if (C2 > 49) C2 = 49;
    if (A1 > 49) A1 = 49;
    if (A2 > 49) A2 = 49;

    unsigned OFFv[3];
    #pragma unroll
    for (int i = 0; i < 3; ++i) {
        int ch = ch_lo + i;
        int c0 = ch / 49; if (c0 > 127) c0 = 127;
        int rr = ch - c0 * 49;
        int kh = rr / 7;
        int kw = rr - kh * 7;
        OFFv[i] = (unsigned)(c0 * PLANE + kh * 72 + kw + 1);
    }

    unsigned F = (unsigned)(base + cc);
    float acc = 0.f;

    {
        const unsigned OFF_ = OFFv[0];
        #pragma unroll 4
        for (int t = 0; t < A1; ++t) {
            unsigned p = F & 4095u;
            unsigned a = OFF_ + p + ((p >> 6) << 3);
            acc = fmaf(at[pix][t], bf2f(Ab[a]), acc);
            F += 128u;
        }
    }
    for (int t = A1; t < A2; ++t) {
        unsigned OFF_ = (F >= B1) ? OFFv[1] : OFFv[0];
        unsigned p = F & 4095u;
        unsigned a = OFF_ + p + ((p >> 6) << 3);
        acc = fmaf(at[pix][t], bf2f(Ab[a]), acc);
        F += 128u;
    }
    {
        const unsigned OFF_ = OFFv[1];
        #pragma unroll 4
        for (int t = A2; t < C1; ++t) {
            unsigned p = F & 4095u;
            unsigned a = OFF_ + p + ((p >> 6) << 3);
            acc = fmaf(at[pix][t], bf2f(Ab[a]), acc);
            F += 128u;
        }
    }
    for (int t = C1; t < C2; ++t) {
        unsigned OFF_ = (F >= B2) ? OFFv[2] : OFFv[1];
        unsigned p = F & 4095u;
        unsigned a = OFF_ + p + ((p >> 6) << 3);
        acc = fmaf(at[pix][t], bf2f(Ab[a]), acc);
        F += 128u;
    }
    {
        const unsigned OFF_ = OFFv[2];
        for (int t = C2; t < 49; ++t) {
            unsigned p = F & 4095u;
            unsigned a = OFF_ + p + ((p >> 6) << 3);
            acc = fmaf(at[pix][t], bf2f(Ab[a]), acc);
            F += 128u;
        }
    }

    // packed store
    const int kb = cc >> 5, k32 = cc & 31;
    const int quad = k32 >> 3, j = k32 & 7;
    const int pt16 = s >> 4, n = s & 15;
    y_p[((b * 4 + kb) * 256 + pt16) * 512 + (quad * 16 + n) * 8 + j] = f2bf(acc);
}

// ---------------------------------------------------------------------------
// maskconv_mfma: out[b,o,p] = x[b,o,p] + sum_cc wm[o,cc] y[p,cc].
// 2 o-tiles per wave (ot covers 128 rows), wm split hi/lo, K=128.
// ---------------------------------------------------------------------------
__global__ __launch_bounds__(256) void maskconv_mfma_kernel(
    const float* __restrict__ x,
    const unsigned short* __restrict__ wmp_hi,
    const unsigned short* __restrict__ wmp_lo,
    const unsigned short* __restrict__ y_p,
    float* __restrict__ out)
{
    const int tid = threadIdx.x;
    const int w   = tid >> 6;
    const int ln  = tid & 63;
    const int lm  = ln & 15;
    const int quad = ln >> 4;
    const int bx = blockIdx.x;   // px 64-tile
    const int ot = blockIdx.y;   // 0..1 (128 o-rows each)
    const int b  = blockIdx.z;
    const int ot16a = ot * 8 + w;
    const int ot16b = ot * 8 + 4 + w;
    const int lnofs = ln * 8;

    floatx4 accA[4] = {{0.f,0.f,0.f,0.f},{0.f,0.f,0.f,0.f},
                       {0.f,0.f,0.f,0.f},{0.f,0.f,0.f,0.f}};
    floatx4 accB[4] = {{0.f,0.f,0.f,0.f},{0.f,0.f,0.f,0.f},
                       {0.f,0.f,0.f,0.f},{0.f,0.f,0.f,0.f}};

    #pragma unroll
    for (int kb = 0; kb < 4; ++kb) {
        const int aoffA = (ot16a * 4 + kb) * 512 + lnofs;
        const int aoffB = (ot16b * 4 + kb) * 512 + lnofs;
        const int boff  = ((b * 4 + kb) * 256 + bx * 4) * 512 + lnofs;
        short8 ahA = *reinterpret_cast<const short8*>(wmp_hi + aoffA);
        short8 alA = *reinterpret_cast<const short8*>(wmp_lo + aoffA);
        short8 ahB = *reinterpret_cast<const short8*>(wmp_hi + aoffB);
        short8 alB = *reinterpret_cast<const short8*>(wmp_lo + aoffB);
        short8 bf[4];
        #pragma unroll
        for (int ct = 0; ct < 4; ++ct)
            bf[ct] = *reinterpret_cast<const short8*>(y_p + boff + ct * 512);
        #pragma unroll
        for (int ct = 0; ct < 4; ++ct) {
            accA[ct] = __builtin_amdgcn_mfma_f32_16x16x32_bf16(ahA, bf[ct], accA[ct], 0, 0, 0);
            accA[ct] = __builtin_amdgcn_mfma_f32_16x16x32_bf16(alA, bf[ct], accA[ct], 0, 0, 0);
            accB[ct] = __builtin_amdgcn_mfma_f32_16x16x32_bf16(ahB, bf[ct], accB[ct], 0, 0, 0);
            accB[ct] = __builtin_amdgcn_mfma_f32_16x16x32_bf16(alB, bf[ct], accB[ct], 0, 0, 0);
        }
    }

    #pragma unroll
    for (int ct = 0; ct < 4; ++ct) {
        const int p = bx * 64 + ct * 16 + lm;
        #pragma unroll
        for (int reg = 0; reg < 4; ++reg) {
            const int oA = ot * 128 + w * 16 + quad * 4 + reg;
            const int ofsA = (b * 256 + oA) * 4096 + p;
            out[ofsA] = accA[ct][reg] + x[ofsA];
            const int ofsB = ofsA + 64 * 4096;
            out[ofsB] = accB[ct][reg] + x[ofsB];
        }
    }
}

extern "C" void kernel_launch(void* const* d_in, const int* in_sizes, int n_in,
                              void* d_out, int out_size, void* d_ws, size_t ws_size,
                              hipStream_t stream) {
    const float* x       = (const float*)d_in[0];
    const float* w_phi   = (const float*)d_in[1];
    const float* w_theta = (const float*)d_in[2];
    const float* w_g     = (const float*)d_in[3];
    const float* w_mask  = (const float*)d_in[4];

    float* out_f = (float*)d_out;

    unsigned short* ws_u  = (unsigned short*)d_ws;
    unsigned short* A_phi = ws_u;                      // 2,580,480 ush
    unsigned short* A_g   = ws_u + 2580480;            // 2,580,480 ush
    unsigned short* y_p   = ws_u + 5160960;            // 2,097,152 ush (packed)
    unsigned short* th_u  = ws_u + 7258112;            // 2,097,152 ush
    float*          sc_f  = (float*)(ws_u + 9355264);  // 1,048,576 fp32
    unsigned short* xph   = ws_u + 11452416;           // 4,194,304 ush
    unsigned short* xpl   = ws_u + 15646720;           // 4,194,304 ush
    unsigned short* w3ph  = ws_u + 19841024;           // 98,304 ush
    unsigned short* w3pl  = ws_u + 19939328;           // 98,304 ush
    unsigned short* wmph  = ws_u + 20037632;           // 32,768 ush
    unsigned short* wmpl  = ws_u + 20070400;           // 32,768 ush
    float*          m_f   = (float*)(ws_u + 20103168); // 12,544 fp32
    float*          inv_f = (float*)(ws_u + 20128256); // 12,544 fp32

    // 1: prep (packed operand build + zero planes)
    hipLaunchKernelGGL(prep_kernel, dim3(1152), dim3(256), 0, stream,
                       x, w_phi, w_theta, w_g, w_mask,
                       xph, xpl, w3ph, w3pl, wmph, wmpl, (uint4*)A_phi);
    // 2: conv3 via packed split-bf16 MFMA (ALL regions per block, xp read 1x)
    hipLaunchKernelGGL(conv3_mfma_kernel, dim3(128, 4), dim3(256), 0, stream,
                       xph, xpl, w3ph, w3pl, A_phi, th_u, A_g);
    // 3: scores (segmented flat-decode gather)
    hipLaunchKernelGGL(scores_kernel, dim3(1024, 4), dim3(256), 0, stream,
                       A_phi, th_u, sc_f);
    // 4: softmax stats (m, inv) only
    hipLaunchKernelGGL(softmax_stats_kernel, dim3(256), dim3(256), 0, stream,
                       sc_f, m_f, inv_f);
    // 5: aggregate (attn inline) -> y packed
    hipLaunchKernelGGL(aggregate_kernel, dim3(2048, 4), dim3(256), 0, stream,
                       sc_f, m_f, inv_f, A_g, y_p);
    // 6: maskconv via packed split-w MFMA + residual -> out
    hipLaunchKernelGGL(maskconv_mfma_kernel, dim3(64, 2, 4), dim3(256), 0, stream,
                       x, wmph, wmpl, y_p, out_f);
}

// Round 3
// 174.295 us; speedup vs baseline: 1.0498x; 1.0498x over previous
//
#include <hip/hip_runtime.h>

// Problem: b=4, c=256, ci=128, h=w=64 (HW=4096), field=7, kk=49. fp32 I/O.
//
// 5-dispatch pipeline; MFMA GEMMs (split-bf16 hi+lo) with operands PACKED in
// MFMA-fragment order (fragment = 512 ushorts; lane ln reads 16 B at
// frag_base + ln*16). A-frag elem[ln*8+j] = W[row=ln&15][k=(ln>>4)*8+j];
// B-frag elem[ln*8+j] = M[k=(ln>>4)*8+j][col=ln&15]; C/D col=lane&15,
// row=quad*4+reg (all r10/r11-verified).
//  1. prep: x -> xp_hi/lo packed; w3 -> w3p_hi/lo; wm -> wmp_hi/lo; zero planes.
//  2. conv3_mfma: one region (phi/theta/g) per block (r0-verified structure),
//     2 A-tiles/wave (24 MFMAs : 12 loads per kb). phi/g -> padded planes,
//     theta -> [p][cc].
//  3. scores: segmented flat-decode gather (verified r6-11).
//  4. softmax_stats: per (b,j,t): m and inv=1/sum only (no normalize pass).
//  5. agg_mask (FUSED aggregate+maskconv): 32 px/block, 512 thr.
//     Phase A: attn = exp(sc-m)*inv -> LDS (same math as r11 aggregate).
//     Phase B: segmented gather over g planes, same per-thread t-order ->
//              bit-identical y bf16; y packed into LDS in MFMA B-frag order.
//     Phase C: maskconv MFMA from LDS y (same per-acc kb/hi/lo order as the
//              verified maskconv) + x residual -> out fp32.
//
// Padded planes: [b][c0][70][72] bf16, data (py,px) at (py+3,px+4), zero
// borders; patch addr for F -> (ch=F>>12, p=F&4095):
//   a = OFF(ch) + p + 8*(p>>6), OFF(ch) = c0*5040 + kh*72 + kw + 1.
// Per-pixel F-range < 2*4096 -> <=3 ch values -> 3 pure + 2 mixed segments.
//
// ws layout (ushort units):
//   A_phi  @ 0          (2,580,480)
//   A_g    @ 2,580,480  (2,580,480)   (zeroed contiguously with A_phi)
//   y_p    @ 5,160,960  (2,097,152)   (unused after fuse; kept for layout)
//   theta  @ 7,258,112  (2,097,152)
//   scores @ 9,355,264  (2,097,152 ush = 1,048,576 fp32)
//   xp_hi  @ 11,452,416 (4,194,304)
//   xp_lo  @ 15,646,720 (4,194,304)
//   w3p_hi @ 19,841,024 (98,304)
//   w3p_lo @ 19,939,328 (98,304)
//   wmp_hi @ 20,037,632 (32,768)
//   wmp_lo @ 20,070,400 (32,768)
//   m_arr  @ 20,103,168 (25,088 ush = 12,544 fp32)
//   inv    @ 20,128,256 (25,088 ush = 12,544 fp32)   => ~40.3 MB total

#define PLANE    5040
#define A_BATCH  645120

typedef __attribute__((ext_vector_type(8))) short short8;
typedef __attribute__((ext_vector_type(4))) float floatx4;

__device__ __forceinline__ float bf2f(unsigned short u) {
    union { unsigned int i; float f; } v; v.i = ((unsigned int)u) << 16; return v.f;
}
__device__ __forceinline__ unsigned short f2bf(float f) {
    union { float f; unsigned int i; } v; v.f = f;
    unsigned int r = v.i + 0x7FFFu + ((v.i >> 16) & 1u);
    return (unsigned short)(r >> 16);
}

// ---------------------------------------------------------------------------
// prep: blocks [0,1024): x fp32 [b][k][p] -> packed hi/lo fragments.
// blocks [1024,1152): w3p/wmp hi/lo packed casts + zero plane regions.
// ---------------------------------------------------------------------------
__global__ __launch_bounds__(256) void prep_kernel(
    const float* __restrict__ x,
    const float* __restrict__ w_phi,
    const float* __restrict__ w_theta,
    const float* __restrict__ w_g,
    const float* __restrict__ w_mask,
    unsigned short* __restrict__ xp_hi,
    unsigned short* __restrict__ xp_lo,
    unsigned short* __restrict__ w3p_hi,
    unsigned short* __restrict__ w3p_lo,
    unsigned short* __restrict__ wmp_hi,
    unsigned short* __restrict__ wmp_lo,
    uint4* __restrict__ zero_region)
{
    const int tid = threadIdx.x;
    const int bx = blockIdx.x;

    if (bx < 1024) {
        const int b  = bx >> 8;          // batch
        const int kt = (bx >> 6) & 3;    // k 64-tile
        const int pt = bx & 63;          // p 64-tile
        __shared__ float tile[64][65];   // [k][p]
        #pragma unroll
        for (int i = 0; i < 16; ++i) {
            int lin = tid + i * 256;
            int kk = lin >> 6, pp = lin & 63;
            tile[kk][pp] = x[(b * 256 + kt * 64 + kk) * 4096 + pt * 64 + pp];
        }
        __syncthreads();
        #pragma unroll
        for (int i = 0; i < 16; ++i) {
            int lin = tid + i * 256;
            int frag = lin >> 9;          // 0..7
            int idx  = lin & 511;
            int kbL  = frag >> 2;         // 0..1
            int ptL  = frag & 3;          // 0..3
            int j    = idx & 7;
            int n    = (idx >> 3) & 15;
            int quad = idx >> 7;
            float f = tile[kbL * 32 + quad * 8 + j][ptL * 16 + n];
            unsigned short h = f2bf(f);
            int addr = ((b * 8 + kt * 2 + kbL) * 256 + pt * 4 + ptL) * 512 + idx;
            xp_hi[addr] = h;
            xp_lo[addr] = f2bf(f - bf2f(h));
        }
    } else {
        const int wid = (bx - 1024) * 256 + tid;   // 0..32767
        for (int e = wid; e < 98304; e += 32768) {
            int frag = e >> 9;            // 0..191
            int idx  = e & 511;
            int nt16 = frag >> 3, kb = frag & 7;
            int j = idx & 7, m = (idx >> 3) & 15, quad = idx >> 7;
            int n = nt16 * 16 + m;
            int k = kb * 32 + quad * 8 + j;
            float v = (n < 128) ? w_phi[n * 256 + k]
                    : (n < 256) ? w_theta[(n - 128) * 256 + k]
                                : w_g[(n - 256) * 256 + k];
            unsigned short h = f2bf(v);
            w3p_hi[e] = h;
            w3p_lo[e] = f2bf(v - bf2f(h));
        }
        {
            int e = wid;                  // exactly covers wmp
            int frag = e >> 9;            // 0..63
            int idx  = e & 511;
            int ot16 = frag >> 2, kb = frag & 3;
            int j = idx & 7, m = (idx >> 3) & 15, quad = idx >> 7;
            float v = w_mask[(ot16 * 16 + m) * 128 + kb * 32 + quad * 8 + j];
            unsigned short h = f2bf(v);
            wmp_hi[e] = h;
            wmp_lo[e] = f2bf(v - bf2f(h));
        }
        const uint4 z = make_uint4(0u, 0u, 0u, 0u);
        for (int i = wid; i < 645120; i += 32768) zero_region[i] = z;
    }
}

// ---------------------------------------------------------------------------
// conv3_mfma: one REGION per block (nt: 0=phi 1=theta 2=g, 128 rows).
// Wave w handles region rows [w*16,+16) (tile a) and [64+w*16,+16) (tile b)
// over 64 px. 24 MFMAs : 12 fragment loads per kb. Split hi/lo.
// (r0-verified structure.)
// ---------------------------------------------------------------------------
__global__ __launch_bounds__(256) void conv3_mfma_kernel(
    const unsigned short* __restrict__ xp_hi,
    const unsigned short* __restrict__ xp_lo,
    const unsigned short* __restrict__ w3p_hi,
    const unsigned short* __restrict__ w3p_lo,
    unsigned short* __restrict__ A_phi,
    unsigned short* __restrict__ theta_bf,
    unsigned short* __restrict__ A_g)
{
    const int tid = threadIdx.x;
    const int w   = tid >> 6;
    const int ln  = tid & 63;
    const int lm  = ln & 15;
    const int quad = ln >> 4;
    const int bx = blockIdx.x;   // px 64-tile; py = bx
    const int nt = blockIdx.y;   // region 0..2
    const int b  = blockIdx.z;
    const int nt16a = nt * 8 + w;
    const int nt16b = nt * 8 + 4 + w;
    const int lnofs = ln * 8;

    floatx4 accA[4] = {{0.f,0.f,0.f,0.f},{0.f,0.f,0.f,0.f},
                       {0.f,0.f,0.f,0.f},{0.f,0.f,0.f,0.f}};
    floatx4 accB[4] = {{0.f,0.f,0.f,0.f},{0.f,0.f,0.f,0.f},
                       {0.f,0.f,0.f,0.f},{0.f,0.f,0.f,0.f}};

    #pragma unroll
    for (int kb = 0; kb < 8; ++kb) {
        const int aoffA = (nt16a * 8 + kb) * 512 + lnofs;
        const int aoffB = (nt16b * 8 + kb) * 512 + lnofs;
        const int boff  = ((b * 8 + kb) * 256 + bx * 4) * 512 + lnofs;
        short8 ahA = *reinterpret_cast<const short8*>(w3p_hi + aoffA);
        short8 alA = *reinterpret_cast<const short8*>(w3p_lo + aoffA);
        short8 ahB = *reinterpret_cast<const short8*>(w3p_hi + aoffB);
        short8 alB = *reinterpret_cast<const short8*>(w3p_lo + aoffB);
        short8 bh[4], bl[4];
        #pragma unroll
        for (int ct = 0; ct < 4; ++ct) {
            bh[ct] = *reinterpret_cast<const short8*>(xp_hi + boff + ct * 512);
            bl[ct] = *reinterpret_cast<const short8*>(xp_lo + boff + ct * 512);
        }
        #pragma unroll
        for (int ct = 0; ct < 4; ++ct) {
            accA[ct] = __builtin_amdgcn_mfma_f32_16x16x32_bf16(ahA, bh[ct], accA[ct], 0, 0, 0);
            accA[ct] = __builtin_amdgcn_mfma_f32_16x16x32_bf16(ahA, bl[ct], accA[ct], 0, 0, 0);
            accA[ct] = __builtin_amdgcn_mfma_f32_16x16x32_bf16(alA, bh[ct], accA[ct], 0, 0, 0);
            accB[ct] = __builtin_amdgcn_mfma_f32_16x16x32_bf16(ahB, bh[ct], accB[ct], 0, 0, 0);
            accB[ct] = __builtin_amdgcn_mfma_f32_16x16x32_bf16(ahB, bl[ct], accB[ct], 0, 0, 0);
            accB[ct] = __builtin_amdgcn_mfma_f32_16x16x32_bf16(alB, bh[ct], accB[ct], 0, 0, 0);
        }
    }

    const int py = bx;
    if (nt == 1) {
        // theta: cc = region row, store theta_bf[(b*4096+p)*128 + cc]
        #pragma unroll
        for (int ct = 0; ct < 4; ++ct) {
            const int p = bx * 64 + ct * 16 + lm;
            #pragma unroll
            for (int reg = 0; reg < 4; ++reg) {
                const int r = w * 16 + quad * 4 + reg;
                theta_bf[(b * 4096 + p) * 128 + r]      = f2bf(accA[ct][reg]);
                theta_bf[(b * 4096 + p) * 128 + r + 64] = f2bf(accB[ct][reg]);
            }
        }
    } else {
        unsigned short* __restrict__ A = (nt == 0) ? A_phi : A_g;
        #pragma unroll
        for (int ct = 0; ct < 4; ++ct) {
            const int pxx = ct * 16 + lm;
            #pragma unroll
            for (int reg = 0; reg < 4; ++reg) {
                const int r = w * 16 + quad * 4 + reg;
                A[b * A_BATCH + r * PLANE + (py + 3) * 72 + pxx + 4] =
                    f2bf(accA[ct][reg]);
                A[b * A_BATCH + (r + 64) * PLANE + (py + 3) * 72 + pxx + 4] =
                    f2bf(accB[ct][reg]);
            }
        }
    }
}

// ---------------------------------------------------------------------------
// scores: wave per pixel s, lane = t. 3 pure + 2 mixed cc-segments over
// padded phi planes. scores fp32 slots [b][s][64] (first 49 used).
// ---------------------------------------------------------------------------
__global__ __launch_bounds__(256) void scores_kernel(
    const unsigned short* __restrict__ Apad,
    const unsigned short* __restrict__ theta_bf,
    float* __restrict__ scores)
{
    const int w  = threadIdx.x >> 6;
    const int ln = threadIdx.x & 63;
    const int s  = blockIdx.x * 4 + w;
    const int b  = blockIdx.y;

    __shared__ float th[4][128];
    {
        const unsigned short* tb = theta_bf + (b * 4096 + s) * 128;
        th[w][ln]      = bf2f(tb[ln]);
        th[w][ln + 64] = bf2f(tb[ln + 64]);
    }
    __syncthreads();

    const unsigned short* __restrict__ Ab = Apad + b * A_BATCH;

    const int base  = s * 6272;
    const int ch_lo = base >> 12;
    const unsigned B1 = (unsigned)(ch_lo + 1) << 12;
    const unsigned B2 = (unsigned)(ch_lo + 2) << 12;
    const int d1 = (int)B1 - base;
    const int d2 = d1 + 4096;

    int A1 = d1 / 49;
    int A2 = (d1 + 48) / 49;
    int C1 = d2 / 49;        if (C1 > 128) C1 = 128;
    int C2 = (d2 + 48) / 49; if (C2 > 128) C2 = 128;

    unsigned OFFv[3];
    #pragma unroll
    for (int i = 0; i < 3; ++i) {
        int ch = ch_lo + i;
        int c0 = ch / 49; if (c0 > 127) c0 = 127;
        int rr = ch - c0 * 49;
        int kh = rr / 7;
        int kw = rr - kh * 7;
        OFFv[i] = (unsigned)(c0 * PLANE + kh * 72 + kw + 1);
    }

    unsigned F = (unsigned)(base + ln);
    float acc = 0.f;

    {
        const unsigned OFF_ = OFFv[0];
        #pragma unroll 4
        for (int cc = 0; cc < A1; ++cc) {
            unsigned p = F & 4095u;
            unsigned a = OFF_ + p + ((p >> 6) << 3);
            acc = fmaf(th[w][cc], bf2f(Ab[a]), acc);
            F += 49u;
        }
    }
    for (int cc = A1; cc < A2; ++cc) {
        unsigned OFF_ = (F >= B1) ? OFFv[1] : OFFv[0];
        unsigned p = F & 4095u;
        unsigned a = OFF_ + p + ((p >> 6) << 3);
        acc = fmaf(th[w][cc], bf2f(Ab[a]), acc);
        F += 49u;
    }
    {
        const unsigned OFF_ = OFFv[1];
        #pragma unroll 4
        for (int cc = A2; cc < C1; ++cc) {
            unsigned p = F & 4095u;
            unsigned a = OFF_ + p + ((p >> 6) << 3);
            acc = fmaf(th[w][cc], bf2f(Ab[a]), acc);
            F += 49u;
        }
    }
    for (int cc = C1; cc < C2; ++cc) {
        unsigned OFF_ = (F >= B2) ? OFFv[2] : OFFv[1];
        unsigned p = F & 4095u;
        unsigned a = OFF_ + p + ((p >> 6) << 3);
        acc = fmaf(th[w][cc], bf2f(Ab[a]), acc);
        F += 49u;
    }
    {
        const unsigned OFF_ = OFFv[2];
        #pragma unroll 4
        for (int cc = C2; cc < 128; ++cc) {
            unsigned p = F & 4095u;
            unsigned a = OFF_ + p + ((p >> 6) << 3);
            acc = fmaf(th[w][cc], bf2f(Ab[a]), acc);
            F += 49u;
        }
    }

    if (ln < 49) scores[(b * 4096 + s) * 64 + ln] = acc;
}

// ---------------------------------------------------------------------------
// softmax_stats: per (b,j,t) compute m = max_i sc, inv = 1/sum_i exp(sc-m).
// Block per (b,j); LDS tile 64(i) x 49(t). No normalize write-back.
// ---------------------------------------------------------------------------
__global__ __launch_bounds__(256) void softmax_stats_kernel(
    const float* __restrict__ scores,
    float* __restrict__ m_arr,
    float* __restrict__ inv_arr)
{
    const int b = blockIdx.x >> 6;
    const int j = blockIdx.x & 63;
    const int tid = threadIdx.x;
    const int wv = tid >> 6;
    const int ln = tid & 63;

    __shared__ float tile[64][52];

    #pragma unroll
    for (int it = 0; it < 16; ++it) {
        int i = it * 4 + wv;
        if (ln < 49) tile[i][ln] = scores[(b * 4096 + i * 64 + j) * 64 + ln];
    }
    __syncthreads();

    if (tid < 49) {
        float m = -3.4e38f;
        #pragma unroll 8
        for (int i = 0; i < 64; ++i) m = fmaxf(m, tile[i][tid]);
        float sum = 0.f;
        #pragma unroll 8
        for (int i = 0; i < 64; ++i) sum += __expf(tile[i][tid] - m);
        m_arr[(b * 64 + j) * 49 + tid]   = m;
        inv_arr[(b * 64 + j) * 49 + tid] = 1.f / sum;
    }
}

// ---------------------------------------------------------------------------
// agg_mask (FUSED): 32 pixels/block, 512 threads, grid (128, 4).
// Phase A: at_l[lp][t] = exp(sc-m)*inv (same math as verified aggregate).
// Phase B: thread (pq=tid>>7, cc=tid&127), reps lp = rep*4+pq: segmented
//   gather over g planes, t=0..48 sequential per (px,cc) -> bit-identical y;
//   y bf16 packed into LDS B-frag order (kb*2+ct)*512 + (quad*16+n)*8 + j.
// Phase C: maskconv MFMA: wave w: o-tiles ot16 = w and w+8; per kb: A-frags
//   from wmp_hi/lo, B-frag ds_read; per-acc order kb asc, ah then al (same
//   as verified maskconv) + x residual -> out.
// ---------------------------------------------------------------------------
__global__ __launch_bounds__(512) void agg_mask_kernel(
    const float* __restrict__ scores,
    const float* __restrict__ m_arr,
    const float* __restrict__ inv_arr,
    const unsigned short* __restrict__ Apad,
    const unsigned short* __restrict__ wmp_hi,
    const unsigned short* __restrict__ wmp_lo,
    const float* __restrict__ x,
    float* __restrict__ out)
{
    const int tid = threadIdx.x;
    const int blk = blockIdx.x;          // 0..127: pixel tile of 32
    const int b   = blockIdx.y;
    const int P0  = blk * 32;            // global pixel base

    __shared__ float at_l[32][52];
    __shared__ unsigned short y_lds[8 * 512];   // 8 B-frags (4 kb x 2 ct)

    // ---- Phase A: attention weights ----
    const int j0 = P0 & 63;
    #pragma unroll
    for (int it = 0; it < 4; ++it) {
        int idx = tid + it * 512;        // 0..2047
        int lp = idx >> 6;               // 0..31
        int t  = idx & 63;
        if (t < 49) {
            const int s = P0 + lp;
            const int j = j0 + lp;
            float sc = scores[(b * 4096 + s) * 64 + t];
            float m  = m_arr[(b * 64 + j) * 49 + t];
            float iv = inv_arr[(b * 64 + j) * 49 + t];
            at_l[lp][t] = __expf(sc - m) * iv;
        }
    }
    __syncthreads();

    // ---- Phase B: gather y (bit-identical to verified aggregate) ----
    const unsigned short* __restrict__ Ab = Apad + b * A_BATCH;
    const int pq = tid >> 7;             // 0..3
    const int cc = tid & 127;

    #pragma unroll
    for (int rep = 0; rep < 8; ++rep) {
        const int lp = rep * 4 + pq;     // 0..31
        const int s  = P0 + lp;

        const int base  = s * 6272;
        const int ch_lo = base >> 12;
        const unsigned B1 = (unsigned)(ch_lo + 1) << 12;
        const unsigned B2 = (unsigned)(ch_lo + 2) << 12;
        const int d1 = (int)B1 - base;
        const int d2 = d1 + 4096;

        int A1 = d1 >> 7;
        int A2 = (d1 + 127) >> 7;
        int C1 = d2 >> 7;          if (C1 > 49) C1 = 49;
        int C2 = (d2 + 127) >> 7;  if (C2 > 49) C2 = 49;
        if (A1 > 49) A1 = 49;
        if (A2 > 49) A2 = 49;

        unsigned OFFv[3];
        #pragma unroll
        for (int i = 0; i < 3; ++i) {
            int ch = ch_lo + i;
            int c0 = ch / 49; if (c0 > 127) c0 = 127;
            int rr = ch - c0 * 49;
            int kh = rr / 7;
            int kw = rr - kh * 7;
            OFFv[i] = (unsigned)(c0 * PLANE + kh * 72 + kw + 1);
        }

        unsigned F = (unsigned)(base + cc);
        float acc = 0.f;

        {
            const unsigned OFF_ = OFFv[0];
            #pragma unroll 4
            for (int t = 0; t < A1; ++t) {
                unsigned p = F & 4095u;
                unsigned a = OFF_ + p + ((p >> 6) << 3);
                acc = fmaf(at_l[lp][t], bf2f(Ab[a]), acc);
                F += 128u;
            }
        }
        for (int t = A1; t < A2; ++t) {
            unsigned OFF_ = (F >= B1) ? OFFv[1] : OFFv[0];
            unsigned p = F & 4095u;
            unsigned a = OFF_ + p + ((p >> 6) << 3);
            acc = fmaf(at_l[lp][t], bf2f(Ab[a]), acc);
            F += 128u;
        }
        {
            const unsigned OFF_ = OFFv[1];
            #pragma unroll 4
            for (int t = A2; t < C1; ++t) {
                unsigned p = F & 4095u;
                unsigned a = OFF_ + p + ((p >> 6) << 3);
                acc = fmaf(at_l[lp][t], bf2f(Ab[a]), acc);
                F += 128u;
            }
        }
        for (int t = C1; t < C2; ++t) {
            unsigned OFF_ = (F >= B2) ? OFFv[2] : OFFv[1];
            unsigned p = F & 4095u;
            unsigned a = OFF_ + p + ((p >> 6) << 3);
            acc = fmaf(at_l[lp][t], bf2f(Ab[a]), acc);
            F += 128u;
        }
        {
            const unsigned OFF_ = OFFv[2];
            for (int t = C2; t < 49; ++t) {
                unsigned p = F & 4095u;
                unsigned a = OFF_ + p + ((p >> 6) << 3);
                acc = fmaf(at_l[lp][t], bf2f(Ab[a]), acc);
                F += 128u;
            }
        }

        // pack into LDS B-frag order
        const int kb = cc >> 5, k32 = cc & 31;
        const int quad = k32 >> 3, jx = k32 & 7;
        const int ct = lp >> 4, n = lp & 15;
        y_lds[(kb * 2 + ct) * 512 + (quad * 16 + n) * 8 + jx] = f2bf(acc);
    }
    __syncthreads();

    // ---- Phase C: maskconv MFMA ----
    const int w    = tid >> 6;           // 0..7
    const int ln   = tid & 63;
    const int lm   = ln & 15;
    const int quad = ln >> 4;
    const int lnofs = ln * 8;
    const int ot16a = w;                 // o rows [w*16, +16)
    const int ot16b = w + 8;             // o rows [(w+8)*16, +16)

    floatx4 accA[2] = {{0.f,0.f,0.f,0.f},{0.f,0.f,0.f,0.f}};
    floatx4 accB[2] = {{0.f,0.f,0.f,0.f},{0.f,0.f,0.f,0.f}};

    #pragma unroll
    for (int kb = 0; kb < 4; ++kb) {
        const int aoffA = (ot16a * 4 + kb) * 512 + lnofs;
        const int aoffB = (ot16b * 4 + kb) * 512 + lnofs;
        short8 ahA = *reinterpret_cast<const short8*>(wmp_hi + aoffA);
        short8 alA = *reinterpret_cast<const short8*>(wmp_lo + aoffA);
        short8 ahB = *reinterpret_cast<const short8*>(wmp_hi + aoffB);
        short8 alB = *reinterpret_cast<const short8*>(wmp_lo + aoffB);
        short8 bf[2];
        #pragma unroll
        for (int ct = 0; ct < 2; ++ct)
            bf[ct] = *reinterpret_cast<const short8*>(
                y_lds + (kb * 2 + ct) * 512 + lnofs);
        #pragma unroll
        for (int ct = 0; ct < 2; ++ct) {
            accA[ct] = __builtin_amdgcn_mfma_f32_16x16x32_bf16(ahA, bf[ct], accA[ct], 0, 0, 0);
            accA[ct] = __builtin_amdgcn_mfma_f32_16x16x32_bf16(alA, bf[ct], accA[ct], 0, 0, 0);
            accB[ct] = __builtin_amdgcn_mfma_f32_16x16x32_bf16(ahB, bf[ct], accB[ct], 0, 0, 0);
            accB[ct] = __builtin_amdgcn_mfma_f32_16x16x32_bf16(alB, bf[ct], accB[ct], 0, 0, 0);
        }
    }

    #pragma unroll
    for (int ct = 0; ct < 2; ++ct) {
        const int p = P0 + ct * 16 + lm;
        #pragma unroll
        for (int reg = 0; reg < 4; ++reg) {
            const int oA = w * 16 + quad * 4 + reg;
            const int ofsA = (b * 256 + oA) * 4096 + p;
            out[ofsA] = accA[ct][reg] + x[ofsA];
            const int ofsB = ofsA + 128 * 4096;
            out[ofsB] = accB[ct][reg] + x[ofsB];
        }
    }
}

extern "C" void kernel_launch(void* const* d_in, const int* in_sizes, int n_in,
                              void* d_out, int out_size, void* d_ws, size_t ws_size,
                              hipStream_t stream) {
    const float* x       = (const float*)d_in[0];
    const float* w_phi   = (const float*)d_in[1];
    const float* w_theta = (const float*)d_in[2];
    const float* w_g     = (const float*)d_in[3];
    const float* w_mask  = (const float*)d_in[4];

    float* out_f = (float*)d_out;

    unsigned short* ws_u  = (unsigned short*)d_ws;
    unsigned short* A_phi = ws_u;                      // 2,580,480 ush
    unsigned short* A_g   = ws_u + 2580480;            // 2,580,480 ush
    unsigned short* th_u  = ws_u + 7258112;            // 2,097,152 ush
    float*          sc_f  = (float*)(ws_u + 9355264);  // 1,048,576 fp32
    unsigned short* xph   = ws_u + 11452416;           // 4,194,304 ush
    unsigned short* xpl   = ws_u + 15646720;           // 4,194,304 ush
    unsigned short* w3ph  = ws_u + 19841024;           // 98,304 ush
    unsigned short* w3pl  = ws_u + 19939328;           // 98,304 ush
    unsigned short* wmph  = ws_u + 20037632;           // 32,768 ush
    unsigned short* wmpl  = ws_u + 20070400;           // 32,768 ush
    float*          m_f   = (float*)(ws_u + 20103168); // 12,544 fp32
    float*          inv_f = (float*)(ws_u + 20128256); // 12,544 fp32

    // 1: prep (packed operand build + zero planes)
    hipLaunchKernelGGL(prep_kernel, dim3(1152), dim3(256), 0, stream,
                       x, w_phi, w_theta, w_g, w_mask,
                       xph, xpl, w3ph, w3pl, wmph, wmpl, (uint4*)A_phi);
    // 2: conv3 via packed split-bf16 MFMA (one region per block, r0 structure)
    hipLaunchKernelGGL(conv3_mfma_kernel, dim3(64, 3, 4), dim3(256), 0, stream,
                       xph, xpl, w3ph, w3pl, A_phi, th_u, A_g);
    // 3: scores (segmented flat-decode gather)
    hipLaunchKernelGGL(scores_kernel, dim3(1024, 4), dim3(256), 0, stream,
                       A_phi, th_u, sc_f);
    // 4: softmax stats (m, inv) only
    hipLaunchKernelGGL(softmax_stats_kernel, dim3(256), dim3(256), 0, stream,
                       sc_f, m_f, inv_f);
    // 5: fused aggregate + maskconv -> out
    hipLaunchKernelGGL(agg_mask_kernel, dim3(128, 4), dim3(512), 0, stream,
                       sc_f, m_f, inv_f, A_g, wmph, wmpl, x, out_f);
}

// Round 4
// 162.555 us; speedup vs baseline: 1.1256x; 1.0722x over previous
//
#include <hip/hip_runtime.h>

// Problem: b=4, c=256, ci=128, h=w=64 (HW=4096), field=7, kk=49. fp32 I/O.
//
// 5-dispatch pipeline; MFMA GEMMs (split-bf16 hi+lo) with operands PACKED in
// MFMA-fragment order (fragment = 512 ushorts; lane ln reads 16 B at
// frag_base + ln*16). A-frag elem[ln*8+j] = W[row=ln&15][k=(ln>>4)*8+j];
// B-frag elem[ln*8+j] = M[k=(ln>>4)*8+j][col=ln&15]; C/D col=lane&15,
// row=quad*4+reg (all r10/r11-verified).
//  1. prep: x -> xp_hi/lo packed; w3 -> w3p_hi/lo; wm -> wmp_hi/lo; zero planes.
//  2. conv3_mfma: one region (phi/theta/g) per block (r0-verified structure).
//  3. scores: segmented flat-decode gather (verified r6-11).
//  4. softmax_stats: per (b,j,t): m and inv=1/sum only.
//  5. agg_mask (FUSED aggregate+maskconv), ROUND-4 RESTRUCTURE:
//     1024 threads, 32 px/block, grid (128,4) -> 2 blocks/CU x 16 waves =
//     32 waves/CU possible (was 16). Gather reps 8 -> 4.
//     AFFINE pure segments: within a pure segment p += 128 (no 4096-wrap),
//     p>>6 += 2 exactly -> a += 144 per t. Decode once at segment entry;
//     addresses algebraically identical -> y bit-identical.
//
// Padded planes: [b][c0][70][72] bf16, data (py,px) at (py+3,px+4), zero
// borders; patch addr for F -> (ch=F>>12, p=F&4095):
//   a = OFF(ch) + p + 8*(p>>6), OFF(ch) = c0*5040 + kh*72 + kw + 1.
// Per-pixel F-range < 2*4096 -> <=3 ch values -> 3 pure + 2 mixed segments.
//
// ws layout (ushort units): unchanged from r3 (~40.3 MB total).

#define PLANE    5040
#define A_BATCH  645120

typedef __attribute__((ext_vector_type(8))) short short8;
typedef __attribute__((ext_vector_type(4))) float floatx4;

__device__ __forceinline__ float bf2f(unsigned short u) {
    union { unsigned int i; float f; } v; v.i = ((unsigned int)u) << 16; return v.f;
}
__device__ __forceinline__ unsigned short f2bf(float f) {
    union { float f; unsigned int i; } v; v.f = f;
    unsigned int r = v.i + 0x7FFFu + ((v.i >> 16) & 1u);
    return (unsigned short)(r >> 16);
}

// ---------------------------------------------------------------------------
// prep: blocks [0,1024): x fp32 [b][k][p] -> packed hi/lo fragments.
// blocks [1024,1152): w3p/wmp hi/lo packed casts + zero plane regions.
// ---------------------------------------------------------------------------
__global__ __launch_bounds__(256) void prep_kernel(
    const float* __restrict__ x,
    const float* __restrict__ w_phi,
    const float* __restrict__ w_theta,
    const float* __restrict__ w_g,
    const float* __restrict__ w_mask,
    unsigned short* __restrict__ xp_hi,
    unsigned short* __restrict__ xp_lo,
    unsigned short* __restrict__ w3p_hi,
    unsigned short* __restrict__ w3p_lo,
    unsigned short* __restrict__ wmp_hi,
    unsigned short* __restrict__ wmp_lo,
    uint4* __restrict__ zero_region)
{
    const int tid = threadIdx.x;
    const int bx = blockIdx.x;

    if (bx < 1024) {
        const int b  = bx >> 8;          // batch
        const int kt = (bx >> 6) & 3;    // k 64-tile
        const int pt = bx & 63;          // p 64-tile
        __shared__ float tile[64][65];   // [k][p]
        #pragma unroll
        for (int i = 0; i < 16; ++i) {
            int lin = tid + i * 256;
            int kk = lin >> 6, pp = lin & 63;
            tile[kk][pp] = x[(b * 256 + kt * 64 + kk) * 4096 + pt * 64 + pp];
        }
        __syncthreads();
        #pragma unroll
        for (int i = 0; i < 16; ++i) {
            int lin = tid + i * 256;
            int frag = lin >> 9;          // 0..7
            int idx  = lin & 511;
            int kbL  = frag >> 2;         // 0..1
            int ptL  = frag & 3;          // 0..3
            int j    = idx & 7;
            int n    = (idx >> 3) & 15;
            int quad = idx >> 7;
            float f = tile[kbL * 32 + quad * 8 + j][ptL * 16 + n];
            unsigned short h = f2bf(f);
            int addr = ((b * 8 + kt * 2 + kbL) * 256 + pt * 4 + ptL) * 512 + idx;
            xp_hi[addr] = h;
            xp_lo[addr] = f2bf(f - bf2f(h));
        }
    } else {
        const int wid = (bx - 1024) * 256 + tid;   // 0..32767
        for (int e = wid; e < 98304; e += 32768) {
            int frag = e >> 9;            // 0..191
            int idx  = e & 511;
            int nt16 = frag >> 3, kb = frag & 7;
            int j = idx & 7, m = (idx >> 3) & 15, quad = idx >> 7;
            int n = nt16 * 16 + m;
            int k = kb * 32 + quad * 8 + j;
            float v = (n < 128) ? w_phi[n * 256 + k]
                    : (n < 256) ? w_theta[(n - 128) * 256 + k]
                                : w_g[(n - 256) * 256 + k];
            unsigned short h = f2bf(v);
            w3p_hi[e] = h;
            w3p_lo[e] = f2bf(v - bf2f(h));
        }
        {
            int e = wid;                  // exactly covers wmp
            int frag = e >> 9;            // 0..63
            int idx  = e & 511;
            int ot16 = frag >> 2, kb = frag & 3;
            int j = idx & 7, m = (idx >> 3) & 15, quad = idx >> 7;
            float v = w_mask[(ot16 * 16 + m) * 128 + kb * 32 + quad * 8 + j];
            unsigned short h = f2bf(v);
            wmp_hi[e] = h;
            wmp_lo[e] = f2bf(v - bf2f(h));
        }
        const uint4 z = make_uint4(0u, 0u, 0u, 0u);
        for (int i = wid; i < 645120; i += 32768) zero_region[i] = z;
    }
}

// ---------------------------------------------------------------------------
// conv3_mfma: one REGION per block (nt: 0=phi 1=theta 2=g, 128 rows).
// Wave w handles region rows [w*16,+16) (tile a) and [64+w*16,+16) (tile b)
// over 64 px. 24 MFMAs : 12 fragment loads per kb. Split hi/lo.
// (r0-verified structure.)
// ---------------------------------------------------------------------------
__global__ __launch_bounds__(256) void conv3_mfma_kernel(
    const unsigned short* __restrict__ xp_hi,
    const unsigned short* __restrict__ xp_lo,
    const unsigned short* __restrict__ w3p_hi,
    const unsigned short* __restrict__ w3p_lo,
    unsigned short* __restrict__ A_phi,
    unsigned short* __restrict__ theta_bf,
    unsigned short* __restrict__ A_g)
{
    const int tid = threadIdx.x;
    const int w   = tid >> 6;
    const int ln  = tid & 63;
    const int lm  = ln & 15;
    const int quad = ln >> 4;
    const int bx = blockIdx.x;   // px 64-tile; py = bx
    const int nt = blockIdx.y;   // region 0..2
    const int b  = blockIdx.z;
    const int nt16a = nt * 8 + w;
    const int nt16b = nt * 8 + 4 + w;
    const int lnofs = ln * 8;

    floatx4 accA[4] = {{0.f,0.f,0.f,0.f},{0.f,0.f,0.f,0.f},
                       {0.f,0.f,0.f,0.f},{0.f,0.f,0.f,0.f}};
    floatx4 accB[4] = {{0.f,0.f,0.f,0.f},{0.f,0.f,0.f,0.f},
                       {0.f,0.f,0.f,0.f},{0.f,0.f,0.f,0.f}};

    #pragma unroll
    for (int kb = 0; kb < 8; ++kb) {
        const int aoffA = (nt16a * 8 + kb) * 512 + lnofs;
        const int aoffB = (nt16b * 8 + kb) * 512 + lnofs;
        const int boff  = ((b * 8 + kb) * 256 + bx * 4) * 512 + lnofs;
        short8 ahA = *reinterpret_cast<const short8*>(w3p_hi + aoffA);
        short8 alA = *reinterpret_cast<const short8*>(w3p_lo + aoffA);
        short8 ahB = *reinterpret_cast<const short8*>(w3p_hi + aoffB);
        short8 alB = *reinterpret_cast<const short8*>(w3p_lo + aoffB);
        short8 bh[4], bl[4];
        #pragma unroll
        for (int ct = 0; ct < 4; ++ct) {
            bh[ct] = *reinterpret_cast<const short8*>(xp_hi + boff + ct * 512);
            bl[ct] = *reinterpret_cast<const short8*>(xp_lo + boff + ct * 512);
        }
        #pragma unroll
        for (int ct = 0; ct < 4; ++ct) {
            accA[ct] = __builtin_amdgcn_mfma_f32_16x16x32_bf16(ahA, bh[ct], accA[ct], 0, 0, 0);
            accA[ct] = __builtin_amdgcn_mfma_f32_16x16x32_bf16(ahA, bl[ct], accA[ct], 0, 0, 0);
            accA[ct] = __builtin_amdgcn_mfma_f32_16x16x32_bf16(alA, bh[ct], accA[ct], 0, 0, 0);
            accB[ct] = __builtin_amdgcn_mfma_f32_16x16x32_bf16(ahB, bh[ct], accB[ct], 0, 0, 0);
            accB[ct] = __builtin_amdgcn_mfma_f32_16x16x32_bf16(ahB, bl[ct], accB[ct], 0, 0, 0);
            accB[ct] = __builtin_amdgcn_mfma_f32_16x16x32_bf16(alB, bh[ct], accB[ct], 0, 0, 0);
        }
    }

    const int py = bx;
    if (nt == 1) {
        // theta: cc = region row, store theta_bf[(b*4096+p)*128 + cc]
        #pragma unroll
        for (int ct = 0; ct < 4; ++ct) {
            const int p = bx * 64 + ct * 16 + lm;
            #pragma unroll
            for (int reg = 0; reg < 4; ++reg) {
                const int r = w * 16 + quad * 4 + reg;
                theta_bf[(b * 4096 + p) * 128 + r]      = f2bf(accA[ct][reg]);
                theta_bf[(b * 4096 + p) * 128 + r + 64] = f2bf(accB[ct][reg]);
            }
        }
    } else {
        unsigned short* __restrict__ A = (nt == 0) ? A_phi : A_g;
        #pragma unroll
        for (int ct = 0; ct < 4; ++ct) {
            const int pxx = ct * 16 + lm;
            #pragma unroll
            for (int reg = 0; reg < 4; ++reg) {
                const int r = w * 16 + quad * 4 + reg;
                A[b * A_BATCH + r * PLANE + (py + 3) * 72 + pxx + 4] =
                    f2bf(accA[ct][reg]);
                A[b * A_BATCH + (r + 64) * PLANE + (py + 3) * 72 + pxx + 4] =
                    f2bf(accB[ct][reg]);
            }
        }
    }
}

// ---------------------------------------------------------------------------
// scores: wave per pixel s, lane = t. 3 pure + 2 mixed cc-segments over
// padded phi planes. scores fp32 slots [b][s][64] (first 49 used).
// ---------------------------------------------------------------------------
__global__ __launch_bounds__(256) void scores_kernel(
    const unsigned short* __restrict__ Apad,
    const unsigned short* __restrict__ theta_bf,
    float* __restrict__ scores)
{
    const int w  = threadIdx.x >> 6;
    const int ln = threadIdx.x & 63;
    const int s  = blockIdx.x * 4 + w;
    const int b  = blockIdx.y;

    __shared__ float th[4][128];
    {
        const unsigned short* tb = theta_bf + (b * 4096 + s) * 128;
        th[w][ln]      = bf2f(tb[ln]);
        th[w][ln + 64] = bf2f(tb[ln + 64]);
    }
    __syncthreads();

    const unsigned short* __restrict__ Ab = Apad + b * A_BATCH;

    const int base  = s * 6272;
    const int ch_lo = base >> 12;
    const unsigned B1 = (unsigned)(ch_lo + 1) << 12;
    const unsigned B2 = (unsigned)(ch_lo + 2) << 12;
    const int d1 = (int)B1 - base;
    const int d2 = d1 + 4096;

    int A1 = d1 / 49;
    int A2 = (d1 + 48) / 49;
    int C1 = d2 / 49;        if (C1 > 128) C1 = 128;
    int C2 = (d2 + 48) / 49; if (C2 > 128) C2 = 128;

    unsigned OFFv[3];
    #pragma unroll
    for (int i = 0; i < 3; ++i) {
        int ch = ch_lo + i;
        int c0 = ch / 49; if (c0 > 127) c0 = 127;
        int rr = ch - c0 * 49;
        int kh = rr / 7;
        int kw = rr - kh * 7;
        OFFv[i] = (unsigned)(c0 * PLANE + kh * 72 + kw + 1);
    }

    unsigned F = (unsigned)(base + ln);
    float acc = 0.f;

    {
        const unsigned OFF_ = OFFv[0];
        #pragma unroll 4
        for (int cc = 0; cc < A1; ++cc) {
            unsigned p = F & 4095u;
            unsigned a = OFF_ + p + ((p >> 6) << 3);
            acc = fmaf(th[w][cc], bf2f(Ab[a]), acc);
            F += 49u;
        }
    }
    for (int cc = A1; cc < A2; ++cc) {
        unsigned OFF_ = (F >= B1) ? OFFv[1] : OFFv[0];
        unsigned p = F & 4095u;
        unsigned a = OFF_ + p + ((p >> 6) << 3);
        acc = fmaf(th[w][cc], bf2f(Ab[a]), acc);
        F += 49u;
    }
    {
        const unsigned OFF_ = OFFv[1];
        #pragma unroll 4
        for (int cc = A2; cc < C1; ++cc) {
            unsigned p = F & 4095u;
            unsigned a = OFF_ + p + ((p >> 6) << 3);
            acc = fmaf(th[w][cc], bf2f(Ab[a]), acc);
            F += 49u;
        }
    }
    for (int cc = C1; cc < C2; ++cc) {
        unsigned OFF_ = (F >= B2) ? OFFv[2] : OFFv[1];
        unsigned p = F & 4095u;
        unsigned a = OFF_ + p + ((p >> 6) << 3);
        acc = fmaf(th[w][cc], bf2f(Ab[a]), acc);
        F += 49u;
    }
    {
        const unsigned OFF_ = OFFv[2];
        #pragma unroll 4
        for (int cc = C2; cc < 128; ++cc) {
            unsigned p = F & 4095u;
            unsigned a = OFF_ + p + ((p >> 6) << 3);
            acc = fmaf(th[w][cc], bf2f(Ab[a]), acc);
            F += 49u;
        }
    }

    if (ln < 49) scores[(b * 4096 + s) * 64 + ln] = acc;
}

// ---------------------------------------------------------------------------
// softmax_stats: per (b,j,t) compute m = max_i sc, inv = 1/sum_i exp(sc-m).
// Block per (b,j); LDS tile 64(i) x 49(t). No normalize write-back.
// ---------------------------------------------------------------------------
__global__ __launch_bounds__(256) void softmax_stats_kernel(
    const float* __restrict__ scores,
    float* __restrict__ m_arr,
    float* __restrict__ inv_arr)
{
    const int b = blockIdx.x >> 6;
    const int j = blockIdx.x & 63;
    const int tid = threadIdx.x;
    const int wv = tid >> 6;
    const int ln = tid & 63;

    __shared__ float tile[64][52];

    #pragma unroll
    for (int it = 0; it < 16; ++it) {
        int i = it * 4 + wv;
        if (ln < 49) tile[i][ln] = scores[(b * 4096 + i * 64 + j) * 64 + ln];
    }
    __syncthreads();

    if (tid < 49) {
        float m = -3.4e38f;
        #pragma unroll 8
        for (int i = 0; i < 64; ++i) m = fmaxf(m, tile[i][tid]);
        float sum = 0.f;
        #pragma unroll 8
        for (int i = 0; i < 64; ++i) sum += __expf(tile[i][tid] - m);
        m_arr[(b * 64 + j) * 49 + tid]   = m;
        inv_arr[(b * 64 + j) * 49 + tid] = 1.f / sum;
    }
}

// ---------------------------------------------------------------------------
// agg_mask (FUSED, r4): 32 pixels/block, 1024 threads, grid (128, 4).
// 2 blocks/CU x 16 waves = 32 waves/CU possible (r3 was grid-capped at 16).
// Phase A: at_l[lp][t] = exp(sc-m)*inv (2 iters of 1024).
// Phase B: thread (pq=tid>>7 in [0,8), cc=tid&127), reps lp = rep*8+pq
//   (rep<4): segmented gather, AFFINE pure segments (a += 144/t; decode only
//   at entry — addresses identical to the verified decode, y bit-identical);
//   y packed into LDS B-frag order.
// Phase C: maskconv MFMA: 16 waves, wave w -> o-tile ot16 = w; per kb
//   A-frags wmp_hi/lo, B-frags y_lds (ct 0,1); per-acc order kb asc,
//   ah then al (verified order) + x residual -> out.
// ---------------------------------------------------------------------------
__global__ __launch_bounds__(1024) void agg_mask_kernel(
    const float* __restrict__ scores,
    const float* __restrict__ m_arr,
    const float* __restrict__ inv_arr,
    const unsigned short* __restrict__ Apad,
    const unsigned short* __restrict__ wmp_hi,
    const unsigned short* __restrict__ wmp_lo,
    const float* __restrict__ x,
    float* __restrict__ out)
{
    const int tid = threadIdx.x;
    const int blk = blockIdx.x;          // 0..127: pixel tile of 32
    const int b   = blockIdx.y;
    const int P0  = blk * 32;            // global pixel base

    __shared__ float at_l[32][52];
    __shared__ unsigned short y_lds[8 * 512];   // 8 B-frags (4 kb x 2 ct)

    // ---- Phase A: attention weights ----
    const int j0 = P0 & 63;
    #pragma unroll
    for (int it = 0; it < 2; ++it) {
        int idx = tid + it * 1024;       // 0..2047
        int lp = idx >> 6;               // 0..31
        int t  = idx & 63;
        if (t < 49) {
            const int s = P0 + lp;
            const int j = j0 + lp;
            float sc = scores[(b * 4096 + s) * 64 + t];
            float m  = m_arr[(b * 64 + j) * 49 + t];
            float iv = inv_arr[(b * 64 + j) * 49 + t];
            at_l[lp][t] = __expf(sc - m) * iv;
        }
    }
    __syncthreads();

    // ---- Phase B: gather y (addresses identical to verified decode) ----
    const unsigned short* __restrict__ Ab = Apad + b * A_BATCH;
    const int pq = tid >> 7;             // 0..7
    const int cc = tid & 127;

    #pragma unroll
    for (int rep = 0; rep < 4; ++rep) {
        const int lp = rep * 8 + pq;     // 0..31
        const int s  = P0 + lp;

        const int base  = s * 6272;
        const int ch_lo = base >> 12;
        const unsigned B1 = (unsigned)(ch_lo + 1) << 12;
        const unsigned B2 = (unsigned)(ch_lo + 2) << 12;
        const int d1 = (int)B1 - base;
        const int d2 = d1 + 4096;

        int A1 = d1 >> 7;
        int A2 = (d1 + 127) >> 7;
        int C1 = d2 >> 7;          if (C1 > 49) C1 = 49;
        int C2 = (d2 + 127) >> 7;  if (C2 > 49) C2 = 49;
        if (A1 > 49) A1 = 49;
        if (A2 > 49) A2 = 49;

        unsigned OFFv[3];
        #pragma unroll
        for (int i = 0; i < 3; ++i) {
            int ch = ch_lo + i;
            int c0 = ch / 49; if (c0 > 127) c0 = 127;
            int rr = ch - c0 * 49;
            int kh = rr / 7;
            int kw = rr - kh * 7;
            OFFv[i] = (unsigned)(c0 * PLANE + kh * 72 + kw + 1);
        }

        float acc = 0.f;

        {   // pure segment 0: t in [0, A1), affine a += 144
            unsigned p0 = (unsigned)(base + cc) & 4095u;
            unsigned a = OFFv[0] + p0 + ((p0 >> 6) << 3);
            #pragma unroll 4
            for (int t = 0; t < A1; ++t) {
                acc = fmaf(at_l[lp][t], bf2f(Ab[a]), acc);
                a += 144u;
            }
        }
        for (int t = A1; t < A2; ++t) {  // mixed (<=1 iter)
            unsigned F = (unsigned)(base + cc) + 128u * (unsigned)t;
            unsigned OFF_ = (F >= B1) ? OFFv[1] : OFFv[0];
            unsigned p = F & 4095u;
            unsigned a = OFF_ + p + ((p >> 6) << 3);
            acc = fmaf(at_l[lp][t], bf2f(Ab[a]), acc);
        }
        {   // pure segment 1: t in [A2, C1), affine
            unsigned F = (unsigned)(base + cc) + 128u * (unsigned)A2;
            unsigned p0 = F & 4095u;
            unsigned a = OFFv[1] + p0 + ((p0 >> 6) << 3);
            #pragma unroll 4
            for (int t = A2; t < C1; ++t) {
                acc = fmaf(at_l[lp][t], bf2f(Ab[a]), acc);
                a += 144u;
            }
        }
        for (int t = C1; t < C2; ++t) {  // mixed (<=1 iter)
            unsigned F = (unsigned)(base + cc) + 128u * (unsigned)t;
            unsigned OFF_ = (F >= B2) ? OFFv[2] : OFFv[1];
            unsigned p = F & 4095u;
            unsigned a = OFF_ + p + ((p >> 6) << 3);
            acc = fmaf(at_l[lp][t], bf2f(Ab[a]), acc);
        }
        {   // pure segment 2: t in [C2, 49), affine
            unsigned F = (unsigned)(base + cc) + 128u * (unsigned)C2;
            unsigned p0 = F & 4095u;
            unsigned a = OFFv[2] + p0 + ((p0 >> 6) << 3);
            #pragma unroll 4
            for (int t = C2; t < 49; ++t) {
                acc = fmaf(at_l[lp][t], bf2f(Ab[a]), acc);
                a += 144u;
            }
        }

        // pack into LDS B-frag order
        const int kb = cc >> 5, k32 = cc & 31;
        const int quad = k32 >> 3, jx = k32 & 7;
        const int ct = lp >> 4, n = lp & 15;
        y_lds[(kb * 2 + ct) * 512 + (quad * 16 + n) * 8 + jx] = f2bf(acc);
    }
    __syncthreads();

    // ---- Phase C: maskconv MFMA (16 waves, 1 o-tile each) ----
    const int w    = tid >> 6;           // 0..15
    const int ln   = tid & 63;
    const int lm   = ln & 15;
    const int quad = ln >> 4;
    const int lnofs = ln * 8;

    floatx4 accA[2] = {{0.f,0.f,0.f,0.f},{0.f,0.f,0.f,0.f}};

    #pragma unroll
    for (int kb = 0; kb < 4; ++kb) {
        const int aoffA = (w * 4 + kb) * 512 + lnofs;
        short8 ahA = *reinterpret_cast<const short8*>(wmp_hi + aoffA);
        short8 alA = *reinterpret_cast<const short8*>(wmp_lo + aoffA);
        short8 bf[2];
        #pragma unroll
        for (int ct = 0; ct < 2; ++ct)
            bf[ct] = *reinterpret_cast<const short8*>(
                y_lds + (kb * 2 + ct) * 512 + lnofs);
        #pragma unroll
        for (int ct = 0; ct < 2; ++ct) {
            accA[ct] = __builtin_amdgcn_mfma_f32_16x16x32_bf16(ahA, bf[ct], accA[ct], 0, 0, 0);
            accA[ct] = __builtin_amdgcn_mfma_f32_16x16x32_bf16(alA, bf[ct], accA[ct], 0, 0, 0);
        }
    }

    #pragma unroll
    for (int ct = 0; ct < 2; ++ct) {
        const int p = P0 + ct * 16 + lm;
        #pragma unroll
        for (int reg = 0; reg < 4; ++reg) {
            const int oA = w * 16 + quad * 4 + reg;
            const int ofsA = (b * 256 + oA) * 4096 + p;
            out[ofsA] = accA[ct][reg] + x[ofsA];
        }
    }
}

extern "C" void kernel_launch(void* const* d_in, const int* in_sizes, int n_in,
                              void* d_out, int out_size, void* d_ws, size_t ws_size,
                              hipStream_t stream) {
    const float* x       = (const float*)d_in[0];
    const float* w_phi   = (const float*)d_in[1];
    const float* w_theta = (const float*)d_in[2];
    const float* w_g     = (const float*)d_in[3];
    const float* w_mask  = (const float*)d_in[4];

    float* out_f = (float*)d_out;

    unsigned short* ws_u  = (unsigned short*)d_ws;
    unsigned short* A_phi = ws_u;                      // 2,580,480 ush
    unsigned short* A_g   = ws_u + 2580480;            // 2,580,480 ush
    unsigned short* th_u  = ws_u + 7258112;            // 2,097,152 ush
    float*          sc_f  = (float*)(ws_u + 9355264);  // 1,048,576 fp32
    unsigned short* xph   = ws_u + 11452416;           // 4,194,304 ush
    unsigned short* xpl   = ws_u + 15646720;           // 4,194,304 ush
    unsigned short* w3ph  = ws_u + 19841024;           // 98,304 ush
    unsigned short* w3pl  = ws_u + 19939328;           // 98,304 ush
    unsigned short* wmph  = ws_u + 20037632;           // 32,768 ush
    unsigned short* wmpl  = ws_u + 20070400;           // 32,768 ush
    float*          m_f   = (float*)(ws_u + 20103168); // 12,544 fp32
    float*          inv_f = (float*)(ws_u + 20128256); // 12,544 fp32

    // 1: prep (packed operand build + zero planes)
    hipLaunchKernelGGL(prep_kernel, dim3(1152), dim3(256), 0, stream,
                       x, w_phi, w_theta, w_g, w_mask,
                       xph, xpl, w3ph, w3pl, wmph, wmpl, (uint4*)A_phi);
    // 2: conv3 via packed split-bf16 MFMA (one region per block, r0 structure)
    hipLaunchKernelGGL(conv3_mfma_kernel, dim3(64, 3, 4), dim3(256), 0, stream,
                       xph, xpl, w3ph, w3pl, A_phi, th_u, A_g);
    // 3: scores (segmented flat-decode gather)
    hipLaunchKernelGGL(scores_kernel, dim3(1024, 4), dim3(256), 0, stream,
                       A_phi, th_u, sc_f);
    // 4: softmax stats (m, inv) only
    hipLaunchKernelGGL(softmax_stats_kernel, dim3(256), dim3(256), 0, stream,
                       sc_f, m_f, inv_f);
    // 5: fused aggregate + maskconv -> out (1024 thr, 32 px, 32 waves/CU)
    hipLaunchKernelGGL(agg_mask_kernel, dim3(128, 4), dim3(1024), 0, stream,
                       sc_f, m_f, inv_f, A_g, wmph, wmpl, x, out_f);
}

// Round 5
// 162.454 us; speedup vs baseline: 1.1263x; 1.0006x over previous
//
#include <hip/hip_runtime.h>

// Problem: b=4, c=256, ci=128, h=w=64 (HW=4096), field=7, kk=49. fp32 I/O.
//
// 5-dispatch pipeline; MFMA GEMMs (split-bf16 hi+lo) with operands PACKED in
// MFMA-fragment order (fragment = 512 ushorts; lane ln reads 16 B at
// frag_base + ln*16). A-frag elem[ln*8+j] = W[row=ln&15][k=(ln>>4)*8+j];
// B-frag elem[ln*8+j] = M[k=(ln>>4)*8+j][col=ln&15]; C/D col=lane&15,
// row=quad*4+reg (all r10/r11-verified).
//  1. prep: x -> xp_hi/lo packed; w3 -> w3p_hi/lo; wm -> wmp_hi/lo; zero planes.
//  2. conv3_mfma: one region (phi/theta/g) per block (r0-verified structure).
//  3. scores: segmented flat-decode gather; r5: __launch_bounds__(256,8)
//     forces VGPR<=64 -> 8 waves/SIMD (was potentially 4 if VGPR>64).
//  4. softmax_stats: per (b,j,t): m and inv=1/sum only.
//  5. agg_mask (FUSED aggregate+maskconv, r4 structure): 1024 thr, 32 px,
//     affine pure segments (a += 144), 32 waves/CU.
//
// Padded planes: [b][c0][70][72] bf16, data (py,px) at (py+3,px+4), zero
// borders; patch addr for F -> (ch=F>>12, p=F&4095):
//   a = OFF(ch) + p + 8*(p>>6), OFF(ch) = c0*5040 + kh*72 + kw + 1.
// Per-pixel F-range < 2*4096 -> <=3 ch values -> 3 pure + 2 mixed segments.
//
// ws layout (ushort units): unchanged (~40.3 MB total).

#define PLANE    5040
#define A_BATCH  645120

typedef __attribute__((ext_vector_type(8))) short short8;
typedef __attribute__((ext_vector_type(4))) float floatx4;

__device__ __forceinline__ float bf2f(unsigned short u) {
    union { unsigned int i; float f; } v; v.i = ((unsigned int)u) << 16; return v.f;
}
__device__ __forceinline__ unsigned short f2bf(float f) {
    union { float f; unsigned int i; } v; v.f = f;
    unsigned int r = v.i + 0x7FFFu + ((v.i >> 16) & 1u);
    return (unsigned short)(r >> 16);
}

// ---------------------------------------------------------------------------
// prep: blocks [0,1024): x fp32 [b][k][p] -> packed hi/lo fragments.
// blocks [1024,1152): w3p/wmp hi/lo packed casts + zero plane regions.
// ---------------------------------------------------------------------------
__global__ __launch_bounds__(256) void prep_kernel(
    const float* __restrict__ x,
    const float* __restrict__ w_phi,
    const float* __restrict__ w_theta,
    const float* __restrict__ w_g,
    const float* __restrict__ w_mask,
    unsigned short* __restrict__ xp_hi,
    unsigned short* __restrict__ xp_lo,
    unsigned short* __restrict__ w3p_hi,
    unsigned short* __restrict__ w3p_lo,
    unsigned short* __restrict__ wmp_hi,
    unsigned short* __restrict__ wmp_lo,
    uint4* __restrict__ zero_region)
{
    const int tid = threadIdx.x;
    const int bx = blockIdx.x;

    if (bx < 1024) {
        const int b  = bx >> 8;          // batch
        const int kt = (bx >> 6) & 3;    // k 64-tile
        const int pt = bx & 63;          // p 64-tile
        __shared__ float tile[64][65];   // [k][p]
        #pragma unroll
        for (int i = 0; i < 16; ++i) {
            int lin = tid + i * 256;
            int kk = lin >> 6, pp = lin & 63;
            tile[kk][pp] = x[(b * 256 + kt * 64 + kk) * 4096 + pt * 64 + pp];
        }
        __syncthreads();
        #pragma unroll
        for (int i = 0; i < 16; ++i) {
            int lin = tid + i * 256;
            int frag = lin >> 9;          // 0..7
            int idx  = lin & 511;
            int kbL  = frag >> 2;         // 0..1
            int ptL  = frag & 3;          // 0..3
            int j    = idx & 7;
            int n    = (idx >> 3) & 15;
            int quad = idx >> 7;
            float f = tile[kbL * 32 + quad * 8 + j][ptL * 16 + n];
            unsigned short h = f2bf(f);
            int addr = ((b * 8 + kt * 2 + kbL) * 256 + pt * 4 + ptL) * 512 + idx;
            xp_hi[addr] = h;
            xp_lo[addr] = f2bf(f - bf2f(h));
        }
    } else {
        const int wid = (bx - 1024) * 256 + tid;   // 0..32767
        for (int e = wid; e < 98304; e += 32768) {
            int frag = e >> 9;            // 0..191
            int idx  = e & 511;
            int nt16 = frag >> 3, kb = frag & 7;
            int j = idx & 7, m = (idx >> 3) & 15, quad = idx >> 7;
            int n = nt16 * 16 + m;
            int k = kb * 32 + quad * 8 + j;
            float v = (n < 128) ? w_phi[n * 256 + k]
                    : (n < 256) ? w_theta[(n - 128) * 256 + k]
                                : w_g[(n - 256) * 256 + k];
            unsigned short h = f2bf(v);
            w3p_hi[e] = h;
            w3p_lo[e] = f2bf(v - bf2f(h));
        }
        {
            int e = wid;                  // exactly covers wmp
            int frag = e >> 9;            // 0..63
            int idx  = e & 511;
            int ot16 = frag >> 2, kb = frag & 3;
            int j = idx & 7, m = (idx >> 3) & 15, quad = idx >> 7;
            float v = w_mask[(ot16 * 16 + m) * 128 + kb * 32 + quad * 8 + j];
            unsigned short h = f2bf(v);
            wmp_hi[e] = h;
            wmp_lo[e] = f2bf(v - bf2f(h));
        }
        const uint4 z = make_uint4(0u, 0u, 0u, 0u);
        for (int i = wid; i < 645120; i += 32768) zero_region[i] = z;
    }
}

// ---------------------------------------------------------------------------
// conv3_mfma: one REGION per block (nt: 0=phi 1=theta 2=g, 128 rows).
// Wave w handles region rows [w*16,+16) (tile a) and [64+w*16,+16) (tile b)
// over 64 px. 24 MFMAs : 12 fragment loads per kb. Split hi/lo.
// (r0-verified structure.)
// ---------------------------------------------------------------------------
__global__ __launch_bounds__(256) void conv3_mfma_kernel(
    const unsigned short* __restrict__ xp_hi,
    const unsigned short* __restrict__ xp_lo,
    const unsigned short* __restrict__ w3p_hi,
    const unsigned short* __restrict__ w3p_lo,
    unsigned short* __restrict__ A_phi,
    unsigned short* __restrict__ theta_bf,
    unsigned short* __restrict__ A_g)
{
    const int tid = threadIdx.x;
    const int w   = tid >> 6;
    const int ln  = tid & 63;
    const int lm  = ln & 15;
    const int quad = ln >> 4;
    const int bx = blockIdx.x;   // px 64-tile; py = bx
    const int nt = blockIdx.y;   // region 0..2
    const int b  = blockIdx.z;
    const int nt16a = nt * 8 + w;
    const int nt16b = nt * 8 + 4 + w;
    const int lnofs = ln * 8;

    floatx4 accA[4] = {{0.f,0.f,0.f,0.f},{0.f,0.f,0.f,0.f},
                       {0.f,0.f,0.f,0.f},{0.f,0.f,0.f,0.f}};
    floatx4 accB[4] = {{0.f,0.f,0.f,0.f},{0.f,0.f,0.f,0.f},
                       {0.f,0.f,0.f,0.f},{0.f,0.f,0.f,0.f}};

    #pragma unroll
    for (int kb = 0; kb < 8; ++kb) {
        const int aoffA = (nt16a * 8 + kb) * 512 + lnofs;
        const int aoffB = (nt16b * 8 + kb) * 512 + lnofs;
        const int boff  = ((b * 8 + kb) * 256 + bx * 4) * 512 + lnofs;
        short8 ahA = *reinterpret_cast<const short8*>(w3p_hi + aoffA);
        short8 alA = *reinterpret_cast<const short8*>(w3p_lo + aoffA);
        short8 ahB = *reinterpret_cast<const short8*>(w3p_hi + aoffB);
        short8 alB = *reinterpret_cast<const short8*>(w3p_lo + aoffB);
        short8 bh[4], bl[4];
        #pragma unroll
        for (int ct = 0; ct < 4; ++ct) {
            bh[ct] = *reinterpret_cast<const short8*>(xp_hi + boff + ct * 512);
            bl[ct] = *reinterpret_cast<const short8*>(xp_lo + boff + ct * 512);
        }
        #pragma unroll
        for (int ct = 0; ct < 4; ++ct) {
            accA[ct] = __builtin_amdgcn_mfma_f32_16x16x32_bf16(ahA, bh[ct], accA[ct], 0, 0, 0);
            accA[ct] = __builtin_amdgcn_mfma_f32_16x16x32_bf16(ahA, bl[ct], accA[ct], 0, 0, 0);
            accA[ct] = __builtin_amdgcn_mfma_f32_16x16x32_bf16(alA, bh[ct], accA[ct], 0, 0, 0);
            accB[ct] = __builtin_amdgcn_mfma_f32_16x16x32_bf16(ahB, bh[ct], accB[ct], 0, 0, 0);
            accB[ct] = __builtin_amdgcn_mfma_f32_16x16x32_bf16(ahB, bl[ct], accB[ct], 0, 0, 0);
            accB[ct] = __builtin_amdgcn_mfma_f32_16x16x32_bf16(alB, bh[ct], accB[ct], 0, 0, 0);
        }
    }

    const int py = bx;
    if (nt == 1) {
        // theta: cc = region row, store theta_bf[(b*4096+p)*128 + cc]
        #pragma unroll
        for (int ct = 0; ct < 4; ++ct) {
            const int p = bx * 64 + ct * 16 + lm;
            #pragma unroll
            for (int reg = 0; reg < 4; ++reg) {
                const int r = w * 16 + quad * 4 + reg;
                theta_bf[(b * 4096 + p) * 128 + r]      = f2bf(accA[ct][reg]);
                theta_bf[(b * 4096 + p) * 128 + r + 64] = f2bf(accB[ct][reg]);
            }
        }
    } else {
        unsigned short* __restrict__ A = (nt == 0) ? A_phi : A_g;
        #pragma unroll
        for (int ct = 0; ct < 4; ++ct) {
            const int pxx = ct * 16 + lm;
            #pragma unroll
            for (int reg = 0; reg < 4; ++reg) {
                const int r = w * 16 + quad * 4 + reg;
                A[b * A_BATCH + r * PLANE + (py + 3) * 72 + pxx + 4] =
                    f2bf(accA[ct][reg]);
                A[b * A_BATCH + (r + 64) * PLANE + (py + 3) * 72 + pxx + 4] =
                    f2bf(accB[ct][reg]);
            }
        }
    }
}

// ---------------------------------------------------------------------------
// scores: wave per pixel s, lane = t. 3 pure + 2 mixed cc-segments over
// padded phi planes. scores fp32 slots [b][s][64] (first 49 used).
// r5: __launch_bounds__(256, 8) caps VGPR at 64 -> 8 waves/SIMD.
// ---------------------------------------------------------------------------
__global__ __launch_bounds__(256, 8) void scores_kernel(
    const unsigned short* __restrict__ Apad,
    const unsigned short* __restrict__ theta_bf,
    float* __restrict__ scores)
{
    const int w  = threadIdx.x >> 6;
    const int ln = threadIdx.x & 63;
    const int s  = blockIdx.x * 4 + w;
    const int b  = blockIdx.y;

    __shared__ float th[4][128];
    {
        const unsigned short* tb = theta_bf + (b * 4096 + s) * 128;
        th[w][ln]      = bf2f(tb[ln]);
        th[w][ln + 64] = bf2f(tb[ln + 64]);
    }
    __syncthreads();

    const unsigned short* __restrict__ Ab = Apad + b * A_BATCH;

    const int base  = s * 6272;
    const int ch_lo = base >> 12;
    const unsigned B1 = (unsigned)(ch_lo + 1) << 12;
    const unsigned B2 = (unsigned)(ch_lo + 2) << 12;
    const int d1 = (int)B1 - base;
    const int d2 = d1 + 4096;

    int A1 = d1 / 49;
    int A2 = (d1 + 48) / 49;
    int C1 = d2 / 49;        if (C1 > 128) C1 = 128;
    int C2 = (d2 + 48) / 49; if (C2 > 128) C2 = 128;

    unsigned OFFv[3];
    #pragma unroll
    for (int i = 0; i < 3; ++i) {
        int ch = ch_lo + i;
        int c0 = ch / 49; if (c0 > 127) c0 = 127;
        int rr = ch - c0 * 49;
        int kh = rr / 7;
        int kw = rr - kh * 7;
        OFFv[i] = (unsigned)(c0 * PLANE + kh * 72 + kw + 1);
    }

    unsigned F = (unsigned)(base + ln);
    float acc = 0.f;

    {
        const unsigned OFF_ = OFFv[0];
        #pragma unroll 4
        for (int cc = 0; cc < A1; ++cc) {
            unsigned p = F & 4095u;
            unsigned a = OFF_ + p + ((p >> 6) << 3);
            acc = fmaf(th[w][cc], bf2f(Ab[a]), acc);
            F += 49u;
        }
    }
    for (int cc = A1; cc < A2; ++cc) {
        unsigned OFF_ = (F >= B1) ? OFFv[1] : OFFv[0];
        unsigned p = F & 4095u;
        unsigned a = OFF_ + p + ((p >> 6) << 3);
        acc = fmaf(th[w][cc], bf2f(Ab[a]), acc);
        F += 49u;
    }
    {
        const unsigned OFF_ = OFFv[1];
        #pragma unroll 4
        for (int cc = A2; cc < C1; ++cc) {
            unsigned p = F & 4095u;
            unsigned a = OFF_ + p + ((p >> 6) << 3);
            acc = fmaf(th[w][cc], bf2f(Ab[a]), acc);
            F += 49u;
        }
    }
    for (int cc = C1; cc < C2; ++cc) {
        unsigned OFF_ = (F >= B2) ? OFFv[2] : OFFv[1];
        unsigned p = F & 4095u;
        unsigned a = OFF_ + p + ((p >> 6) << 3);
        acc = fmaf(th[w][cc], bf2f(Ab[a]), acc);
        F += 49u;
    }
    {
        const unsigned OFF_ = OFFv[2];
        #pragma unroll 4
        for (int cc = C2; cc < 128; ++cc) {
            unsigned p = F & 4095u;
            unsigned a = OFF_ + p + ((p >> 6) << 3);
            acc = fmaf(th[w][cc], bf2f(Ab[a]), acc);
            F += 49u;
        }
    }

    if (ln < 49) scores[(b * 4096 + s) * 64 + ln] = acc;
}

// ---------------------------------------------------------------------------
// softmax_stats: per (b,j,t) compute m = max_i sc, inv = 1/sum_i exp(sc-m).
// Block per (b,j); LDS tile 64(i) x 49(t). No normalize write-back.
// ---------------------------------------------------------------------------
__global__ __launch_bounds__(256) void softmax_stats_kernel(
    const float* __restrict__ scores,
    float* __restrict__ m_arr,
    float* __restrict__ inv_arr)
{
    const int b = blockIdx.x >> 6;
    const int j = blockIdx.x & 63;
    const int tid = threadIdx.x;
    const int wv = tid >> 6;
    const int ln = tid & 63;

    __shared__ float tile[64][52];

    #pragma unroll
    for (int it = 0; it < 16; ++it) {
        int i = it * 4 + wv;
        if (ln < 49) tile[i][ln] = scores[(b * 4096 + i * 64 + j) * 64 + ln];
    }
    __syncthreads();

    if (tid < 49) {
        float m = -3.4e38f;
        #pragma unroll 8
        for (int i = 0; i < 64; ++i) m = fmaxf(m, tile[i][tid]);
        float sum = 0.f;
        #pragma unroll 8
        for (int i = 0; i < 64; ++i) sum += __expf(tile[i][tid] - m);
        m_arr[(b * 64 + j) * 49 + tid]   = m;
        inv_arr[(b * 64 + j) * 49 + tid] = 1.f / sum;
    }
}

// ---------------------------------------------------------------------------
// agg_mask (FUSED, r4): 32 pixels/block, 1024 threads, grid (128, 4).
// Phase A: at_l[lp][t] = exp(sc-m)*inv (2 iters of 1024).
// Phase B: thread (pq=tid>>7 in [0,8), cc=tid&127), reps lp = rep*8+pq
//   (rep<4): segmented gather, AFFINE pure segments (a += 144/t);
//   y packed into LDS B-frag order.
// Phase C: maskconv MFMA: 16 waves, wave w -> o-tile ot16 = w; per kb
//   A-frags wmp_hi/lo, B-frags y_lds (ct 0,1); per-acc order kb asc,
//   ah then al (verified order) + x residual -> out.
// ---------------------------------------------------------------------------
__global__ __launch_bounds__(1024) void agg_mask_kernel(
    const float* __restrict__ scores,
    const float* __restrict__ m_arr,
    const float* __restrict__ inv_arr,
    const unsigned short* __restrict__ Apad,
    const unsigned short* __restrict__ wmp_hi,
    const unsigned short* __restrict__ wmp_lo,
    const float* __restrict__ x,
    float* __restrict__ out)
{
    const int tid = threadIdx.x;
    const int blk = blockIdx.x;          // 0..127: pixel tile of 32
    const int b   = blockIdx.y;
    const int P0  = blk * 32;            // global pixel base

    __shared__ float at_l[32][52];
    __shared__ unsigned short y_lds[8 * 512];   // 8 B-frags (4 kb x 2 ct)

    // ---- Phase A: attention weights ----
    const int j0 = P0 & 63;
    #pragma unroll
    for (int it = 0; it < 2; ++it) {
        int idx = tid + it * 1024;       // 0..2047
        int lp = idx >> 6;               // 0..31
        int t  = idx & 63;
        if (t < 49) {
            const int s = P0 + lp;
            const int j = j0 + lp;
            float sc = scores[(b * 4096 + s) * 64 + t];
            float m  = m_arr[(b * 64 + j) * 49 + t];
            float iv = inv_arr[(b * 64 + j) * 49 + t];
            at_l[lp][t] = __expf(sc - m) * iv;
        }
    }
    __syncthreads();

    // ---- Phase B: gather y (addresses identical to verified decode) ----
    const unsigned short* __restrict__ Ab = Apad + b * A_BATCH;
    const int pq = tid >> 7;             // 0..7
    const int cc = tid & 127;

    #pragma unroll
    for (int rep = 0; rep < 4; ++rep) {
        const int lp = rep * 8 + pq;     // 0..31
        const int s  = P0 + lp;

        const int base  = s * 6272;
        const int ch_lo = base >> 12;
        const unsigned B1 = (unsigned)(ch_lo + 1) << 12;
        const unsigned B2 = (unsigned)(ch_lo + 2) << 12;
        const int d1 = (int)B1 - base;
        const int d2 = d1 + 4096;

        int A1 = d1 >> 7;
        int A2 = (d1 + 127) >> 7;
        int C1 = d2 >> 7;          if (C1 > 49) C1 = 49;
        int C2 = (d2 + 127) >> 7;  if (C2 > 49) C2 = 49;
        if (A1 > 49) A1 = 49;
        if (A2 > 49) A2 = 49;

        unsigned OFFv[3];
        #pragma unroll
        for (int i = 0; i < 3; ++i) {
            int ch = ch_lo + i;
            int c0 = ch / 49; if (c0 > 127) c0 = 127;
            int rr = ch - c0 * 49;
            int kh = rr / 7;
            int kw = rr - kh * 7;
            OFFv[i] = (unsigned)(c0 * PLANE + kh * 72 + kw + 1);
        }

        float acc = 0.f;

        {   // pure segment 0: t in [0, A1), affine a += 144
            unsigned p0 = (unsigned)(base + cc) & 4095u;
            unsigned a = OFFv[0] + p0 + ((p0 >> 6) << 3);
            #pragma unroll 4
            for (int t = 0; t < A1; ++t) {
                acc = fmaf(at_l[lp][t], bf2f(Ab[a]), acc);
                a += 144u;
            }
        }
        for (int t = A1; t < A2; ++t) {  // mixed (<=1 iter)
            unsigned F = (unsigned)(base + cc) + 128u * (unsigned)t;
            unsigned OFF_ = (F >= B1) ? OFFv[1] : OFFv[0];
            unsigned p = F & 4095u;
            unsigned a = OFF_ + p + ((p >> 6) << 3);
            acc = fmaf(at_l[lp][t], bf2f(Ab[a]), acc);
        }
        {   // pure segment 1: t in [A2, C1), affine
            unsigned F = (unsigned)(base + cc) + 128u * (unsigned)A2;
            unsigned p0 = F & 4095u;
            unsigned a = OFFv[1] + p0 + ((p0 >> 6) << 3);
            #pragma unroll 4
            for (int t = A2; t < C1; ++t) {
                acc = fmaf(at_l[lp][t], bf2f(Ab[a]), acc);
                a += 144u;
            }
        }
        for (int t = C1; t < C2; ++t) {  // mixed (<=1 iter)
            unsigned F = (unsigned)(base + cc) + 128u * (unsigned)t;
            unsigned OFF_ = (F >= B2) ? OFFv[2] : OFFv[1];
            unsigned p = F & 4095u;
            unsigned a = OFF_ + p + ((p >> 6) << 3);
            acc = fmaf(at_l[lp][t], bf2f(Ab[a]), acc);
        }
        {   // pure segment 2: t in [C2, 49), affine
            unsigned F = (unsigned)(base + cc) + 128u * (unsigned)C2;
            unsigned p0 = F & 4095u;
            unsigned a = OFFv[2] + p0 + ((p0 >> 6) << 3);
            #pragma unroll 4
            for (int t = C2; t < 49; ++t) {
                acc = fmaf(at_l[lp][t], bf2f(Ab[a]), acc);
                a += 144u;
            }
        }

        // pack into LDS B-frag order
        const int kb = cc >> 5, k32 = cc & 31;
        const int quad = k32 >> 3, jx = k32 & 7;
        const int ct = lp >> 4, n = lp & 15;
        y_lds[(kb * 2 + ct) * 512 + (quad * 16 + n) * 8 + jx] = f2bf(acc);
    }
    __syncthreads();

    // ---- Phase C: maskconv MFMA (16 waves, 1 o-tile each) ----
    const int w    = tid >> 6;           // 0..15
    const int ln   = tid & 63;
    const int lm   = ln & 15;
    const int quad = ln >> 4;
    const int lnofs = ln * 8;

    floatx4 accA[2] = {{0.f,0.f,0.f,0.f},{0.f,0.f,0.f,0.f}};

    #pragma unroll
    for (int kb = 0; kb < 4; ++kb) {
        const int aoffA = (w * 4 + kb) * 512 + lnofs;
        short8 ahA = *reinterpret_cast<const short8*>(wmp_hi + aoffA);
        short8 alA = *reinterpret_cast<const short8*>(wmp_lo + aoffA);
        short8 bf[2];
        #pragma unroll
        for (int ct = 0; ct < 2; ++ct)
            bf[ct] = *reinterpret_cast<const short8*>(
                y_lds + (kb * 2 + ct) * 512 + lnofs);
        #pragma unroll
        for (int ct = 0; ct < 2; ++ct) {
            accA[ct] = __builtin_amdgcn_mfma_f32_16x16x32_bf16(ahA, bf[ct], accA[ct], 0, 0, 0);
            accA[ct] = __builtin_amdgcn_mfma_f32_16x16x32_bf16(alA, bf[ct], accA[ct], 0, 0, 0);
        }
    }

    #pragma unroll
    for (int ct = 0; ct < 2; ++ct) {
        const int p = P0 + ct * 16 + lm;
        #pragma unroll
        for (int reg = 0; reg < 4; ++reg) {
            const int oA = w * 16 + quad * 4 + reg;
            const int ofsA = (b * 256 + oA) * 4096 + p;
            out[ofsA] = accA[ct][reg] + x[ofsA];
        }
    }
}

extern "C" void kernel_launch(void* const* d_in, const int* in_sizes, int n_in,
                              void* d_out, int out_size, void* d_ws, size_t ws_size,
                              hipStream_t stream) {
    const float* x       = (const float*)d_in[0];
    const float* w_phi   = (const float*)d_in[1];
    const float* w_theta = (const float*)d_in[2];
    const float* w_g     = (const float*)d_in[3];
    const float* w_mask  = (const float*)d_in[4];

    float* out_f = (float*)d_out;

    unsigned short* ws_u  = (unsigned short*)d_ws;
    unsigned short* A_phi = ws_u;                      // 2,580,480 ush
    unsigned short* A_g   = ws_u + 2580480;            // 2,580,480 ush
    unsigned short* th_u  = ws_u + 7258112;            // 2,097,152 ush
    float*          sc_f  = (float*)(ws_u + 9355264);  // 1,048,576 fp32
    unsigned short* xph   = ws_u + 11452416;           // 4,194,304 ush
    unsigned short* xpl   = ws_u + 15646720;           // 4,194,304 ush
    unsigned short* w3ph  = ws_u + 19841024;           // 98,304 ush
    unsigned short* w3pl  = ws_u + 19939328;           // 98,304 ush
    unsigned short* wmph  = ws_u + 20037632;           // 32,768 ush
    unsigned short* wmpl  = ws_u + 20070400;           // 32,768 ush
    float*          m_f   = (float*)(ws_u + 20103168); // 12,544 fp32
    float*          inv_f = (float*)(ws_u + 20128256); // 12,544 fp32

    // 1: prep (packed operand build + zero planes)
    hipLaunchKernelGGL(prep_kernel, dim3(1152), dim3(256), 0, stream,
                       x, w_phi, w_theta, w_g, w_mask,
                       xph, xpl, w3ph, w3pl, wmph, wmpl, (uint4*)A_phi);
    // 2: conv3 via packed split-bf16 MFMA (one region per block, r0 structure)
    hipLaunchKernelGGL(conv3_mfma_kernel, dim3(64, 3, 4), dim3(256), 0, stream,
                       xph, xpl, w3ph, w3pl, A_phi, th_u, A_g);
    // 3: scores (segmented flat-decode gather, VGPR-capped for 8 waves/SIMD)
    hipLaunchKernelGGL(scores_kernel, dim3(1024, 4), dim3(256), 0, stream,
                       A_phi, th_u, sc_f);
    // 4: softmax stats (m, inv) only
    hipLaunchKernelGGL(softmax_stats_kernel, dim3(256), dim3(256), 0, stream,
                       sc_f, m_f, inv_f);
    // 5: fused aggregate + maskconv -> out (1024 thr, 32 px, 32 waves/CU)
    hipLaunchKernelGGL(agg_mask_kernel, dim3(128, 4), dim3(1024), 0, stream,
                       sc_f, m_f, inv_f, A_g, wmph, wmpl, x, out_f);
}

// Round 6
// 159.140 us; speedup vs baseline: 1.1497x; 1.0208x over previous
//
#include <hip/hip_runtime.h>

// Problem: b=4, c=256, ci=128, h=w=64 (HW=4096), field=7, kk=49. fp32 I/O.
//
// 5-dispatch pipeline; MFMA GEMMs (split-bf16 hi+lo) with operands PACKED in
// MFMA-fragment order (fragment = 512 ushorts; lane ln reads 16 B at
// frag_base + ln*16). A-frag elem[ln*8+j] = W[row=ln&15][k=(ln>>4)*8+j];
// B-frag elem[ln*8+j] = M[k=(ln>>4)*8+j][col=ln&15]; C/D col=lane&15,
// row=quad*4+reg (all r10/r11-verified).
//  1. prep: x -> xp_hi/lo packed; w3 -> w3p_hi/lo; wm -> wmp_hi/lo; zero planes.
//  2. conv3_mfma: one region (phi/theta/g) per block (r0-verified structure).
//  3. scores (r6 LDS-STAGED): 1024 thr / 16 px per block. Block's flat range
//     [s0*6272, (s0+15)*6272+6286] maps to a CONTIGUOUS plane window
//     [a_base, a_max], a_max-a_base+1 <= 9486 (~10x value reuse). Stage it
//     coalesced into LDS, then run the verbatim 5-segment decode per wave
//     with OFFv rebased by a_base -> bit-identical to the verified path.
//  4. softmax_stats: per (b,j,t): m and inv=1/sum only.
//  5. agg_mask (FUSED aggregate+maskconv, r4 structure): 1024 thr, 32 px,
//     affine pure segments (a += 144), 32 waves/CU.
//
// Padded planes: [b][c0][70][72] bf16, data (py,px) at (py+3,px+4), zero
// borders; patch addr for F -> (ch=F>>12, p=F&4095):
//   a = OFF(ch) + p + 8*(p>>6), OFF(ch) = c0*5040 + kh*72 + kw + 1.
// Per-pixel F-range < 2*4096 -> <=3 ch values -> 3 pure + 2 mixed segments.
// OFF is monotone in ch; block window size <= 4886 (OFF span, incl. one c0
// crossing) + 4599 (p-term max) + 1 = 9486 ushorts.
//
// ws layout (ushort units): unchanged (~40.3 MB total).

#define PLANE    5040
#define A_BATCH  645120

typedef __attribute__((ext_vector_type(8))) short short8;
typedef __attribute__((ext_vector_type(4))) float floatx4;

__device__ __forceinline__ float bf2f(unsigned short u) {
    union { unsigned int i; float f; } v; v.i = ((unsigned int)u) << 16; return v.f;
}
__device__ __forceinline__ unsigned short f2bf(float f) {
    union { float f; unsigned int i; } v; v.f = f;
    unsigned int r = v.i + 0x7FFFu + ((v.i >> 16) & 1u);
    return (unsigned short)(r >> 16);
}

__device__ __forceinline__ unsigned off_of_ch(int ch) {
    int c0 = ch / 49; if (c0 > 127) c0 = 127;
    int rr = ch - c0 * 49;
    int kh = rr / 7;
    int kw = rr - kh * 7;
    return (unsigned)(c0 * PLANE + kh * 72 + kw + 1);
}

// ---------------------------------------------------------------------------
// prep: blocks [0,1024): x fp32 [b][k][p] -> packed hi/lo fragments.
// blocks [1024,1152): w3p/wmp hi/lo packed casts + zero plane regions.
// ---------------------------------------------------------------------------
__global__ __launch_bounds__(256) void prep_kernel(
    const float* __restrict__ x,
    const float* __restrict__ w_phi,
    const float* __restrict__ w_theta,
    const float* __restrict__ w_g,
    const float* __restrict__ w_mask,
    unsigned short* __restrict__ xp_hi,
    unsigned short* __restrict__ xp_lo,
    unsigned short* __restrict__ w3p_hi,
    unsigned short* __restrict__ w3p_lo,
    unsigned short* __restrict__ wmp_hi,
    unsigned short* __restrict__ wmp_lo,
    uint4* __restrict__ zero_region)
{
    const int tid = threadIdx.x;
    const int bx = blockIdx.x;

    if (bx < 1024) {
        const int b  = bx >> 8;          // batch
        const int kt = (bx >> 6) & 3;    // k 64-tile
        const int pt = bx & 63;          // p 64-tile
        __shared__ float tile[64][65];   // [k][p]
        #pragma unroll
        for (int i = 0; i < 16; ++i) {
            int lin = tid + i * 256;
            int kk = lin >> 6, pp = lin & 63;
            tile[kk][pp] = x[(b * 256 + kt * 64 + kk) * 4096 + pt * 64 + pp];
        }
        __syncthreads();
        #pragma unroll
        for (int i = 0; i < 16; ++i) {
            int lin = tid + i * 256;
            int frag = lin >> 9;          // 0..7
            int idx  = lin & 511;
            int kbL  = frag >> 2;         // 0..1
            int ptL  = frag & 3;          // 0..3
            int j    = idx & 7;
            int n    = (idx >> 3) & 15;
            int quad = idx >> 7;
            float f = tile[kbL * 32 + quad * 8 + j][ptL * 16 + n];
            unsigned short h = f2bf(f);
            int addr = ((b * 8 + kt * 2 + kbL) * 256 + pt * 4 + ptL) * 512 + idx;
            xp_hi[addr] = h;
            xp_lo[addr] = f2bf(f - bf2f(h));
        }
    } else {
        const int wid = (bx - 1024) * 256 + tid;   // 0..32767
        for (int e = wid; e < 98304; e += 32768) {
            int frag = e >> 9;            // 0..191
            int idx  = e & 511;
            int nt16 = frag >> 3, kb = frag & 7;
            int j = idx & 7, m = (idx >> 3) & 15, quad = idx >> 7;
            int n = nt16 * 16 + m;
            int k = kb * 32 + quad * 8 + j;
            float v = (n < 128) ? w_phi[n * 256 + k]
                    : (n < 256) ? w_theta[(n - 128) * 256 + k]
                                : w_g[(n - 256) * 256 + k];
            unsigned short h = f2bf(v);
            w3p_hi[e] = h;
            w3p_lo[e] = f2bf(v - bf2f(h));
        }
        {
            int e = wid;                  // exactly covers wmp
            int frag = e >> 9;            // 0..63
            int idx  = e & 511;
            int ot16 = frag >> 2, kb = frag & 3;
            int j = idx & 7, m = (idx >> 3) & 15, quad = idx >> 7;
            float v = w_mask[(ot16 * 16 + m) * 128 + kb * 32 + quad * 8 + j];
            unsigned short h = f2bf(v);
            wmp_hi[e] = h;
            wmp_lo[e] = f2bf(v - bf2f(h));
        }
        const uint4 z = make_uint4(0u, 0u, 0u, 0u);
        for (int i = wid; i < 645120; i += 32768) zero_region[i] = z;
    }
}

// ---------------------------------------------------------------------------
// conv3_mfma: one REGION per block (nt: 0=phi 1=theta 2=g, 128 rows).
// Wave w handles region rows [w*16,+16) (tile a) and [64+w*16,+16) (tile b)
// over 64 px. 24 MFMAs : 12 fragment loads per kb. Split hi/lo.
// (r0-verified structure.)
// ---------------------------------------------------------------------------
__global__ __launch_bounds__(256) void conv3_mfma_kernel(
    const unsigned short* __restrict__ xp_hi,
    const unsigned short* __restrict__ xp_lo,
    const unsigned short* __restrict__ w3p_hi,
    const unsigned short* __restrict__ w3p_lo,
    unsigned short* __restrict__ A_phi,
    unsigned short* __restrict__ theta_bf,
    unsigned short* __restrict__ A_g)
{
    const int tid = threadIdx.x;
    const int w   = tid >> 6;
    const int ln  = tid & 63;
    const int lm  = ln & 15;
    const int quad = ln >> 4;
    const int bx = blockIdx.x;   // px 64-tile; py = bx
    const int nt = blockIdx.y;   // region 0..2
    const int b  = blockIdx.z;
    const int nt16a = nt * 8 + w;
    const int nt16b = nt * 8 + 4 + w;
    const int lnofs = ln * 8;

    floatx4 accA[4] = {{0.f,0.f,0.f,0.f},{0.f,0.f,0.f,0.f},
                       {0.f,0.f,0.f,0.f},{0.f,0.f,0.f,0.f}};
    floatx4 accB[4] = {{0.f,0.f,0.f,0.f},{0.f,0.f,0.f,0.f},
                       {0.f,0.f,0.f,0.f},{0.f,0.f,0.f,0.f}};

    #pragma unroll
    for (int kb = 0; kb < 8; ++kb) {
        const int aoffA = (nt16a * 8 + kb) * 512 + lnofs;
        const int aoffB = (nt16b * 8 + kb) * 512 + lnofs;
        const int boff  = ((b * 8 + kb) * 256 + bx * 4) * 512 + lnofs;
        short8 ahA = *reinterpret_cast<const short8*>(w3p_hi + aoffA);
        short8 alA = *reinterpret_cast<const short8*>(w3p_lo + aoffA);
        short8 ahB = *reinterpret_cast<const short8*>(w3p_hi + aoffB);
        short8 alB = *reinterpret_cast<const short8*>(w3p_lo + aoffB);
        short8 bh[4], bl[4];
        #pragma unroll
        for (int ct = 0; ct < 4; ++ct) {
            bh[ct] = *reinterpret_cast<const short8*>(xp_hi + boff + ct * 512);
            bl[ct] = *reinterpret_cast<const short8*>(xp_lo + boff + ct * 512);
        }
        #pragma unroll
        for (int ct = 0; ct < 4; ++ct) {
            accA[ct] = __builtin_amdgcn_mfma_f32_16x16x32_bf16(ahA, bh[ct], accA[ct], 0, 0, 0);
            accA[ct] = __builtin_amdgcn_mfma_f32_16x16x32_bf16(ahA, bl[ct], accA[ct], 0, 0, 0);
            accA[ct] = __builtin_amdgcn_mfma_f32_16x16x32_bf16(alA, bh[ct], accA[ct], 0, 0, 0);
            accB[ct] = __builtin_amdgcn_mfma_f32_16x16x32_bf16(ahB, bh[ct], accB[ct], 0, 0, 0);
            accB[ct] = __builtin_amdgcn_mfma_f32_16x16x32_bf16(ahB, bl[ct], accB[ct], 0, 0, 0);
            accB[ct] = __builtin_amdgcn_mfma_f32_16x16x32_bf16(alB, bh[ct], accB[ct], 0, 0, 0);
        }
    }

    const int py = bx;
    if (nt == 1) {
        // theta: cc = region row, store theta_bf[(b*4096+p)*128 + cc]
        #pragma unroll
        for (int ct = 0; ct < 4; ++ct) {
            const int p = bx * 64 + ct * 16 + lm;
            #pragma unroll
            for (int reg = 0; reg < 4; ++reg) {
                const int r = w * 16 + quad * 4 + reg;
                theta_bf[(b * 4096 + p) * 128 + r]      = f2bf(accA[ct][reg]);
                theta_bf[(b * 4096 + p) * 128 + r + 64] = f2bf(accB[ct][reg]);
            }
        }
    } else {
        unsigned short* __restrict__ A = (nt == 0) ? A_phi : A_g;
        #pragma unroll
        for (int ct = 0; ct < 4; ++ct) {
            const int pxx = ct * 16 + lm;
            #pragma unroll
            for (int reg = 0; reg < 4; ++reg) {
                const int r = w * 16 + quad * 4 + reg;
                A[b * A_BATCH + r * PLANE + (py + 3) * 72 + pxx + 4] =
                    f2bf(accA[ct][reg]);
                A[b * A_BATCH + (r + 64) * PLANE + (py + 3) * 72 + pxx + 4] =
                    f2bf(accB[ct][reg]);
            }
        }
    }
}

// ---------------------------------------------------------------------------
// scores (r6 LDS-STAGED): block = (16-px tile, b), 1024 thr, wave = pixel.
// Stage the block's contiguous plane window [a_base, a_max] (<=9486 ush)
// into LDS coalesced, then the verbatim 5-segment decode per wave with
// OFFv rebased by a_base. Reads/fma order bit-identical to verified path.
// ---------------------------------------------------------------------------
__global__ __launch_bounds__(1024, 8) void scores_kernel(
    const unsigned short* __restrict__ Apad,
    const unsigned short* __restrict__ theta_bf,
    float* __restrict__ scores)
{
    const int tid = threadIdx.x;
    const int w   = tid >> 6;            // 0..15: wave = pixel
    const int ln  = tid & 63;
    const int s0  = blockIdx.x * 16;
    const int b   = blockIdx.y;
    const int s   = s0 + w;

    __shared__ float th[16][128];
    __shared__ unsigned short sA[9600];

    // stage theta (16 px x 128 cc; 2 per thread)
    {
        int idx = tid * 2;
        int lp = idx >> 7, cc = idx & 127;
        const unsigned short* tb = theta_bf + (b * 4096 + s0 + lp) * 128 + cc;
        th[lp][cc]     = bf2f(tb[0]);
        th[lp][cc + 1] = bf2f(tb[1]);
    }

    // block plane window
    const int chB_lo = (s0 * 6272) >> 12;
    int chB_hi = ((s0 + 15) * 6272 + 6286) >> 12;
    if (chB_hi > 6271) chB_hi = 6271;
    const unsigned a_base = off_of_ch(chB_lo);
    const int cnt = (int)(off_of_ch(chB_hi) + 4599u - a_base) + 1;  // <= 9486

    // stage window (coalesced u16)
    {
        const unsigned short* src = Apad + b * A_BATCH + a_base;
        for (int i = tid; i < cnt; i += 1024) sA[i] = src[i];
    }
    __syncthreads();

    // per-pixel decode (identical structure to verified path, rebased)
    const int base  = s * 6272;
    const int ch_lo = base >> 12;
    const unsigned B1 = (unsigned)(ch_lo + 1) << 12;
    const unsigned B2 = (unsigned)(ch_lo + 2) << 12;
    const int d1 = (int)B1 - base;
    const int d2 = d1 + 4096;

    int A1 = d1 / 49;
    int A2 = (d1 + 48) / 49;
    int C1 = d2 / 49;        if (C1 > 128) C1 = 128;
    int C2 = (d2 + 48) / 49; if (C2 > 128) C2 = 128;

    unsigned OFFv[3];
    #pragma unroll
    for (int i = 0; i < 3; ++i)
        OFFv[i] = off_of_ch(ch_lo + i) - a_base;

    unsigned F = (unsigned)(base + ln);
    float acc = 0.f;

    {
        const unsigned OFF_ = OFFv[0];
        #pragma unroll 4
        for (int cc = 0; cc < A1; ++cc) {
            unsigned p = F & 4095u;
            unsigned a = OFF_ + p + ((p >> 6) << 3);
            acc = fmaf(th[w][cc], bf2f(sA[a]), acc);
            F += 49u;
        }
    }
    for (int cc = A1; cc < A2; ++cc) {
        unsigned OFF_ = (F >= B1) ? OFFv[1] : OFFv[0];
        unsigned p = F & 4095u;
        unsigned a = OFF_ + p + ((p >> 6) << 3);
        acc = fmaf(th[w][cc], bf2f(sA[a]), acc);
        F += 49u;
    }
    {
        const unsigned OFF_ = OFFv[1];
        #pragma unroll 4
        for (int cc = A2; cc < C1; ++cc) {
            unsigned p = F & 4095u;
            unsigned a = OFF_ + p + ((p >> 6) << 3);
            acc = fmaf(th[w][cc], bf2f(sA[a]), acc);
            F += 49u;
        }
    }
    for (int cc = C1; cc < C2; ++cc) {
        unsigned OFF_ = (F >= B2) ? OFFv[2] : OFFv[1];
        unsigned p = F & 4095u;
        unsigned a = OFF_ + p + ((p >> 6) << 3);
        acc = fmaf(th[w][cc], bf2f(sA[a]), acc);
        F += 49u;
    }
    {
        const unsigned OFF_ = OFFv[2];
        #pragma unroll 4
        for (int cc = C2; cc < 128; ++cc) {
            unsigned p = F & 4095u;
            unsigned a = OFF_ + p + ((p >> 6) << 3);
            acc = fmaf(th[w][cc], bf2f(sA[a]), acc);
            F += 49u;
        }
    }

    if (ln < 49) scores[(b * 4096 + s) * 64 + ln] = acc;
}

// ---------------------------------------------------------------------------
// softmax_stats: per (b,j,t) compute m = max_i sc, inv = 1/sum_i exp(sc-m).
// Block per (b,j); LDS tile 64(i) x 49(t). No normalize write-back.
// ---------------------------------------------------------------------------
__global__ __launch_bounds__(256) void softmax_stats_kernel(
    const float* __restrict__ scores,
    float* __restrict__ m_arr,
    float* __restrict__ inv_arr)
{
    const int b = blockIdx.x >> 6;
    const int j = blockIdx.x & 63;
    const int tid = threadIdx.x;
    const int wv = tid >> 6;
    const int ln = tid & 63;

    __shared__ float tile[64][52];

    #pragma unroll
    for (int it = 0; it < 16; ++it) {
        int i = it * 4 + wv;
        if (ln < 49) tile[i][ln] = scores[(b * 4096 + i * 64 + j) * 64 + ln];
    }
    __syncthreads();

    if (tid < 49) {
        float m = -3.4e38f;
        #pragma unroll 8
        for (int i = 0; i < 64; ++i) m = fmaxf(m, tile[i][tid]);
        float sum = 0.f;
        #pragma unroll 8
        for (int i = 0; i < 64; ++i) sum += __expf(tile[i][tid] - m);
        m_arr[(b * 64 + j) * 49 + tid]   = m;
        inv_arr[(b * 64 + j) * 49 + tid] = 1.f / sum;
    }
}

// ---------------------------------------------------------------------------
// agg_mask (FUSED, r4): 32 pixels/block, 1024 threads, grid (128, 4).
// Phase A: at_l[lp][t] = exp(sc-m)*inv (2 iters of 1024).
// Phase B: thread (pq=tid>>7 in [0,8), cc=tid&127), reps lp = rep*8+pq
//   (rep<4): segmented gather, AFFINE pure segments (a += 144/t);
//   y packed into LDS B-frag order.
// Phase C: maskconv MFMA: 16 waves, wave w -> o-tile ot16 = w; per kb
//   A-frags wmp_hi/lo, B-frags y_lds (ct 0,1); per-acc order kb asc,
//   ah then al (verified order) + x residual -> out.
// ---------------------------------------------------------------------------
__global__ __launch_bounds__(1024) void agg_mask_kernel(
    const float* __restrict__ scores,
    const float* __restrict__ m_arr,
    const float* __restrict__ inv_arr,
    const unsigned short* __restrict__ Apad,
    const unsigned short* __restrict__ wmp_hi,
    const unsigned short* __restrict__ wmp_lo,
    const float* __restrict__ x,
    float* __restrict__ out)
{
    const int tid = threadIdx.x;
    const int blk = blockIdx.x;          // 0..127: pixel tile of 32
    const int b   = blockIdx.y;
    const int P0  = blk * 32;            // global pixel base

    __shared__ float at_l[32][52];
    __shared__ unsigned short y_lds[8 * 512];   // 8 B-frags (4 kb x 2 ct)

    // ---- Phase A: attention weights ----
    const int j0 = P0 & 63;
    #pragma unroll
    for (int it = 0; it < 2; ++it) {
        int idx = tid + it * 1024;       // 0..2047
        int lp = idx >> 6;               // 0..31
        int t  = idx & 63;
        if (t < 49) {
            const int s = P0 + lp;
            const int j = j0 + lp;
            float sc = scores[(b * 4096 + s) * 64 + t];
            float m  = m_arr[(b * 64 + j) * 49 + t];
            float iv = inv_arr[(b * 64 + j) * 49 + t];
            at_l[lp][t] = __expf(sc - m) * iv;
        }
    }
    __syncthreads();

    // ---- Phase B: gather y (addresses identical to verified decode) ----
    const unsigned short* __restrict__ Ab = Apad + b * A_BATCH;
    const int pq = tid >> 7;             // 0..7
    const int cc = tid & 127;

    #pragma unroll
    for (int rep = 0; rep < 4; ++rep) {
        const int lp = rep * 8 + pq;     // 0..31
        const int s  = P0 + lp;

        const int base  = s * 6272;
        const int ch_lo = base >> 12;
        const unsigned B1 = (unsigned)(ch_lo + 1) << 12;
        const unsigned B2 = (unsigned)(ch_lo + 2) << 12;
        const int d1 = (int)B1 - base;
        const int d2 = d1 + 4096;

        int A1 = d1 >> 7;
        int A2 = (d1 + 127) >> 7;
        int C1 = d2 >> 7;          if (C1 > 49) C1 = 49;
        int C2 = (d2 + 127) >> 7;  if (C2 > 49) C2 = 49;
        if (A1 > 49) A1 = 49;
        if (A2 > 49) A2 = 49;

        unsigned OFFv[3];
        #pragma unroll
        for (int i = 0; i < 3; ++i) {
            int ch = ch_lo + i;
            int c0 = ch / 49; if (c0 > 127) c0 = 127;
            int rr = ch - c0 * 49;
            int kh = rr / 7;
            int kw = rr - kh * 7;
            OFFv[i] = (unsigned)(c0 * PLANE + kh * 72 + kw + 1);
        }

        float acc = 0.f;

        {   // pure segment 0: t in [0, A1), affine a += 144
            unsigned p0 = (unsigned)(base + cc) & 4095u;
            unsigned a = OFFv[0] + p0 + ((p0 >> 6) << 3);
            #pragma unroll 4
            for (int t = 0; t < A1; ++t) {
                acc = fmaf(at_l[lp][t], bf2f(Ab[a]), acc);
                a += 144u;
            }
        }
        for (int t = A1; t < A2; ++t) {  // mixed (<=1 iter)
            unsigned F = (unsigned)(base + cc) + 128u * (unsigned)t;
            unsigned OFF_ = (F >= B1) ? OFFv[1] : OFFv[0];
            unsigned p = F & 4095u;
            unsigned a = OFF_ + p + ((p >> 6) << 3);
            acc = fmaf(at_l[lp][t], bf2f(Ab[a]), acc);
        }
        {   // pure segment 1: t in [A2, C1), affine
            unsigned F = (unsigned)(base + cc) + 128u * (unsigned)A2;
            unsigned p0 = F & 4095u;
            unsigned a = OFFv[1] + p0 + ((p0 >> 6) << 3);
            #pragma unroll 4
            for (int t = A2; t < C1; ++t) {
                acc = fmaf(at_l[lp][t], bf2f(Ab[a]), acc);
                a += 144u;
            }
        }
        for (int t = C1; t < C2; ++t) {  // mixed (<=1 iter)
            unsigned F = (unsigned)(base + cc) + 128u * (unsigned)t;
            unsigned OFF_ = (F >= B2) ? OFFv[2] : OFFv[1];
            unsigned p = F & 4095u;
            unsigned a = OFF_ + p + ((p >> 6) << 3);
            acc = fmaf(at_l[lp][t], bf2f(Ab[a]), acc);
        }
        {   // pure segment 2: t in [C2, 49), affine
            unsigned F = (unsigned)(base + cc) + 128u * (unsigned)C2;
            unsigned p0 = F & 4095u;
            unsigned a = OFFv[2] + p0 + ((p0 >> 6) << 3);
            #pragma unroll 4
            for (int t = C2; t < 49; ++t) {
                acc = fmaf(at_l[lp][t], bf2f(Ab[a]), acc);
                a += 144u;
            }
        }

        // pack into LDS B-frag order
        const int kb = cc >> 5, k32 = cc & 31;
        const int quad = k32 >> 3, jx = k32 & 7;
        const int ct = lp >> 4, n = lp & 15;
        y_lds[(kb * 2 + ct) * 512 + (quad * 16 + n) * 8 + jx] = f2bf(acc);
    }
    __syncthreads();

    // ---- Phase C: maskconv MFMA (16 waves, 1 o-tile each) ----
    const int w    = tid >> 6;           // 0..15
    const int ln   = tid & 63;
    const int lm   = ln & 15;
    const int quad = ln >> 4;
    const int lnofs = ln * 8;

    floatx4 accA[2] = {{0.f,0.f,0.f,0.f},{0.f,0.f,0.f,0.f}};

    #pragma unroll
    for (int kb = 0; kb < 4; ++kb) {
        const int aoffA = (w * 4 + kb) * 512 + lnofs;
        short8 ahA = *reinterpret_cast<const short8*>(wmp_hi + aoffA);
        short8 alA = *reinterpret_cast<const short8*>(wmp_lo + aoffA);
        short8 bf[2];
        #pragma unroll
        for (int ct = 0; ct < 2; ++ct)
            bf[ct] = *reinterpret_cast<const short8*>(
                y_lds + (kb * 2 + ct) * 512 + lnofs);
        #pragma unroll
        for (int ct = 0; ct < 2; ++ct) {
            accA[ct] = __builtin_amdgcn_mfma_f32_16x16x32_bf16(ahA, bf[ct], accA[ct], 0, 0, 0);
            accA[ct] = __builtin_amdgcn_mfma_f32_16x16x32_bf16(alA, bf[ct], accA[ct], 0, 0, 0);
        }
    }

    #pragma unroll
    for (int ct = 0; ct < 2; ++ct) {
        const int p = P0 + ct * 16 + lm;
        #pragma unroll
        for (int reg = 0; reg < 4; ++reg) {
            const int oA = w * 16 + quad * 4 + reg;
            const int ofsA = (b * 256 + oA) * 4096 + p;
            out[ofsA] = accA[ct][reg] + x[ofsA];
        }
    }
}

extern "C" void kernel_launch(void* const* d_in, const int* in_sizes, int n_in,
                              void* d_out, int out_size, void* d_ws, size_t ws_size,
                              hipStream_t stream) {
    const float* x       = (const float*)d_in[0];
    const float* w_phi   = (const float*)d_in[1];
    const float* w_theta = (const float*)d_in[2];
    const float* w_g     = (const float*)d_in[3];
    const float* w_mask  = (const float*)d_in[4];

    float* out_f = (float*)d_out;

    unsigned short* ws_u  = (unsigned short*)d_ws;
    unsigned short* A_phi = ws_u;                      // 2,580,480 ush
    unsigned short* A_g   = ws_u + 2580480;            // 2,580,480 ush
    unsigned short* th_u  = ws_u + 7258112;            // 2,097,152 ush
    float*          sc_f  = (float*)(ws_u + 9355264);  // 1,048,576 fp32
    unsigned short* xph   = ws_u + 11452416;           // 4,194,304 ush
    unsigned short* xpl   = ws_u + 15646720;           // 4,194,304 ush
    unsigned short* w3ph  = ws_u + 19841024;           // 98,304 ush
    unsigned short* w3pl  = ws_u + 19939328;           // 98,304 ush
    unsigned short* wmph  = ws_u + 20037632;           // 32,768 ush
    unsigned short* wmpl  = ws_u + 20070400;           // 32,768 ush
    float*          m_f   = (float*)(ws_u + 20103168); // 12,544 fp32
    float*          inv_f = (float*)(ws_u + 20128256); // 12,544 fp32

    // 1: prep (packed operand build + zero planes)
    hipLaunchKernelGGL(prep_kernel, dim3(1152), dim3(256), 0, stream,
                       x, w_phi, w_theta, w_g, w_mask,
                       xph, xpl, w3ph, w3pl, wmph, wmpl, (uint4*)A_phi);
    // 2: conv3 via packed split-bf16 MFMA (one region per block, r0 structure)
    hipLaunchKernelGGL(conv3_mfma_kernel, dim3(64, 3, 4), dim3(256), 0, stream,
                       xph, xpl, w3ph, w3pl, A_phi, th_u, A_g);
    // 3: scores (LDS-staged window gather, 16 px / 1024 thr per block)
    hipLaunchKernelGGL(scores_kernel, dim3(256, 4), dim3(1024), 0, stream,
                       A_phi, th_u, sc_f);
    // 4: softmax stats (m, inv) only
    hipLaunchKernelGGL(softmax_stats_kernel, dim3(256), dim3(256), 0, stream,
                       sc_f, m_f, inv_f);
    // 5: fused aggregate + maskconv -> out (1024 thr, 32 px, 32 waves/CU)
    hipLaunchKernelGGL(agg_mask_kernel, dim3(128, 4), dim3(1024), 0, stream,
                       sc_f, m_f, inv_f, A_g, wmph, wmpl, x, out_f);
}

// Round 7
// 156.244 us; speedup vs baseline: 1.1711x; 1.0185x over previous
//
#include <hip/hip_runtime.h>

// Problem: b=4, c=256, ci=128, h=w=64 (HW=4096), field=7, kk=49. fp32 I/O.
//
// 5-dispatch pipeline; MFMA GEMMs (split-bf16 hi+lo) with operands PACKED in
// MFMA-fragment order (fragment = 512 ushorts; lane ln reads 16 B at
// frag_base + ln*16). A-frag elem[ln*8+j] = W[row=ln&15][k=(ln>>4)*8+j];
// B-frag elem[ln*8+j] = M[k=(ln>>4)*8+j][col=ln&15]; C/D col=lane&15,
// row=quad*4+reg (all r10/r11-verified).
//  1. prep: x -> xp_hi/lo packed; w3 -> w3p_hi/lo; wm -> wmp_hi/lo; zero planes.
//  2. conv3_mfma (r7 SPLIT): 32-px tile per block, grid (128,3,4) = 1536
//     blocks = 6 blocks/CU -> 24 waves/CU (was 12). Same per-acc MFMA order
//     as r0 -> bit-identical. Store decomposition = r2-verified (py=bx>>1).
//  3. scores (r6 LDS-STAGED): 1024 thr / 16 px per block; contiguous plane
//     window staged to LDS; verbatim 5-segment decode rebased by a_base.
//  4. softmax_stats: per (b,j,t): m and inv=1/sum only.
//  5. agg_mask (r7: + LDS window staging): 1024 thr, 32 px; A_g window
//     (<= 9640 ush: OFF span <= 5040 since dch <= 49) staged to LDS,
//     OFFv rebased, affine +144 kept -> bit-identical; then maskconv MFMA.
//
// Padded planes: [b][c0][70][72] bf16, data (py,px) at (py+3,px+4), zero
// borders; patch addr for F -> (ch=F>>12, p=F&4095):
//   a = OFF(ch) + p + 8*(p>>6), OFF(ch) = c0*5040 + kh*72 + kw + 1.
// OFF is monotone in ch.
//
// ws layout (ushort units): unchanged (~40.3 MB total).

#define PLANE    5040
#define A_BATCH  645120

typedef __attribute__((ext_vector_type(8))) short short8;
typedef __attribute__((ext_vector_type(4))) float floatx4;

__device__ __forceinline__ float bf2f(unsigned short u) {
    union { unsigned int i; float f; } v; v.i = ((unsigned int)u) << 16; return v.f;
}
__device__ __forceinline__ unsigned short f2bf(float f) {
    union { float f; unsigned int i; } v; v.f = f;
    unsigned int r = v.i + 0x7FFFu + ((v.i >> 16) & 1u);
    return (unsigned short)(r >> 16);
}

__device__ __forceinline__ unsigned off_of_ch(int ch) {
    int c0 = ch / 49; if (c0 > 127) c0 = 127;
    int rr = ch - c0 * 49;
    int kh = rr / 7;
    int kw = rr - kh * 7;
    return (unsigned)(c0 * PLANE + kh * 72 + kw + 1);
}

// ---------------------------------------------------------------------------
// prep: blocks [0,1024): x fp32 [b][k][p] -> packed hi/lo fragments.
// blocks [1024,1152): w3p/wmp hi/lo packed casts + zero plane regions.
// ---------------------------------------------------------------------------
__global__ __launch_bounds__(256) void prep_kernel(
    const float* __restrict__ x,
    const float* __restrict__ w_phi,
    const float* __restrict__ w_theta,
    const float* __restrict__ w_g,
    const float* __restrict__ w_mask,
    unsigned short* __restrict__ xp_hi,
    unsigned short* __restrict__ xp_lo,
    unsigned short* __restrict__ w3p_hi,
    unsigned short* __restrict__ w3p_lo,
    unsigned short* __restrict__ wmp_hi,
    unsigned short* __restrict__ wmp_lo,
    uint4* __restrict__ zero_region)
{
    const int tid = threadIdx.x;
    const int bx = blockIdx.x;

    if (bx < 1024) {
        const int b  = bx >> 8;          // batch
        const int kt = (bx >> 6) & 3;    // k 64-tile
        const int pt = bx & 63;          // p 64-tile
        __shared__ float tile[64][65];   // [k][p]
        #pragma unroll
        for (int i = 0; i < 16; ++i) {
            int lin = tid + i * 256;
            int kk = lin >> 6, pp = lin & 63;
            tile[kk][pp] = x[(b * 256 + kt * 64 + kk) * 4096 + pt * 64 + pp];
        }
        __syncthreads();
        #pragma unroll
        for (int i = 0; i < 16; ++i) {
            int lin = tid + i * 256;
            int frag = lin >> 9;          // 0..7
            int idx  = lin & 511;
            int kbL  = frag >> 2;         // 0..1
            int ptL  = frag & 3;          // 0..3
            int j    = idx & 7;
            int n    = (idx >> 3) & 15;
            int quad = idx >> 7;
            float f = tile[kbL * 32 + quad * 8 + j][ptL * 16 + n];
            unsigned short h = f2bf(f);
            int addr = ((b * 8 + kt * 2 + kbL) * 256 + pt * 4 + ptL) * 512 + idx;
            xp_hi[addr] = h;
            xp_lo[addr] = f2bf(f - bf2f(h));
        }
    } else {
        const int wid = (bx - 1024) * 256 + tid;   // 0..32767
        for (int e = wid; e < 98304; e += 32768) {
            int frag = e >> 9;            // 0..191
            int idx  = e & 511;
            int nt16 = frag >> 3, kb = frag & 7;
            int j = idx & 7, m = (idx >> 3) & 15, quad = idx >> 7;
            int n = nt16 * 16 + m;
            int k = kb * 32 + quad * 8 + j;
            float v = (n < 128) ? w_phi[n * 256 + k]
                    : (n < 256) ? w_theta[(n - 128) * 256 + k]
                                : w_g[(n - 256) * 256 + k];
            unsigned short h = f2bf(v);
            w3p_hi[e] = h;
            w3p_lo[e] = f2bf(v - bf2f(h));
        }
        {
            int e = wid;                  // exactly covers wmp
            int frag = e >> 9;            // 0..63
            int idx  = e & 511;
            int ot16 = frag >> 2, kb = frag & 3;
            int j = idx & 7, m = (idx >> 3) & 15, quad = idx >> 7;
            float v = w_mask[(ot16 * 16 + m) * 128 + kb * 32 + quad * 8 + j];
            unsigned short h = f2bf(v);
            wmp_hi[e] = h;
            wmp_lo[e] = f2bf(v - bf2f(h));
        }
        const uint4 z = make_uint4(0u, 0u, 0u, 0u);
        for (int i = wid; i < 645120; i += 32768) zero_region[i] = z;
    }
}

// ---------------------------------------------------------------------------
// conv3_mfma (r7 SPLIT): one REGION x 32-px tile per block. Grid (128,3,4).
// Wave w: region rows [w*16,+16) (tile a) and [64+w*16,+16) (tile b) over
// 32 px. Per kb: 8 A-frag + 4 B-frag loads : 12 MFMAs. Same per-acc order
// as r0 -> bit-identical. 6 blocks/CU -> 24 waves/CU.
// ---------------------------------------------------------------------------
__global__ __launch_bounds__(256) void conv3_mfma_kernel(
    const unsigned short* __restrict__ xp_hi,
    const unsigned short* __restrict__ xp_lo,
    const unsigned short* __restrict__ w3p_hi,
    const unsigned short* __restrict__ w3p_lo,
    unsigned short* __restrict__ A_phi,
    unsigned short* __restrict__ theta_bf,
    unsigned short* __restrict__ A_g)
{
    const int tid = threadIdx.x;
    const int w   = tid >> 6;
    const int ln  = tid & 63;
    const int lm  = ln & 15;
    const int quad = ln >> 4;
    const int bx = blockIdx.x;   // 32-px tile: pixels [bx*32, bx*32+32)
    const int nt = blockIdx.y;   // region 0..2
    const int b  = blockIdx.z;
    const int nt16a = nt * 8 + w;
    const int nt16b = nt * 8 + 4 + w;
    const int lnofs = ln * 8;

    floatx4 accA[2] = {{0.f,0.f,0.f,0.f},{0.f,0.f,0.f,0.f}};
    floatx4 accB[2] = {{0.f,0.f,0.f,0.f},{0.f,0.f,0.f,0.f}};

    #pragma unroll
    for (int kb = 0; kb < 8; ++kb) {
        const int aoffA = (nt16a * 8 + kb) * 512 + lnofs;
        const int aoffB = (nt16b * 8 + kb) * 512 + lnofs;
        const int boff  = ((b * 8 + kb) * 256 + bx * 2) * 512 + lnofs;
        short8 ahA = *reinterpret_cast<const short8*>(w3p_hi + aoffA);
        short8 alA = *reinterpret_cast<const short8*>(w3p_lo + aoffA);
        short8 ahB = *reinterpret_cast<const short8*>(w3p_hi + aoffB);
        short8 alB = *reinterpret_cast<const short8*>(w3p_lo + aoffB);
        short8 bh[2], bl[2];
        #pragma unroll
        for (int ct = 0; ct < 2; ++ct) {
            bh[ct] = *reinterpret_cast<const short8*>(xp_hi + boff + ct * 512);
            bl[ct] = *reinterpret_cast<const short8*>(xp_lo + boff + ct * 512);
        }
        #pragma unroll
        for (int ct = 0; ct < 2; ++ct) {
            accA[ct] = __builtin_amdgcn_mfma_f32_16x16x32_bf16(ahA, bh[ct], accA[ct], 0, 0, 0);
            accA[ct] = __builtin_amdgcn_mfma_f32_16x16x32_bf16(ahA, bl[ct], accA[ct], 0, 0, 0);
            accA[ct] = __builtin_amdgcn_mfma_f32_16x16x32_bf16(alA, bh[ct], accA[ct], 0, 0, 0);
            accB[ct] = __builtin_amdgcn_mfma_f32_16x16x32_bf16(ahB, bh[ct], accB[ct], 0, 0, 0);
            accB[ct] = __builtin_amdgcn_mfma_f32_16x16x32_bf16(ahB, bl[ct], accB[ct], 0, 0, 0);
            accB[ct] = __builtin_amdgcn_mfma_f32_16x16x32_bf16(alB, bh[ct], accB[ct], 0, 0, 0);
        }
    }

    const int py   = bx >> 1;            // image row
    const int px32 = (bx & 1) * 32;      // px base within the row

    if (nt == 1) {
        // theta: store theta_bf[(b*4096+p)*128 + cc]
        #pragma unroll
        for (int ct = 0; ct < 2; ++ct) {
            const int p = bx * 32 + ct * 16 + lm;
            #pragma unroll
            for (int reg = 0; reg < 4; ++reg) {
                const int r = w * 16 + quad * 4 + reg;
                theta_bf[(b * 4096 + p) * 128 + r]      = f2bf(accA[ct][reg]);
                theta_bf[(b * 4096 + p) * 128 + r + 64] = f2bf(accB[ct][reg]);
            }
        }
    } else {
        unsigned short* __restrict__ A = (nt == 0) ? A_phi : A_g;
        #pragma unroll
        for (int ct = 0; ct < 2; ++ct) {
            const int pxx = px32 + ct * 16 + lm;
            const int pbase = (py + 3) * 72 + pxx + 4;
            #pragma unroll
            for (int reg = 0; reg < 4; ++reg) {
                const int r = w * 16 + quad * 4 + reg;
                A[b * A_BATCH + r * PLANE + pbase]        = f2bf(accA[ct][reg]);
                A[b * A_BATCH + (r + 64) * PLANE + pbase] = f2bf(accB[ct][reg]);
            }
        }
    }
}

// ---------------------------------------------------------------------------
// scores (r6 LDS-STAGED): block = (16-px tile, b), 1024 thr, wave = pixel.
// Stage the block's contiguous plane window [a_base, a_max] into LDS
// coalesced, then the verbatim 5-segment decode per wave, rebased.
// ---------------------------------------------------------------------------
__global__ __launch_bounds__(1024, 8) void scores_kernel(
    const unsigned short* __restrict__ Apad,
    const unsigned short* __restrict__ theta_bf,
    float* __restrict__ scores)
{
    const int tid = threadIdx.x;
    const int w   = tid >> 6;            // 0..15: wave = pixel
    const int ln  = tid & 63;
    const int s0  = blockIdx.x * 16;
    const int b   = blockIdx.y;
    const int s   = s0 + w;

    __shared__ float th[16][128];
    __shared__ unsigned short sA[9600];

    // stage theta (16 px x 128 cc; 2 per thread)
    {
        int idx = tid * 2;
        int lp = idx >> 7, cc = idx & 127;
        const unsigned short* tb = theta_bf + (b * 4096 + s0 + lp) * 128 + cc;
        th[lp][cc]     = bf2f(tb[0]);
        th[lp][cc + 1] = bf2f(tb[1]);
    }

    // block plane window
    const int chB_lo = (s0 * 6272) >> 12;
    int chB_hi = ((s0 + 15) * 6272 + 6286) >> 12;
    if (chB_hi > 6271) chB_hi = 6271;
    const unsigned a_base = off_of_ch(chB_lo);
    const int cnt = (int)(off_of_ch(chB_hi) + 4599u - a_base) + 1;

    // stage window (coalesced u16)
    {
        const unsigned short* src = Apad + b * A_BATCH + a_base;
        for (int i = tid; i < cnt; i += 1024) sA[i] = src[i];
    }
    __syncthreads();

    // per-pixel decode (identical structure to verified path, rebased)
    const int base  = s * 6272;
    const int ch_lo = base >> 12;
    const unsigned B1 = (unsigned)(ch_lo + 1) << 12;
    const unsigned B2 = (unsigned)(ch_lo + 2) << 12;
    const int d1 = (int)B1 - base;
    const int d2 = d1 + 4096;

    int A1 = d1 / 49;
    int A2 = (d1 + 48) / 49;
    int C1 = d2 / 49;        if (C1 > 128) C1 = 128;
    int C2 = (d2 + 48) / 49; if (C2 > 128) C2 = 128;

    unsigned OFFv[3];
    #pragma unroll
    for (int i = 0; i < 3; ++i)
        OFFv[i] = off_of_ch(ch_lo + i) - a_base;

    unsigned F = (unsigned)(base + ln);
    float acc = 0.f;

    {
        const unsigned OFF_ = OFFv[0];
        #pragma unroll 4
        for (int cc = 0; cc < A1; ++cc) {
            unsigned p = F & 4095u;
            unsigned a = OFF_ + p + ((p >> 6) << 3);
            acc = fmaf(th[w][cc], bf2f(sA[a]), acc);
            F += 49u;
        }
    }
    for (int cc = A1; cc < A2; ++cc) {
        unsigned OFF_ = (F >= B1) ? OFFv[1] : OFFv[0];
        unsigned p = F & 4095u;
        unsigned a = OFF_ + p + ((p >> 6) << 3);
        acc = fmaf(th[w][cc], bf2f(sA[a]), acc);
        F += 49u;
    }
    {
        const unsigned OFF_ = OFFv[1];
        #pragma unroll 4
        for (int cc = A2; cc < C1; ++cc) {
            unsigned p = F & 4095u;
            unsigned a = OFF_ + p + ((p >> 6) << 3);
            acc = fmaf(th[w][cc], bf2f(sA[a]), acc);
            F += 49u;
        }
    }
    for (int cc = C1; cc < C2; ++cc) {
        unsigned OFF_ = (F >= B2) ? OFFv[2] : OFFv[1];
        unsigned p = F & 4095u;
        unsigned a = OFF_ + p + ((p >> 6) << 3);
        acc = fmaf(th[w][cc], bf2f(sA[a]), acc);
        F += 49u;
    }
    {
        const unsigned OFF_ = OFFv[2];
        #pragma unroll 4
        for (int cc = C2; cc < 128; ++cc) {
            unsigned p = F & 4095u;
            unsigned a = OFF_ + p + ((p >> 6) << 3);
            acc = fmaf(th[w][cc], bf2f(sA[a]), acc);
            F += 49u;
        }
    }

    if (ln < 49) scores[(b * 4096 + s) * 64 + ln] = acc;
}

// ---------------------------------------------------------------------------
// softmax_stats: per (b,j,t) compute m = max_i sc, inv = 1/sum_i exp(sc-m).
// Block per (b,j); LDS tile 64(i) x 49(t). No normalize write-back.
// ---------------------------------------------------------------------------
__global__ __launch_bounds__(256) void softmax_stats_kernel(
    const float* __restrict__ scores,
    float* __restrict__ m_arr,
    float* __restrict__ inv_arr)
{
    const int b = blockIdx.x >> 6;
    const int j = blockIdx.x & 63;
    const int tid = threadIdx.x;
    const int wv = tid >> 6;
    const int ln = tid & 63;

    __shared__ float tile[64][52];

    #pragma unroll
    for (int it = 0; it < 16; ++it) {
        int i = it * 4 + wv;
        if (ln < 49) tile[i][ln] = scores[(b * 4096 + i * 64 + j) * 64 + ln];
    }
    __syncthreads();

    if (tid < 49) {
        float m = -3.4e38f;
        #pragma unroll 8
        for (int i = 0; i < 64; ++i) m = fmaxf(m, tile[i][tid]);
        float sum = 0.f;
        #pragma unroll 8
        for (int i = 0; i < 64; ++i) sum += __expf(tile[i][tid] - m);
        m_arr[(b * 64 + j) * 49 + tid]   = m;
        inv_arr[(b * 64 + j) * 49 + tid] = 1.f / sum;
    }
}

// ---------------------------------------------------------------------------
// agg_mask (r7: + LDS window staging): 32 pixels/block, 1024 threads,
// grid (128, 4).
// Phase A: at_l[lp][t] = exp(sc-m)*inv; stage A_g window into sA (<=9640).
// Phase B: segmented gather FROM LDS (OFFv rebased, affine +144 kept) ->
//   bit-identical y; packed into y_lds B-frag order.
// Phase C: maskconv MFMA (verified order) + x residual -> out.
// ---------------------------------------------------------------------------
__global__ __launch_bounds__(1024) void agg_mask_kernel(
    const float* __restrict__ scores,
    const float* __restrict__ m_arr,
    const float* __restrict__ inv_arr,
    const unsigned short* __restrict__ Apad,
    const unsigned short* __restrict__ wmp_hi,
    const unsigned short* __restrict__ wmp_lo,
    const float* __restrict__ x,
    float* __restrict__ out)
{
    const int tid = threadIdx.x;
    const int blk = blockIdx.x;          // 0..127: pixel tile of 32
    const int b   = blockIdx.y;
    const int P0  = blk * 32;            // global pixel base

    __shared__ float at_l[32][52];
    __shared__ unsigned short y_lds[8 * 512];   // 8 B-frags (4 kb x 2 ct)
    __shared__ unsigned short sA[9728];

    // ---- Phase A: attention weights ----
    const int j0 = P0 & 63;
    #pragma unroll
    for (int it = 0; it < 2; ++it) {
        int idx = tid + it * 1024;       // 0..2047
        int lp = idx >> 6;               // 0..31
        int t  = idx & 63;
        if (t < 49) {
            const int s = P0 + lp;
            const int j = j0 + lp;
            float sc = scores[(b * 4096 + s) * 64 + t];
            float m  = m_arr[(b * 64 + j) * 49 + t];
            float iv = inv_arr[(b * 64 + j) * 49 + t];
            at_l[lp][t] = __expf(sc - m) * iv;
        }
    }

    // ---- stage A_g window ----
    const int chB_lo = (P0 * 6272) >> 12;
    int chB_hi = ((P0 + 31) * 6272 + 6271) >> 12;
    if (chB_hi > 6271) chB_hi = 6271;
    const unsigned a_base = off_of_ch(chB_lo);
    const int cnt = (int)(off_of_ch(chB_hi) + 4599u - a_base) + 1;  // <= 9640
    {
        const unsigned short* src = Apad + b * A_BATCH + a_base;
        for (int i = tid; i < cnt; i += 1024) sA[i] = src[i];
    }
    __syncthreads();

    // ---- Phase B: gather y from LDS (rebased; addresses identical) ----
    const int pq = tid >> 7;             // 0..7
    const int cc = tid & 127;

    #pragma unroll
    for (int rep = 0; rep < 4; ++rep) {
        const int lp = rep * 8 + pq;     // 0..31
        const int s  = P0 + lp;

        const int base  = s * 6272;
        const int ch_lo = base >> 12;
        const unsigned B1 = (unsigned)(ch_lo + 1) << 12;
        const unsigned B2 = (unsigned)(ch_lo + 2) << 12;
        const int d1 = (int)B1 - base;
        const int d2 = d1 + 4096;

        int A1 = d1 >> 7;
        int A2 = (d1 + 127) >> 7;
        int C1 = d2 >> 7;          if (C1 > 49) C1 = 49;
        int C2 = (d2 + 127) >> 7;  if (C2 > 49) C2 = 49;
        if (A1 > 49) A1 = 49;
        if (A2 > 49) A2 = 49;

        unsigned OFFv[3];
        #pragma unroll
        for (int i = 0; i < 3; ++i)
            OFFv[i] = off_of_ch(ch_lo + i) - a_base;

        float acc = 0.f;

        {   // pure segment 0: t in [0, A1), affine a += 144
            unsigned p0 = (unsigned)(base + cc) & 4095u;
            unsigned a = OFFv[0] + p0 + ((p0 >> 6) << 3);
            #pragma unroll 4
            for (int t = 0; t < A1; ++t) {
                acc = fmaf(at_l[lp][t], bf2f(sA[a]), acc);
                a += 144u;
            }
        }
        for (int t = A1; t < A2; ++t) {  // mixed (<=1 iter)
            unsigned F = (unsigned)(base + cc) + 128u * (unsigned)t;
            unsigned OFF_ = (F >= B1) ? OFFv[1] : OFFv[0];
            unsigned p = F & 4095u;
            unsigned a = OFF_ + p + ((p >> 6) << 3);
            acc = fmaf(at_l[lp][t], bf2f(sA[a]), acc);
        }
        {   // pure segment 1: t in [A2, C1), affine
            unsigned F = (unsigned)(base + cc) + 128u * (unsigned)A2;
            unsigned p0 = F & 4095u;
            unsigned a = OFFv[1] + p0 + ((p0 >> 6) << 3);
            #pragma unroll 4
            for (int t = A2; t < C1; ++t) {
                acc = fmaf(at_l[lp][t], bf2f(sA[a]), acc);
                a += 144u;
            }
        }
        for (int t = C1; t < C2; ++t) {  // mixed (<=1 iter)
            unsigned F = (unsigned)(base + cc) + 128u * (unsigned)t;
            unsigned OFF_ = (F >= B2) ? OFFv[2] : OFFv[1];
            unsigned p = F & 4095u;
            unsigned a = OFF_ + p + ((p >> 6) << 3);
            acc = fmaf(at_l[lp][t], bf2f(sA[a]), acc);
        }
        {   // pure segment 2: t in [C2, 49), affine
            unsigned F = (unsigned)(base + cc) + 128u * (unsigned)C2;
            unsigned p0 = F & 4095u;
            unsigned a = OFFv[2] + p0 + ((p0 >> 6) << 3);
            #pragma unroll 4
            for (int t = C2; t < 49; ++t) {
                acc = fmaf(at_l[lp][t], bf2f(sA[a]), acc);
                a += 144u;
            }
        }

        // pack into LDS B-frag order
        const int kb = cc >> 5, k32 = cc & 31;
        const int quad = k32 >> 3, jx = k32 & 7;
        const int ct = lp >> 4, n = lp & 15;
        y_lds[(kb * 2 + ct) * 512 + (quad * 16 + n) * 8 + jx] = f2bf(acc);
    }
    __syncthreads();

    // ---- Phase C: maskconv MFMA (16 waves, 1 o-tile each) ----
    const int w    = tid >> 6;           // 0..15
    const int ln   = tid & 63;
    const int lm   = ln & 15;
    const int quad = ln >> 4;
    const int lnofs = ln * 8;

    floatx4 accA[2] = {{0.f,0.f,0.f,0.f},{0.f,0.f,0.f,0.f}};

    #pragma unroll
    for (int kb = 0; kb < 4; ++kb) {
        const int aoffA = (w * 4 + kb) * 512 + lnofs;
        short8 ahA = *reinterpret_cast<const short8*>(wmp_hi + aoffA);
        short8 alA = *reinterpret_cast<const short8*>(wmp_lo + aoffA);
        short8 bf[2];
        #pragma unroll
        for (int ct = 0; ct < 2; ++ct)
            bf[ct] = *reinterpret_cast<const short8*>(
                y_lds + (kb * 2 + ct) * 512 + lnofs);
        #pragma unroll
        for (int ct = 0; ct < 2; ++ct) {
            accA[ct] = __builtin_amdgcn_mfma_f32_16x16x32_bf16(ahA, bf[ct], accA[ct], 0, 0, 0);
            accA[ct] = __builtin_amdgcn_mfma_f32_16x16x32_bf16(alA, bf[ct], accA[ct], 0, 0, 0);
        }
    }

    #pragma unroll
    for (int ct = 0; ct < 2; ++ct) {
        const int p = P0 + ct * 16 + lm;
        #pragma unroll
        for (int reg = 0; reg < 4; ++reg) {
            const int oA = w * 16 + quad * 4 + reg;
            const int ofsA = (b * 256 + oA) * 4096 + p;
            out[ofsA] = accA[ct][reg] + x[ofsA];
        }
    }
}

extern "C" void kernel_launch(void* const* d_in, const int* in_sizes, int n_in,
                              void* d_out, int out_size, void* d_ws, size_t ws_size,
                              hipStream_t stream) {
    const float* x       = (const float*)d_in[0];
    const float* w_phi   = (const float*)d_in[1];
    const float* w_theta = (const float*)d_in[2];
    const float* w_g     = (const float*)d_in[3];
    const float* w_mask  = (const float*)d_in[4];

    float* out_f = (float*)d_out;

    unsigned short* ws_u  = (unsigned short*)d_ws;
    unsigned short* A_phi = ws_u;                      // 2,580,480 ush
    unsigned short* A_g   = ws_u + 2580480;            // 2,580,480 ush
    unsigned short* th_u  = ws_u + 7258112;            // 2,097,152 ush
    float*          sc_f  = (float*)(ws_u + 9355264);  // 1,048,576 fp32
    unsigned short* xph   = ws_u + 11452416;           // 4,194,304 ush
    unsigned short* xpl   = ws_u + 15646720;           // 4,194,304 ush
    unsigned short* w3ph  = ws_u + 19841024;           // 98,304 ush
    unsigned short* w3pl  = ws_u + 19939328;           // 98,304 ush
    unsigned short* wmph  = ws_u + 20037632;           // 32,768 ush
    unsigned short* wmpl  = ws_u + 20070400;           // 32,768 ush
    float*          m_f   = (float*)(ws_u + 20103168); // 12,544 fp32
    float*          inv_f = (float*)(ws_u + 20128256); // 12,544 fp32

    // 1: prep (packed operand build + zero planes)
    hipLaunchKernelGGL(prep_kernel, dim3(1152), dim3(256), 0, stream,
                       x, w_phi, w_theta, w_g, w_mask,
                       xph, xpl, w3ph, w3pl, wmph, wmpl, (uint4*)A_phi);
    // 2: conv3 split-tile MFMA (32 px/block, 24 waves/CU)
    hipLaunchKernelGGL(conv3_mfma_kernel, dim3(128, 3, 4), dim3(256), 0, stream,
                       xph, xpl, w3ph, w3pl, A_phi, th_u, A_g);
    // 3: scores (LDS-staged window gather, 16 px / 1024 thr per block)
    hipLaunchKernelGGL(scores_kernel, dim3(256, 4), dim3(1024), 0, stream,
                       A_phi, th_u, sc_f);
    // 4: softmax stats (m, inv) only
    hipLaunchKernelGGL(softmax_stats_kernel, dim3(256), dim3(256), 0, stream,
                       sc_f, m_f, inv_f);
    // 5: fused aggregate + maskconv -> out (LDS-staged A_g window)
    hipLaunchKernelGGL(agg_mask_kernel, dim3(128, 4), dim3(1024), 0, stream,
                       sc_f, m_f, inv_f, A_g, wmph, wmpl, x, out_f);
}

// Round 8
// 154.717 us; speedup vs baseline: 1.1826x; 1.0099x over previous
//
#include <hip/hip_runtime.h>

// Problem: b=4, c=256, ci=128, h=w=64 (HW=4096), field=7, kk=49. fp32 I/O.
//
// 5-dispatch pipeline; MFMA GEMMs (split-bf16 hi+lo) with operands PACKED in
// MFMA-fragment order (fragment = 512 ushorts; lane ln reads 16 B at
// frag_base + ln*16). A-frag elem[ln*8+j] = W[row=ln&15][k=(ln>>4)*8+j];
// B-frag elem[ln*8+j] = M[k=(ln>>4)*8+j][col=ln&15]; C/D col=lane&15,
// row=quad*4+reg (all r10/r11-verified).
//  1. prep: x -> xp_hi/lo packed; w3 -> w3p_hi/lo; wm -> wmp_hi/lo; zero planes.
//  2. conv3_mfma (r7 split): 32-px tile per block, grid (128,3,4).
//  3. scores (r8): fp32 LDS window (cvt in stager) + residue-tracked
//     incremental addresses in pure segments (a += 49 + 8*[r+49>=64]) --
//     addresses identical to the verified decode -> bit-identical.
//  4. softmax_stats: per (b,j,t): m and inv=1/sum only.
//  5. agg_mask (r8): fp32 LDS window; pure-segment loop PAIRED (stride 144
//     elems; sAf[a]/sAf[a+144] and at[t]/at[t+1] fuse to ds_read2_b32).
//     fma order t-ascending, values identical -> bit-identical.
//
// Padded planes: [b][c0][70][72] bf16, data (py,px) at (py+3,px+4), zero
// borders; patch addr for F -> (ch=F>>12, p=F&4095):
//   a = OFF(ch) + p + 8*(p>>6), OFF(ch) = c0*5040 + kh*72 + kw + 1.
// OFF is monotone in ch. Pure-segment residue step: p += 49 (no 4096-wrap),
// crossing iff (p&63)+49 >= 64; a step = 49 or 57.
//
// ws layout (ushort units): unchanged (~40.3 MB total).

#define PLANE    5040
#define A_BATCH  645120

typedef __attribute__((ext_vector_type(8))) short short8;
typedef __attribute__((ext_vector_type(4))) float floatx4;

__device__ __forceinline__ float bf2f(unsigned short u) {
    union { unsigned int i; float f; } v; v.i = ((unsigned int)u) << 16; return v.f;
}
__device__ __forceinline__ unsigned short f2bf(float f) {
    union { float f; unsigned int i; } v; v.f = f;
    unsigned int r = v.i + 0x7FFFu + ((v.i >> 16) & 1u);
    return (unsigned short)(r >> 16);
}

__device__ __forceinline__ unsigned off_of_ch(int ch) {
    int c0 = ch / 49; if (c0 > 127) c0 = 127;
    int rr = ch - c0 * 49;
    int kh = rr / 7;
    int kw = rr - kh * 7;
    return (unsigned)(c0 * PLANE + kh * 72 + kw + 1);
}

// ---------------------------------------------------------------------------
// prep: blocks [0,1024): x fp32 [b][k][p] -> packed hi/lo fragments.
// blocks [1024,1152): w3p/wmp hi/lo packed casts + zero plane regions.
// ---------------------------------------------------------------------------
__global__ __launch_bounds__(256) void prep_kernel(
    const float* __restrict__ x,
    const float* __restrict__ w_phi,
    const float* __restrict__ w_theta,
    const float* __restrict__ w_g,
    const float* __restrict__ w_mask,
    unsigned short* __restrict__ xp_hi,
    unsigned short* __restrict__ xp_lo,
    unsigned short* __restrict__ w3p_hi,
    unsigned short* __restrict__ w3p_lo,
    unsigned short* __restrict__ wmp_hi,
    unsigned short* __restrict__ wmp_lo,
    uint4* __restrict__ zero_region)
{
    const int tid = threadIdx.x;
    const int bx = blockIdx.x;

    if (bx < 1024) {
        const int b  = bx >> 8;          // batch
        const int kt = (bx >> 6) & 3;    // k 64-tile
        const int pt = bx & 63;          // p 64-tile
        __shared__ float tile[64][65];   // [k][p]
        #pragma unroll
        for (int i = 0; i < 16; ++i) {
            int lin = tid + i * 256;
            int kk = lin >> 6, pp = lin & 63;
            tile[kk][pp] = x[(b * 256 + kt * 64 + kk) * 4096 + pt * 64 + pp];
        }
        __syncthreads();
        #pragma unroll
        for (int i = 0; i < 16; ++i) {
            int lin = tid + i * 256;
            int frag = lin >> 9;          // 0..7
            int idx  = lin & 511;
            int kbL  = frag >> 2;         // 0..1
            int ptL  = frag & 3;          // 0..3
            int j    = idx & 7;
            int n    = (idx >> 3) & 15;
            int quad = idx >> 7;
            float f = tile[kbL * 32 + quad * 8 + j][ptL * 16 + n];
            unsigned short h = f2bf(f);
            int addr = ((b * 8 + kt * 2 + kbL) * 256 + pt * 4 + ptL) * 512 + idx;
            xp_hi[addr] = h;
            xp_lo[addr] = f2bf(f - bf2f(h));
        }
    } else {
        const int wid = (bx - 1024) * 256 + tid;   // 0..32767
        for (int e = wid; e < 98304; e += 32768) {
            int frag = e >> 9;            // 0..191
            int idx  = e & 511;
            int nt16 = frag >> 3, kb = frag & 7;
            int j = idx & 7, m = (idx >> 3) & 15, quad = idx >> 7;
            int n = nt16 * 16 + m;
            int k = kb * 32 + quad * 8 + j;
            float v = (n < 128) ? w_phi[n * 256 + k]
                    : (n < 256) ? w_theta[(n - 128) * 256 + k]
                                : w_g[(n - 256) * 256 + k];
            unsigned short h = f2bf(v);
            w3p_hi[e] = h;
            w3p_lo[e] = f2bf(v - bf2f(h));
        }
        {
            int e = wid;                  // exactly covers wmp
            int frag = e >> 9;            // 0..63
            int idx  = e & 511;
            int ot16 = frag >> 2, kb = frag & 3;
            int j = idx & 7, m = (idx >> 3) & 15, quad = idx >> 7;
            float v = w_mask[(ot16 * 16 + m) * 128 + kb * 32 + quad * 8 + j];
            unsigned short h = f2bf(v);
            wmp_hi[e] = h;
            wmp_lo[e] = f2bf(v - bf2f(h));
        }
        const uint4 z = make_uint4(0u, 0u, 0u, 0u);
        for (int i = wid; i < 645120; i += 32768) zero_region[i] = z;
    }
}

// ---------------------------------------------------------------------------
// conv3_mfma (r7 split): one REGION x 32-px tile per block. Grid (128,3,4).
// Same per-acc MFMA order as r0 -> bit-identical.
// ---------------------------------------------------------------------------
__global__ __launch_bounds__(256) void conv3_mfma_kernel(
    const unsigned short* __restrict__ xp_hi,
    const unsigned short* __restrict__ xp_lo,
    const unsigned short* __restrict__ w3p_hi,
    const unsigned short* __restrict__ w3p_lo,
    unsigned short* __restrict__ A_phi,
    unsigned short* __restrict__ theta_bf,
    unsigned short* __restrict__ A_g)
{
    const int tid = threadIdx.x;
    const int w   = tid >> 6;
    const int ln  = tid & 63;
    const int lm  = ln & 15;
    const int quad = ln >> 4;
    const int bx = blockIdx.x;   // 32-px tile
    const int nt = blockIdx.y;   // region 0..2
    const int b  = blockIdx.z;
    const int nt16a = nt * 8 + w;
    const int nt16b = nt * 8 + 4 + w;
    const int lnofs = ln * 8;

    floatx4 accA[2] = {{0.f,0.f,0.f,0.f},{0.f,0.f,0.f,0.f}};
    floatx4 accB[2] = {{0.f,0.f,0.f,0.f},{0.f,0.f,0.f,0.f}};

    #pragma unroll
    for (int kb = 0; kb < 8; ++kb) {
        const int aoffA = (nt16a * 8 + kb) * 512 + lnofs;
        const int aoffB = (nt16b * 8 + kb) * 512 + lnofs;
        const int boff  = ((b * 8 + kb) * 256 + bx * 2) * 512 + lnofs;
        short8 ahA = *reinterpret_cast<const short8*>(w3p_hi + aoffA);
        short8 alA = *reinterpret_cast<const short8*>(w3p_lo + aoffA);
        short8 ahB = *reinterpret_cast<const short8*>(w3p_hi + aoffB);
        short8 alB = *reinterpret_cast<const short8*>(w3p_lo + aoffB);
        short8 bh[2], bl[2];
        #pragma unroll
        for (int ct = 0; ct < 2; ++ct) {
            bh[ct] = *reinterpret_cast<const short8*>(xp_hi + boff + ct * 512);
            bl[ct] = *reinterpret_cast<const short8*>(xp_lo + boff + ct * 512);
        }
        #pragma unroll
        for (int ct = 0; ct < 2; ++ct) {
            accA[ct] = __builtin_amdgcn_mfma_f32_16x16x32_bf16(ahA, bh[ct], accA[ct], 0, 0, 0);
            accA[ct] = __builtin_amdgcn_mfma_f32_16x16x32_bf16(ahA, bl[ct], accA[ct], 0, 0, 0);
            accA[ct] = __builtin_amdgcn_mfma_f32_16x16x32_bf16(alA, bh[ct], accA[ct], 0, 0, 0);
            accB[ct] = __builtin_amdgcn_mfma_f32_16x16x32_bf16(ahB, bh[ct], accB[ct], 0, 0, 0);
            accB[ct] = __builtin_amdgcn_mfma_f32_16x16x32_bf16(ahB, bl[ct], accB[ct], 0, 0, 0);
            accB[ct] = __builtin_amdgcn_mfma_f32_16x16x32_bf16(alB, bh[ct], accB[ct], 0, 0, 0);
        }
    }

    const int py   = bx >> 1;
    const int px32 = (bx & 1) * 32;

    if (nt == 1) {
        #pragma unroll
        for (int ct = 0; ct < 2; ++ct) {
            const int p = bx * 32 + ct * 16 + lm;
            #pragma unroll
            for (int reg = 0; reg < 4; ++reg) {
                const int r = w * 16 + quad * 4 + reg;
                theta_bf[(b * 4096 + p) * 128 + r]      = f2bf(accA[ct][reg]);
                theta_bf[(b * 4096 + p) * 128 + r + 64] = f2bf(accB[ct][reg]);
            }
        }
    } else {
        unsigned short* __restrict__ A = (nt == 0) ? A_phi : A_g;
        #pragma unroll
        for (int ct = 0; ct < 2; ++ct) {
            const int pxx = px32 + ct * 16 + lm;
            const int pbase = (py + 3) * 72 + pxx + 4;
            #pragma unroll
            for (int reg = 0; reg < 4; ++reg) {
                const int r = w * 16 + quad * 4 + reg;
                A[b * A_BATCH + r * PLANE + pbase]        = f2bf(accA[ct][reg]);
                A[b * A_BATCH + (r + 64) * PLANE + pbase] = f2bf(accB[ct][reg]);
            }
        }
    }
}

// ---------------------------------------------------------------------------
// scores (r8): block = (16-px tile, b), 1024 thr, wave = pixel.
// fp32 LDS window (cvt in stager). Pure segments use residue-tracked
// incremental addresses: a += 49 + 8*[(r+49) >= 64] -- identical addresses
// to the verified decode -> bit-identical.
// ---------------------------------------------------------------------------
__global__ __launch_bounds__(1024, 8) void scores_kernel(
    const unsigned short* __restrict__ Apad,
    const unsigned short* __restrict__ theta_bf,
    float* __restrict__ scores)
{
    const int tid = threadIdx.x;
    const int w   = tid >> 6;            // 0..15: wave = pixel
    const int ln  = tid & 63;
    const int s0  = blockIdx.x * 16;
    const int b   = blockIdx.y;
    const int s   = s0 + w;

    __shared__ float th[16][128];
    __shared__ float sAf[9600];

    // stage theta (16 px x 128 cc; 2 per thread)
    {
        int idx = tid * 2;
        int lp = idx >> 7, cc = idx & 127;
        const unsigned short* tb = theta_bf + (b * 4096 + s0 + lp) * 128 + cc;
        th[lp][cc]     = bf2f(tb[0]);
        th[lp][cc + 1] = bf2f(tb[1]);
    }

    // block plane window -> fp32 LDS
    const int chB_lo = (s0 * 6272) >> 12;
    int chB_hi = ((s0 + 15) * 6272 + 6286) >> 12;
    if (chB_hi > 6271) chB_hi = 6271;
    const unsigned a_base = off_of_ch(chB_lo);
    const int cnt = (int)(off_of_ch(chB_hi) + 4599u - a_base) + 1;
    {
        const unsigned short* src = Apad + b * A_BATCH + a_base;
        for (int i = tid; i < cnt; i += 1024) sAf[i] = bf2f(src[i]);
    }
    __syncthreads();

    const int base  = s * 6272;
    const int ch_lo = base >> 12;
    const unsigned B1 = (unsigned)(ch_lo + 1) << 12;
    const unsigned B2 = (unsigned)(ch_lo + 2) << 12;
    const int d1 = (int)B1 - base;
    const int d2 = d1 + 4096;

    int A1 = d1 / 49;
    int A2 = (d1 + 48) / 49;
    int C1 = d2 / 49;        if (C1 > 128) C1 = 128;
    int C2 = (d2 + 48) / 49; if (C2 > 128) C2 = 128;

    unsigned OFFv[3];
    #pragma unroll
    for (int i = 0; i < 3; ++i)
        OFFv[i] = off_of_ch(ch_lo + i) - a_base;

    float acc = 0.f;

    {   // pure segment 0: cc in [0, A1), residue-tracked
        unsigned p = (unsigned)(base + ln) & 4095u;
        unsigned r = p & 63u;
        unsigned a = OFFv[0] + p + ((p >> 6) << 3);
        #pragma unroll 4
        for (int cc = 0; cc < A1; ++cc) {
            acc = fmaf(th[w][cc], sAf[a], acc);
            unsigned rp = r + 49u;
            unsigned c  = rp & 64u;
            r = rp ^ c;
            a += 49u + (c >> 3);
        }
    }
    for (int cc = A1; cc < A2; ++cc) {  // mixed (<=1 iter)
        unsigned F = (unsigned)(base + ln) + 49u * (unsigned)cc;
        unsigned OFF_ = (F >= B1) ? OFFv[1] : OFFv[0];
        unsigned p = F & 4095u;
        unsigned a = OFF_ + p + ((p >> 6) << 3);
        acc = fmaf(th[w][cc], sAf[a], acc);
    }
    {   // pure segment 1: cc in [A2, C1)
        unsigned F = (unsigned)(base + ln) + 49u * (unsigned)A2;
        unsigned p = F & 4095u;
        unsigned r = p & 63u;
        unsigned a = OFFv[1] + p + ((p >> 6) << 3);
        #pragma unroll 4
        for (int cc = A2; cc < C1; ++cc) {
            acc = fmaf(th[w][cc], sAf[a], acc);
            unsigned rp = r + 49u;
            unsigned c  = rp & 64u;
            r = rp ^ c;
            a += 49u + (c >> 3);
        }
    }
    for (int cc = C1; cc < C2; ++cc) {  // mixed (<=1 iter)
        unsigned F = (unsigned)(base + ln) + 49u * (unsigned)cc;
        unsigned OFF_ = (F >= B2) ? OFFv[2] : OFFv[1];
        unsigned p = F & 4095u;
        unsigned a = OFF_ + p + ((p >> 6) << 3);
        acc = fmaf(th[w][cc], sAf[a], acc);
    }
    {   // pure segment 2: cc in [C2, 128)
        unsigned F = (unsigned)(base + ln) + 49u * (unsigned)C2;
        unsigned p = F & 4095u;
        unsigned r = p & 63u;
        unsigned a = OFFv[2] + p + ((p >> 6) << 3);
        #pragma unroll 4
        for (int cc = C2; cc < 128; ++cc) {
            acc = fmaf(th[w][cc], sAf[a], acc);
            unsigned rp = r + 49u;
            unsigned c  = rp & 64u;
            r = rp ^ c;
            a += 49u + (c >> 3);
        }
    }

    if (ln < 49) scores[(b * 4096 + s) * 64 + ln] = acc;
}

// ---------------------------------------------------------------------------
// softmax_stats: per (b,j,t) compute m = max_i sc, inv = 1/sum_i exp(sc-m).
// ---------------------------------------------------------------------------
__global__ __launch_bounds__(256) void softmax_stats_kernel(
    const float* __restrict__ scores,
    float* __restrict__ m_arr,
    float* __restrict__ inv_arr)
{
    const int b = blockIdx.x >> 6;
    const int j = blockIdx.x & 63;
    const int tid = threadIdx.x;
    const int wv = tid >> 6;
    const int ln = tid & 63;

    __shared__ float tile[64][52];

    #pragma unroll
    for (int it = 0; it < 16; ++it) {
        int i = it * 4 + wv;
        if (ln < 49) tile[i][ln] = scores[(b * 4096 + i * 64 + j) * 64 + ln];
    }
    __syncthreads();

    if (tid < 49) {
        float m = -3.4e38f;
        #pragma unroll 8
        for (int i = 0; i < 64; ++i) m = fmaxf(m, tile[i][tid]);
        float sum = 0.f;
        #pragma unroll 8
        for (int i = 0; i < 64; ++i) sum += __expf(tile[i][tid] - m);
        m_arr[(b * 64 + j) * 49 + tid]   = m;
        inv_arr[(b * 64 + j) * 49 + tid] = 1.f / sum;
    }
}

// ---------------------------------------------------------------------------
// agg_mask (r8): 32 pixels/block, 1024 threads, grid (128, 4).
// fp32 LDS window; pure segments PAIRED (stride 144 elems -> ds_read2
// fusable). fma order t-ascending, values identical -> bit-identical.
// ---------------------------------------------------------------------------
__global__ __launch_bounds__(1024) void agg_mask_kernel(
    const float* __restrict__ scores,
    const float* __restrict__ m_arr,
    const float* __restrict__ inv_arr,
    const unsigned short* __restrict__ Apad,
    const unsigned short* __restrict__ wmp_hi,
    const unsigned short* __restrict__ wmp_lo,
    const float* __restrict__ x,
    float* __restrict__ out)
{
    const int tid = threadIdx.x;
    const int blk = blockIdx.x;          // 0..127: pixel tile of 32
    const int b   = blockIdx.y;
    const int P0  = blk * 32;

    __shared__ float at_l[32][52];
    __shared__ unsigned short y_lds[8 * 512];
    __shared__ float sAf[9728];

    // ---- Phase A: attention weights ----
    const int j0 = P0 & 63;
    #pragma unroll
    for (int it = 0; it < 2; ++it) {
        int idx = tid + it * 1024;
        int lp = idx >> 6;
        int t  = idx & 63;
        if (t < 49) {
            const int s = P0 + lp;
            const int j = j0 + lp;
            float sc = scores[(b * 4096 + s) * 64 + t];
            float m  = m_arr[(b * 64 + j) * 49 + t];
            float iv = inv_arr[(b * 64 + j) * 49 + t];
            at_l[lp][t] = __expf(sc - m) * iv;
        }
    }

    // ---- stage A_g window -> fp32 LDS ----
    const int chB_lo = (P0 * 6272) >> 12;
    int chB_hi = ((P0 + 31) * 6272 + 6271) >> 12;
    if (chB_hi > 6271) chB_hi = 6271;
    const unsigned a_base = off_of_ch(chB_lo);
    const int cnt = (int)(off_of_ch(chB_hi) + 4599u - a_base) + 1;  // <= 9640
    {
        const unsigned short* src = Apad + b * A_BATCH + a_base;
        for (int i = tid; i < cnt; i += 1024) sAf[i] = bf2f(src[i]);
    }
    __syncthreads();

    // ---- Phase B: gather y from LDS (paired; addresses identical) ----
    const int pq = tid >> 7;             // 0..7
    const int cc = tid & 127;

    #pragma unroll
    for (int rep = 0; rep < 4; ++rep) {
        const int lp = rep * 8 + pq;     // 0..31
        const int s  = P0 + lp;
        const float* at_row = at_l[lp];

        const int base  = s * 6272;
        const int ch_lo = base >> 12;
        const unsigned B1 = (unsigned)(ch_lo + 1) << 12;
        const unsigned B2 = (unsigned)(ch_lo + 2) << 12;
        const int d1 = (int)B1 - base;
        const int d2 = d1 + 4096;

        int A1 = d1 >> 7;
        int A2 = (d1 + 127) >> 7;
        int C1 = d2 >> 7;          if (C1 > 49) C1 = 49;
        int C2 = (d2 + 127) >> 7;  if (C2 > 49) C2 = 49;
        if (A1 > 49) A1 = 49;
        if (A2 > 49) A2 = 49;

        unsigned OFFv[3];
        #pragma unroll
        for (int i = 0; i < 3; ++i)
            OFFv[i] = off_of_ch(ch_lo + i) - a_base;

        float acc = 0.f;

        {   // pure segment 0: t in [0, A1), paired, affine a += 144
            unsigned p0 = (unsigned)(base + cc) & 4095u;
            unsigned a = OFFv[0] + p0 + ((p0 >> 6) << 3);
            int t = 0;
            for (; t + 1 < A1; t += 2) {
                float v0 = sAf[a];
                float v1 = sAf[a + 144];
                acc = fmaf(at_row[t], v0, acc);
                acc = fmaf(at_row[t + 1], v1, acc);
                a += 288u;
            }
            if (t < A1) { acc = fmaf(at_row[t], sAf[a], acc); }
        }
        for (int t = A1; t < A2; ++t) {  // mixed (<=1 iter)
            unsigned F = (unsigned)(base + cc) + 128u * (unsigned)t;
            unsigned OFF_ = (F >= B1) ? OFFv[1] : OFFv[0];
            unsigned p = F & 4095u;
            unsigned a = OFF_ + p + ((p >> 6) << 3);
            acc = fmaf(at_row[t], sAf[a], acc);
        }
        {   // pure segment 1: t in [A2, C1), paired
            unsigned F = (unsigned)(base + cc) + 128u * (unsigned)A2;
            unsigned p0 = F & 4095u;
            unsigned a = OFFv[1] + p0 + ((p0 >> 6) << 3);
            int t = A2;
            for (; t + 1 < C1; t += 2) {
                float v0 = sAf[a];
                float v1 = sAf[a + 144];
                acc = fmaf(at_row[t], v0, acc);
                acc = fmaf(at_row[t + 1], v1, acc);
                a += 288u;
            }
            if (t < C1) { acc = fmaf(at_row[t], sAf[a], acc); }
        }
        for (int t = C1; t < C2; ++t) {  // mixed (<=1 iter)
            unsigned F = (unsigned)(base + cc) + 128u * (unsigned)t;
            unsigned OFF_ = (F >= B2) ? OFFv[2] : OFFv[1];
            unsigned p = F & 4095u;
            unsigned a = OFF_ + p + ((p >> 6) << 3);
            acc = fmaf(at_row[t], sAf[a], acc);
        }
        {   // pure segment 2: t in [C2, 49), paired
            unsigned F = (unsigned)(base + cc) + 128u * (unsigned)C2;
            unsigned p0 = F & 4095u;
            unsigned a = OFFv[2] + p0 + ((p0 >> 6) << 3);
            int t = C2;
            for (; t + 1 < 49; t += 2) {
                float v0 = sAf[a];
                float v1 = sAf[a + 144];
                acc = fmaf(at_row[t], v0, acc);
                acc = fmaf(at_row[t + 1], v1, acc);
                a += 288u;
            }
            if (t < 49) { acc = fmaf(at_row[t], sAf[a], acc); }
        }

        // pack into LDS B-frag order
        const int kb = cc >> 5, k32 = cc & 31;
        const int quad = k32 >> 3, jx = k32 & 7;
        const int ct = lp >> 4, n = lp & 15;
        y_lds[(kb * 2 + ct) * 512 + (quad * 16 + n) * 8 + jx] = f2bf(acc);
    }
    __syncthreads();

    // ---- Phase C: maskconv MFMA (16 waves, 1 o-tile each) ----
    const int w    = tid >> 6;           // 0..15
    const int ln   = tid & 63;
    const int lm   = ln & 15;
    const int quad = ln >> 4;
    const int lnofs = ln * 8;

    floatx4 accA[2] = {{0.f,0.f,0.f,0.f},{0.f,0.f,0.f,0.f}};

    #pragma unroll
    for (int kb = 0; kb < 4; ++kb) {
        const int aoffA = (w * 4 + kb) * 512 + lnofs;
        short8 ahA = *reinterpret_cast<const short8*>(wmp_hi + aoffA);
        short8 alA = *reinterpret_cast<const short8*>(wmp_lo + aoffA);
        short8 bf[2];
        #pragma unroll
        for (int ct = 0; ct < 2; ++ct)
            bf[ct] = *reinterpret_cast<const short8*>(
                y_lds + (kb * 2 + ct) * 512 + lnofs);
        #pragma unroll
        for (int ct = 0; ct < 2; ++ct) {
            accA[ct] = __builtin_amdgcn_mfma_f32_16x16x32_bf16(ahA, bf[ct], accA[ct], 0, 0, 0);
            accA[ct] = __builtin_amdgcn_mfma_f32_16x16x32_bf16(alA, bf[ct], accA[ct], 0, 0, 0);
        }
    }

    #pragma unroll
    for (int ct = 0; ct < 2; ++ct) {
        const int p = P0 + ct * 16 + lm;
        #pragma unroll
        for (int reg = 0; reg < 4; ++reg) {
            const int oA = w * 16 + quad * 4 + reg;
            const int ofsA = (b * 256 + oA) * 4096 + p;
            out[ofsA] = accA[ct][reg] + x[ofsA];
        }
    }
}

extern "C" void kernel_launch(void* const* d_in, const int* in_sizes, int n_in,
                              void* d_out, int out_size, void* d_ws, size_t ws_size,
                              hipStream_t stream) {
    const float* x       = (const float*)d_in[0];
    const float* w_phi   = (const float*)d_in[1];
    const float* w_theta = (const float*)d_in[2];
    const float* w_g     = (const float*)d_in[3];
    const float* w_mask  = (const float*)d_in[4];

    float* out_f = (float*)d_out;

    unsigned short* ws_u  = (unsigned short*)d_ws;
    unsigned short* A_phi = ws_u;                      // 2,580,480 ush
    unsigned short* A_g   = ws_u + 2580480;            // 2,580,480 ush
    unsigned short* th_u  = ws_u + 7258112;            // 2,097,152 ush
    float*          sc_f  = (float*)(ws_u + 9355264);  // 1,048,576 fp32
    unsigned short* xph   = ws_u + 11452416;           // 4,194,304 ush
    unsigned short* xpl   = ws_u + 15646720;           // 4,194,304 ush
    unsigned short* w3ph  = ws_u + 19841024;           // 98,304 ush
    unsigned short* w3pl  = ws_u + 19939328;           // 98,304 ush
    unsigned short* wmph  = ws_u + 20037632;           // 32,768 ush
    unsigned short* wmpl  = ws_u + 20070400;           // 32,768 ush
    float*          m_f   = (float*)(ws_u + 20103168); // 12,544 fp32
    float*          inv_f = (float*)(ws_u + 20128256); // 12,544 fp32

    // 1: prep (packed operand build + zero planes)
    hipLaunchKernelGGL(prep_kernel, dim3(1152), dim3(256), 0, stream,
                       x, w_phi, w_theta, w_g, w_mask,
                       xph, xpl, w3ph, w3pl, wmph, wmpl, (uint4*)A_phi);
    // 2: conv3 split-tile MFMA (32 px/block)
    hipLaunchKernelGGL(conv3_mfma_kernel, dim3(128, 3, 4), dim3(256), 0, stream,
                       xph, xpl, w3ph, w3pl, A_phi, th_u, A_g);
    // 3: scores (fp32 LDS window + residue-tracked addresses)
    hipLaunchKernelGGL(scores_kernel, dim3(256, 4), dim3(1024), 0, stream,
                       A_phi, th_u, sc_f);
    // 4: softmax stats (m, inv) only
    hipLaunchKernelGGL(softmax_stats_kernel, dim3(256), dim3(256), 0, stream,
                       sc_f, m_f, inv_f);
    // 5: fused aggregate + maskconv -> out (fp32 window, paired reads)
    hipLaunchKernelGGL(agg_mask_kernel, dim3(128, 4), dim3(1024), 0, stream,
                       sc_f, m_f, inv_f, A_g, wmph, wmpl, x, out_f);
}

// Round 10
// 154.265 us; speedup vs baseline: 1.1861x; 1.0029x over previous
//
#include <hip/hip_runtime.h>

// Problem: b=4, c=256, ci=128, h=w=64 (HW=4096), field=7, kk=49. fp32 I/O.
//
// 5-dispatch pipeline (r8-verified) + r10: vectorized LDS coefficient
// broadcasts in the two gather kernels (same values, same fma order ->
// bit-identical output).
//  1. prep: x -> xp_hi/lo packed; w3 -> w3p_hi/lo; wm -> wmp_hi/lo; zero planes.
//  2. conv3_mfma (r7 split): 32-px tile per block, grid (128,3,4).
//  3. scores (r10): fp32 LDS window + residue-tracked addresses; theta
//     broadcast fetched 4-wide (ds_read_b128) in 4-aligned segment bodies.
//  4. softmax_stats: per (b,j,t): m and inv=1/sum only.
//  5. agg_mask (r10): fp32 LDS window; paired pure segments with at-pair
//     fetched 2-wide (ds_read_b64) on even-t bodies.
//
// Padded planes: [b][c0][70][72] bf16, data (py,px) at (py+3,px+4), zero
// borders; patch addr for F -> (ch=F>>12, p=F&4095):
//   a = OFF(ch) + p + 8*(p>>6), OFF(ch) = c0*5040 + kh*72 + kw + 1.
// OFF is monotone in ch. Pure-segment residue step: p += 49 (no 4096-wrap),
// crossing iff (p&63)+49 >= 64; a step = 49 or 57. Agg stride: a += 144.
//
// ws layout (ushort units): unchanged (~40.3 MB total).

#define PLANE    5040
#define A_BATCH  645120

typedef __attribute__((ext_vector_type(8))) short short8;
typedef __attribute__((ext_vector_type(4))) float floatx4;
typedef __attribute__((ext_vector_type(2))) float floatx2;

__device__ __forceinline__ float bf2f(unsigned short u) {
    union { unsigned int i; float f; } v; v.i = ((unsigned int)u) << 16; return v.f;
}
__device__ __forceinline__ unsigned short f2bf(float f) {
    union { float f; unsigned int i; } v; v.f = f;
    unsigned int r = v.i + 0x7FFFu + ((v.i >> 16) & 1u);
    return (unsigned short)(r >> 16);
}

__device__ __forceinline__ unsigned off_of_ch(int ch) {
    int c0 = ch / 49; if (c0 > 127) c0 = 127;
    int rr = ch - c0 * 49;
    int kh = rr / 7;
    int kw = rr - kh * 7;
    return (unsigned)(c0 * PLANE + kh * 72 + kw + 1);
}

// ---------------------------------------------------------------------------
// prep: blocks [0,1024): x fp32 [b][k][p] -> packed hi/lo fragments.
// blocks [1024,1152): w3p/wmp hi/lo packed casts + zero plane regions.
// ---------------------------------------------------------------------------
__global__ __launch_bounds__(256) void prep_kernel(
    const float* __restrict__ x,
    const float* __restrict__ w_phi,
    const float* __restrict__ w_theta,
    const float* __restrict__ w_g,
    const float* __restrict__ w_mask,
    unsigned short* __restrict__ xp_hi,
    unsigned short* __restrict__ xp_lo,
    unsigned short* __restrict__ w3p_hi,
    unsigned short* __restrict__ w3p_lo,
    unsigned short* __restrict__ wmp_hi,
    unsigned short* __restrict__ wmp_lo,
    uint4* __restrict__ zero_region)
{
    const int tid = threadIdx.x;
    const int bx = blockIdx.x;

    if (bx < 1024) {
        const int b  = bx >> 8;          // batch
        const int kt = (bx >> 6) & 3;    // k 64-tile
        const int pt = bx & 63;          // p 64-tile
        __shared__ float tile[64][65];   // [k][p]
        #pragma unroll
        for (int i = 0; i < 16; ++i) {
            int lin = tid + i * 256;
            int kk = lin >> 6, pp = lin & 63;
            tile[kk][pp] = x[(b * 256 + kt * 64 + kk) * 4096 + pt * 64 + pp];
        }
        __syncthreads();
        #pragma unroll
        for (int i = 0; i < 16; ++i) {
            int lin = tid + i * 256;
            int frag = lin >> 9;          // 0..7
            int idx  = lin & 511;
            int kbL  = frag >> 2;         // 0..1
            int ptL  = frag & 3;          // 0..3
            int j    = idx & 7;
            int n    = (idx >> 3) & 15;
            int quad = idx >> 7;
            float f = tile[kbL * 32 + quad * 8 + j][ptL * 16 + n];
            unsigned short h = f2bf(f);
            int addr = ((b * 8 + kt * 2 + kbL) * 256 + pt * 4 + ptL) * 512 + idx;
            xp_hi[addr] = h;
            xp_lo[addr] = f2bf(f - bf2f(h));
        }
    } else {
        const int wid = (bx - 1024) * 256 + tid;   // 0..32767
        for (int e = wid; e < 98304; e += 32768) {
            int frag = e >> 9;            // 0..191
            int idx  = e & 511;
            int nt16 = frag >> 3, kb = frag & 7;
            int j = idx & 7, m = (idx >> 3) & 15, quad = idx >> 7;
            int n = nt16 * 16 + m;
            int k = kb * 32 + quad * 8 + j;
            float v = (n < 128) ? w_phi[n * 256 + k]
                    : (n < 256) ? w_theta[(n - 128) * 256 + k]
                                : w_g[(n - 256) * 256 + k];
            unsigned short h = f2bf(v);
            w3p_hi[e] = h;
            w3p_lo[e] = f2bf(v - bf2f(h));
        }
        {
            int e = wid;                  // exactly covers wmp
            int frag = e >> 9;            // 0..63
            int idx  = e & 511;
            int ot16 = frag >> 2, kb = frag & 3;
            int j = idx & 7, m = (idx >> 3) & 15, quad = idx >> 7;
            float v = w_mask[(ot16 * 16 + m) * 128 + kb * 32 + quad * 8 + j];
            unsigned short h = f2bf(v);
            wmp_hi[e] = h;
            wmp_lo[e] = f2bf(v - bf2f(h));
        }
        const uint4 z = make_uint4(0u, 0u, 0u, 0u);
        for (int i = wid; i < 645120; i += 32768) zero_region[i] = z;
    }
}

// ---------------------------------------------------------------------------
// conv3_mfma (r7 split): one REGION x 32-px tile per block. Grid (128,3,4).
// Same per-acc MFMA order as r0 -> bit-identical.
// ---------------------------------------------------------------------------
__global__ __launch_bounds__(256) void conv3_mfma_kernel(
    const unsigned short* __restrict__ xp_hi,
    const unsigned short* __restrict__ xp_lo,
    const unsigned short* __restrict__ w3p_hi,
    const unsigned short* __restrict__ w3p_lo,
    unsigned short* __restrict__ A_phi,
    unsigned short* __restrict__ theta_bf,
    unsigned short* __restrict__ A_g)
{
    const int tid = threadIdx.x;
    const int w   = tid >> 6;
    const int ln  = tid & 63;
    const int lm  = ln & 15;
    const int quad = ln >> 4;
    const int bx = blockIdx.x;   // 32-px tile
    const int nt = blockIdx.y;   // region 0..2
    const int b  = blockIdx.z;
    const int nt16a = nt * 8 + w;
    const int nt16b = nt * 8 + 4 + w;
    const int lnofs = ln * 8;

    floatx4 accA[2] = {{0.f,0.f,0.f,0.f},{0.f,0.f,0.f,0.f}};
    floatx4 accB[2] = {{0.f,0.f,0.f,0.f},{0.f,0.f,0.f,0.f}};

    #pragma unroll
    for (int kb = 0; kb < 8; ++kb) {
        const int aoffA = (nt16a * 8 + kb) * 512 + lnofs;
        const int aoffB = (nt16b * 8 + kb) * 512 + lnofs;
        const int boff  = ((b * 8 + kb) * 256 + bx * 2) * 512 + lnofs;
        short8 ahA = *reinterpret_cast<const short8*>(w3p_hi + aoffA);
        short8 alA = *reinterpret_cast<const short8*>(w3p_lo + aoffA);
        short8 ahB = *reinterpret_cast<const short8*>(w3p_hi + aoffB);
        short8 alB = *reinterpret_cast<const short8*>(w3p_lo + aoffB);
        short8 bh[2], bl[2];
        #pragma unroll
        for (int ct = 0; ct < 2; ++ct) {
            bh[ct] = *reinterpret_cast<const short8*>(xp_hi + boff + ct * 512);
            bl[ct] = *reinterpret_cast<const short8*>(xp_lo + boff + ct * 512);
        }
        #pragma unroll
        for (int ct = 0; ct < 2; ++ct) {
            accA[ct] = __builtin_amdgcn_mfma_f32_16x16x32_bf16(ahA, bh[ct], accA[ct], 0, 0, 0);
            accA[ct] = __builtin_amdgcn_mfma_f32_16x16x32_bf16(ahA, bl[ct], accA[ct], 0, 0, 0);
            accA[ct] = __builtin_amdgcn_mfma_f32_16x16x32_bf16(alA, bh[ct], accA[ct], 0, 0, 0);
            accB[ct] = __builtin_amdgcn_mfma_f32_16x16x32_bf16(ahB, bh[ct], accB[ct], 0, 0, 0);
            accB[ct] = __builtin_amdgcn_mfma_f32_16x16x32_bf16(ahB, bl[ct], accB[ct], 0, 0, 0);
            accB[ct] = __builtin_amdgcn_mfma_f32_16x16x32_bf16(alB, bh[ct], accB[ct], 0, 0, 0);
        }
    }

    const int py   = bx >> 1;
    const int px32 = (bx & 1) * 32;

    if (nt == 1) {
        #pragma unroll
        for (int ct = 0; ct < 2; ++ct) {
            const int p = bx * 32 + ct * 16 + lm;
            #pragma unroll
            for (int reg = 0; reg < 4; ++reg) {
                const int r = w * 16 + quad * 4 + reg;
                theta_bf[(b * 4096 + p) * 128 + r]      = f2bf(accA[ct][reg]);
                theta_bf[(b * 4096 + p) * 128 + r + 64] = f2bf(accB[ct][reg]);
            }
        }
    } else {
        unsigned short* __restrict__ A = (nt == 0) ? A_phi : A_g;
        #pragma unroll
        for (int ct = 0; ct < 2; ++ct) {
            const int pxx = px32 + ct * 16 + lm;
            const int pbase = (py + 3) * 72 + pxx + 4;
            #pragma unroll
            for (int reg = 0; reg < 4; ++reg) {
                const int r = w * 16 + quad * 4 + reg;
                A[b * A_BATCH + r * PLANE + pbase]        = f2bf(accA[ct][reg]);
                A[b * A_BATCH + (r + 64) * PLANE + pbase] = f2bf(accB[ct][reg]);
            }
        }
    }
}

// ---------------------------------------------------------------------------
// scores (r10): block = (16-px tile, b), 1024 thr, wave = pixel.
// fp32 LDS window; residue-tracked incremental addresses; theta broadcast
// fetched 4-wide in 4-aligned segment bodies (values/order identical).
// ---------------------------------------------------------------------------
__global__ __launch_bounds__(1024, 8) void scores_kernel(
    const unsigned short* __restrict__ Apad,
    const unsigned short* __restrict__ theta_bf,
    float* __restrict__ scores)
{
    const int tid = threadIdx.x;
    const int w   = tid >> 6;            // 0..15: wave = pixel
    const int ln  = tid & 63;
    const int s0  = blockIdx.x * 16;
    const int b   = blockIdx.y;
    const int s   = s0 + w;

    __shared__ float th[16][128];
    __shared__ float sAf[9600];

    // stage theta (16 px x 128 cc; 2 per thread)
    {
        int idx = tid * 2;
        int lp = idx >> 7, cc = idx & 127;
        const unsigned short* tb = theta_bf + (b * 4096 + s0 + lp) * 128 + cc;
        th[lp][cc]     = bf2f(tb[0]);
        th[lp][cc + 1] = bf2f(tb[1]);
    }

    // block plane window -> fp32 LDS
    const int chB_lo = (s0 * 6272) >> 12;
    int chB_hi = ((s0 + 15) * 6272 + 6286) >> 12;
    if (chB_hi > 6271) chB_hi = 6271;
    const unsigned a_base = off_of_ch(chB_lo);
    const int cnt = (int)(off_of_ch(chB_hi) + 4599u - a_base) + 1;
    {
        const unsigned short* src = Apad + b * A_BATCH + a_base;
        for (int i = tid; i < cnt; i += 1024) sAf[i] = bf2f(src[i]);
    }
    __syncthreads();

    const int base  = s * 6272;
    const int ch_lo = base >> 12;
    const unsigned B1 = (unsigned)(ch_lo + 1) << 12;
    const unsigned B2 = (unsigned)(ch_lo + 2) << 12;
    const int d1 = (int)B1 - base;
    const int d2 = d1 + 4096;

    int A1 = d1 / 49;
    int A2 = (d1 + 48) / 49;
    int C1 = d2 / 49;        if (C1 > 128) C1 = 128;
    int C2 = (d2 + 48) / 49; if (C2 > 128) C2 = 128;

    unsigned OFFv[3];
    #pragma unroll
    for (int i = 0; i < 3; ++i)
        OFFv[i] = off_of_ch(ch_lo + i) - a_base;

    float acc = 0.f;

    {   // pure segment 0: cc in [0, A1) -- starts 4-aligned
        unsigned p = (unsigned)(base + ln) & 4095u;
        unsigned r = p & 63u;
        unsigned a = OFFv[0] + p + ((p >> 6) << 3);
        int cc = 0;
        for (; cc + 3 < A1; cc += 4) {
            floatx4 tv = *reinterpret_cast<const floatx4*>(&th[w][cc]);
            #pragma unroll
            for (int q = 0; q < 4; ++q) {
                acc = fmaf(tv[q], sAf[a], acc);
                unsigned rp = r + 49u;
                unsigned c  = rp & 64u;
                r = rp ^ c;
                a += 49u + (c >> 3);
            }
        }
        for (; cc < A1; ++cc) {
            acc = fmaf(th[w][cc], sAf[a], acc);
            unsigned rp = r + 49u;
            unsigned c  = rp & 64u;
            r = rp ^ c;
            a += 49u + (c >> 3);
        }
    }
    for (int cc = A1; cc < A2; ++cc) {  // mixed (<=1 iter)
        unsigned F = (unsigned)(base + ln) + 49u * (unsigned)cc;
        unsigned OFF_ = (F >= B1) ? OFFv[1] : OFFv[0];
        unsigned p = F & 4095u;
        unsigned a = OFF_ + p + ((p >> 6) << 3);
        acc = fmaf(th[w][cc], sAf[a], acc);
    }
    {   // pure segment 1: cc in [A2, C1), head to 4-align
        unsigned F = (unsigned)(base + ln) + 49u * (unsigned)A2;
        unsigned p = F & 4095u;
        unsigned r = p & 63u;
        unsigned a = OFFv[1] + p + ((p >> 6) << 3);
        int cc = A2;
        for (; cc < C1 && (cc & 3); ++cc) {
            acc = fmaf(th[w][cc], sAf[a], acc);
            unsigned rp = r + 49u;
            unsigned c  = rp & 64u;
            r = rp ^ c;
            a += 49u + (c >> 3);
        }
        for (; cc + 3 < C1; cc += 4) {
            floatx4 tv = *reinterpret_cast<const floatx4*>(&th[w][cc]);
            #pragma unroll
            for (int q = 0; q < 4; ++q) {
                acc = fmaf(tv[q], sAf[a], acc);
                unsigned rp = r + 49u;
                unsigned c  = rp & 64u;
                r = rp ^ c;
                a += 49u + (c >> 3);
            }
        }
        for (; cc < C1; ++cc) {
            acc = fmaf(th[w][cc], sAf[a], acc);
            unsigned rp = r + 49u;
            unsigned c  = rp & 64u;
            r = rp ^ c;
            a += 49u + (c >> 3);
        }
    }
    for (int cc = C1; cc < C2; ++cc) {  // mixed (<=1 iter)
        unsigned F = (unsigned)(base + ln) + 49u * (unsigned)cc;
        unsigned OFF_ = (F >= B2) ? OFFv[2] : OFFv[1];
        unsigned p = F & 4095u;
        unsigned a = OFF_ + p + ((p >> 6) << 3);
        acc = fmaf(th[w][cc], sAf[a], acc);
    }
    {   // pure segment 2: cc in [C2, 128), head to 4-align
        unsigned F = (unsigned)(base + ln) + 49u * (unsigned)C2;
        unsigned p = F & 4095u;
        unsigned r = p & 63u;
        unsigned a = OFFv[2] + p + ((p >> 6) << 3);
        int cc = C2;
        for (; cc < 128 && (cc & 3); ++cc) {
            acc = fmaf(th[w][cc], sAf[a], acc);
            unsigned rp = r + 49u;
            unsigned c  = rp & 64u;
            r = rp ^ c;
            a += 49u + (c >> 3);
        }
        for (; cc + 3 < 128; cc += 4) {
            floatx4 tv = *reinterpret_cast<const floatx4*>(&th[w][cc]);
            #pragma unroll
            for (int q = 0; q < 4; ++q) {
                acc = fmaf(tv[q], sAf[a], acc);
                unsigned rp = r + 49u;
                unsigned c  = rp & 64u;
                r = rp ^ c;
                a += 49u + (c >> 3);
            }
        }
        for (; cc < 128; ++cc) {
            acc = fmaf(th[w][cc], sAf[a], acc);
            unsigned rp = r + 49u;
            unsigned c  = rp & 64u;
            r = rp ^ c;
            a += 49u + (c >> 3);
        }
    }

    if (ln < 49) scores[(b * 4096 + s) * 64 + ln] = acc;
}

// ---------------------------------------------------------------------------
// softmax_stats: per (b,j,t) compute m = max_i sc, inv = 1/sum_i exp(sc-m).
// ---------------------------------------------------------------------------
__global__ __launch_bounds__(256) void softmax_stats_kernel(
    const float* __restrict__ scores,
    float* __restrict__ m_arr,
    float* __restrict__ inv_arr)
{
    const int b = blockIdx.x >> 6;
    const int j = blockIdx.x & 63;
    const int tid = threadIdx.x;
    const int wv = tid >> 6;
    const int ln = tid & 63;

    __shared__ float tile[64][52];

    #pragma unroll
    for (int it = 0; it < 16; ++it) {
        int i = it * 4 + wv;
        if (ln < 49) tile[i][ln] = scores[(b * 4096 + i * 64 + j) * 64 + ln];
    }
    __syncthreads();

    if (tid < 49) {
        float m = -3.4e38f;
        #pragma unroll 8
        for (int i = 0; i < 64; ++i) m = fmaxf(m, tile[i][tid]);
        float sum = 0.f;
        #pragma unroll 8
        for (int i = 0; i < 64; ++i) sum += __expf(tile[i][tid] - m);
        m_arr[(b * 64 + j) * 49 + tid]   = m;
        inv_arr[(b * 64 + j) * 49 + tid] = 1.f / sum;
    }
}

// ---------------------------------------------------------------------------
// agg_mask (r10): 32 pixels/block, 1024 threads, grid (128, 4).
// fp32 LDS window; paired pure segments with 2-wide at reads on even-t
// bodies (parity head keeps values/order identical -> bit-identical).
// ---------------------------------------------------------------------------
__global__ __launch_bounds__(1024) void agg_mask_kernel(
    const float* __restrict__ scores,
    const float* __restrict__ m_arr,
    const float* __restrict__ inv_arr,
    const unsigned short* __restrict__ Apad,
    const unsigned short* __restrict__ wmp_hi,
    const unsigned short* __restrict__ wmp_lo,
    const float* __restrict__ x,
    float* __restrict__ out)
{
    const int tid = threadIdx.x;
    const int blk = blockIdx.x;          // 0..127: pixel tile of 32
    const int b   = blockIdx.y;
    const int P0  = blk * 32;

    __shared__ float at_l[32][52];
    __shared__ unsigned short y_lds[8 * 512];
    __shared__ float sAf[9728];

    // ---- Phase A: attention weights ----
    const int j0 = P0 & 63;
    #pragma unroll
    for (int it = 0; it < 2; ++it) {
        int idx = tid + it * 1024;
        int lp = idx >> 6;
        int t  = idx & 63;
        if (t < 49) {
            const int s = P0 + lp;
            const int j = j0 + lp;
            float sc = scores[(b * 4096 + s) * 64 + t];
            float m  = m_arr[(b * 64 + j) * 49 + t];
            float iv = inv_arr[(b * 64 + j) * 49 + t];
            at_l[lp][t] = __expf(sc - m) * iv;
        }
    }

    // ---- stage A_g window -> fp32 LDS ----
    const int chB_lo = (P0 * 6272) >> 12;
    int chB_hi = ((P0 + 31) * 6272 + 6271) >> 12;
    if (chB_hi > 6271) chB_hi = 6271;
    const unsigned a_base = off_of_ch(chB_lo);
    const int cnt = (int)(off_of_ch(chB_hi) + 4599u - a_base) + 1;  // <= 9640
    {
        const unsigned short* src = Apad + b * A_BATCH + a_base;
        for (int i = tid; i < cnt; i += 1024) sAf[i] = bf2f(src[i]);
    }
    __syncthreads();

    // ---- Phase B: gather y from LDS (paired; addresses identical) ----
    const int pq = tid >> 7;             // 0..7
    const int cc = tid & 127;

    #pragma unroll
    for (int rep = 0; rep < 4; ++rep) {
        const int lp = rep * 8 + pq;     // 0..31
        const int s  = P0 + lp;
        const float* at_row = at_l[lp];

        const int base  = s * 6272;
        const int ch_lo = base >> 12;
        const unsigned B1 = (unsigned)(ch_lo + 1) << 12;
        const unsigned B2 = (unsigned)(ch_lo + 2) << 12;
        const int d1 = (int)B1 - base;
        const int d2 = d1 + 4096;

        int A1 = d1 >> 7;
        int A2 = (d1 + 127) >> 7;
        int C1 = d2 >> 7;          if (C1 > 49) C1 = 49;
        int C2 = (d2 + 127) >> 7;  if (C2 > 49) C2 = 49;
        if (A1 > 49) A1 = 49;
        if (A2 > 49) A2 = 49;

        unsigned OFFv[3];
        #pragma unroll
        for (int i = 0; i < 3; ++i)
            OFFv[i] = off_of_ch(ch_lo + i) - a_base;

        float acc = 0.f;

        {   // pure segment 0: t in [0, A1) -- starts even
            unsigned p0 = (unsigned)(base + cc) & 4095u;
            unsigned a = OFFv[0] + p0 + ((p0 >> 6) << 3);
            int t = 0;
            for (; t + 1 < A1; t += 2) {
                floatx2 av = *reinterpret_cast<const floatx2*>(&at_row[t]);
                float v0 = sAf[a];
                float v1 = sAf[a + 144];
                acc = fmaf(av[0], v0, acc);
                acc = fmaf(av[1], v1, acc);
                a += 288u;
            }
            if (t < A1) { acc = fmaf(at_row[t], sAf[a], acc); }
        }
        for (int t = A1; t < A2; ++t) {  // mixed (<=1 iter)
            unsigned F = (unsigned)(base + cc) + 128u * (unsigned)t;
            unsigned OFF_ = (F >= B1) ? OFFv[1] : OFFv[0];
            unsigned p = F & 4095u;
            unsigned a = OFF_ + p + ((p >> 6) << 3);
            acc = fmaf(at_row[t], sAf[a], acc);
        }
        {   // pure segment 1: t in [A2, C1), parity head
            unsigned F = (unsigned)(base + cc) + 128u * (unsigned)A2;
            unsigned p0 = F & 4095u;
            unsigned a = OFFv[1] + p0 + ((p0 >> 6) << 3);
            int t = A2;
            if ((t & 1) && t < C1) {
                acc = fmaf(at_row[t], sAf[a], acc);
                a += 144u;
                ++t;
            }
            for (; t + 1 < C1; t += 2) {
                floatx2 av = *reinterpret_cast<const floatx2*>(&at_row[t]);
                float v0 = sAf[a];
                float v1 = sAf[a + 144];
                acc = fmaf(av[0], v0, acc);
                acc = fmaf(av[1], v1, acc);
                a += 288u;
            }
            if (t < C1) { acc = fmaf(at_row[t], sAf[a], acc); }
        }
        for (int t = C1; t < C2; ++t) {  // mixed (<=1 iter)
            unsigned F = (unsigned)(base + cc) + 128u * (unsigned)t;
            unsigned OFF_ = (F >= B2) ? OFFv[2] : OFFv[1];
            unsigned p = F & 4095u;
            unsigned a = OFF_ + p + ((p >> 6) << 3);
            acc = fmaf(at_row[t], sAf[a], acc);
        }
        {   // pure segment 2: t in [C2, 49), parity head
            unsigned F = (unsigned)(base + cc) + 128u * (unsigned)C2;
            unsigned p0 = F & 4095u;
            unsigned a = OFFv[2] + p0 + ((p0 >> 6) << 3);
            int t = C2;
            if ((t & 1) && t < 49) {
                acc = fmaf(at_row[t], sAf[a], acc);
                a += 144u;
                ++t;
            }
            for (; t + 1 < 49; t += 2) {
                floatx2 av = *reinterpret_cast<const floatx2*>(&at_row[t]);
                float v0 = sAf[a];
                float v1 = sAf[a + 144];
                acc = fmaf(av[0], v0, acc);
                acc = fmaf(av[1], v1, acc);
                a += 288u;
            }
            if (t < 49) { acc = fmaf(at_row[t], sAf[a], acc); }
        }

        // pack into LDS B-frag order
        const int kb = cc >> 5, k32 = cc & 31;
        const int quad = k32 >> 3, jx = k32 & 7;
        const int ct = lp >> 4, n = lp & 15;
        y_lds[(kb * 2 + ct) * 512 + (quad * 16 + n) * 8 + jx] = f2bf(acc);
    }
    __syncthreads();

    // ---- Phase C: maskconv MFMA (16 waves, 1 o-tile each) ----
    const int w    = tid >> 6;           // 0..15
    const int ln   = tid & 63;
    const int lm   = ln & 15;
    const int quad = ln >> 4;
    const int lnofs = ln * 8;

    floatx4 accA[2] = {{0.f,0.f,0.f,0.f},{0.f,0.f,0.f,0.f}};

    #pragma unroll
    for (int kb = 0; kb < 4; ++kb) {
        const int aoffA = (w * 4 + kb) * 512 + lnofs;
        short8 ahA = *reinterpret_cast<const short8*>(wmp_hi + aoffA);
        short8 alA = *reinterpret_cast<const short8*>(wmp_lo + aoffA);
        short8 bf[2];
        #pragma unroll
        for (int ct = 0; ct < 2; ++ct)
            bf[ct] = *reinterpret_cast<const short8*>(
                y_lds + (kb * 2 + ct) * 512 + lnofs);
        #pragma unroll
        for (int ct = 0; ct < 2; ++ct) {
            accA[ct] = __builtin_amdgcn_mfma_f32_16x16x32_bf16(ahA, bf[ct], accA[ct], 0, 0, 0);
            accA[ct] = __builtin_amdgcn_mfma_f32_16x16x32_bf16(alA, bf[ct], accA[ct], 0, 0, 0);
        }
    }

    #pragma unroll
    for (int ct = 0; ct < 2; ++ct) {
        const int p = P0 + ct * 16 + lm;
        #pragma unroll
        for (int reg = 0; reg < 4; ++reg) {
            const int oA = w * 16 + quad * 4 + reg;
            const int ofsA = (b * 256 + oA) * 4096 + p;
            out[ofsA] = accA[ct][reg] + x[ofsA];
        }
    }
}

extern "C" void kernel_launch(void* const* d_in, const int* in_sizes, int n_in,
                              void* d_out, int out_size, void* d_ws, size_t ws_size,
                              hipStream_t stream) {
    const float* x       = (const float*)d_in[0];
    const float* w_phi   = (const float*)d_in[1];
    const float* w_theta = (const float*)d_in[2];
    const float* w_g     = (const float*)d_in[3];
    const float* w_mask  = (const float*)d_in[4];

    float* out_f = (float*)d_out;

    unsigned short* ws_u  = (unsigned short*)d_ws;
    unsigned short* A_phi = ws_u;                      // 2,580,480 ush
    unsigned short* A_g   = ws_u + 2580480;            // 2,580,480 ush
    unsigned short* th_u  = ws_u + 7258112;            // 2,097,152 ush
    float*          sc_f  = (float*)(ws_u + 9355264);  // 1,048,576 fp32
    unsigned short* xph   = ws_u + 11452416;           // 4,194,304 ush
    unsigned short* xpl   = ws_u + 15646720;           // 4,194,304 ush
    unsigned short* w3ph  = ws_u + 19841024;           // 98,304 ush
    unsigned short* w3pl  = ws_u + 19939328;           // 98,304 ush
    unsigned short* wmph  = ws_u + 20037632;           // 32,768 ush
    unsigned short* wmpl  = ws_u + 20070400;           // 32,768 ush
    float*          m_f   = (float*)(ws_u + 20103168); // 12,544 fp32
    float*          inv_f = (float*)(ws_u + 20128256); // 12,544 fp32

    // 1: prep (packed operand build + zero planes)
    hipLaunchKernelGGL(prep_kernel, dim3(1152), dim3(256), 0, stream,
                       x, w_phi, w_theta, w_g, w_mask,
                       xph, xpl, w3ph, w3pl, wmph, wmpl, (uint4*)A_phi);
    // 2: conv3 split-tile MFMA (32 px/block)
    hipLaunchKernelGGL(conv3_mfma_kernel, dim3(128, 3, 4), dim3(256), 0, stream,
                       xph, xpl, w3ph, w3pl, A_phi, th_u, A_g);
    // 3: scores (fp32 LDS window + residue addresses + 4-wide theta reads)
    hipLaunchKernelGGL(scores_kernel, dim3(256, 4), dim3(1024), 0, stream,
                       A_phi, th_u, sc_f);
    // 4: softmax stats (m, inv) only
    hipLaunchKernelGGL(softmax_stats_kernel, dim3(256), dim3(256), 0, stream,
                       sc_f, m_f, inv_f);
    // 5: fused aggregate + maskconv -> out (2-wide at reads)
    hipLaunchKernelGGL(agg_mask_kernel, dim3(128, 4), dim3(1024), 0, stream,
                       sc_f, m_f, inv_f, A_g, wmph, wmpl, x, out_f);
}